// Round 5
// baseline (115.945 us; speedup 1.0000x reference)
//
#include <hip/hip_runtime.h>
#include <hip/hip_bf16.h>
#include <cstdint>
#include <cstddef>

#define BB 4
#define CC 128
#define NN 8192
#define KK 16
#define HH 64
#define MM 32
#define C2 256

typedef __attribute__((ext_vector_type(8))) short bf16x8;
typedef __attribute__((ext_vector_type(4))) float f32x4;
typedef unsigned int __attribute__((ext_vector_type(2))) u32x2;

__device__ __forceinline__ unsigned short f2bf(float f){
    unsigned int x = __float_as_uint(f);
    x += 0x7fffu + ((x >> 16) & 1u);
    return (unsigned short)(x >> 16);
}
__device__ __forceinline__ unsigned int pk2(float a, float b){
    return (unsigned int)f2bf(a) | ((unsigned int)f2bf(b) << 16);
}
__device__ __forceinline__ float lo16(unsigned int u){ return __uint_as_float(u << 16); }
__device__ __forceinline__ float hi16(unsigned int u){ return __uint_as_float(u & 0xffff0000u); }
__device__ __forceinline__ float b2f(unsigned short u){ return __uint_as_float((unsigned int)u << 16); }
__device__ __forceinline__ float gelu(float a){
    return 0.5f*a*(1.0f+erff(a*0.7071067811865475f));
}
// batch-affinity XCD remap: XCD pair {2b,2b+1} owns batch b.
__device__ __forceinline__ void xcd_remap(int bid, int& b, int& tile){
    int xcd = bid & 7;
    b = xcd >> 1;
    tile = (bid >> 3) * 2 + (xcd & 1);
}

// ---------------- K1: pe path, fused MFMA version ---------------------------
__global__ __launch_bounds__(256) void k_pe(
    const float* __restrict__ dp, const float* __restrict__ dirs,
    const float* __restrict__ w1,
    const float* __restrict__ bng, const float* __restrict__ bnb,
    const float* __restrict__ bnm, const float* __restrict__ bnv,
    const float* __restrict__ w2, const float* __restrict__ b2,
    unsigned short* __restrict__ pe)
{
    __shared__ float s_dx[MM], s_dy[MM], s_dz[MM];
    __shared__ alignas(16) float dnx[64*16], dny[64*16], dnz[64*16];
    __shared__ alignas(16) unsigned short th[64*32];
    __shared__ alignas(16) unsigned short ws1[64*32];
    __shared__ alignas(16) unsigned short hs[64*64];
    __shared__ alignas(16) unsigned short ws2[128*64];
    __shared__ float s_sc[HH], s_sh[HH], s_b2[CC];

    const int tid = threadIdx.x;
    int b, tile; xcd_remap(blockIdx.x, b, tile);
    const int n0 = tile * 64;

    if (tid < MM){
        float x=dirs[tid*3+0], y=dirs[tid*3+1], z=dirs[tid*3+2];
        float inv = 1.0f / fmaxf(sqrtf(x*x+y*y+z*z), 1e-12f);
        s_dx[tid]=x*inv; s_dy[tid]=y*inv; s_dz[tid]=z*inv;
    }
    #pragma unroll
    for (int p=0;p<2;p++){
        int id = tid + p*256;
        int row = id >> 3, c4 = (id & 7)*4;
        float4 w = *(const float4*)(w1 + row*MM + c4);
        int off = row*64 + ((c4*2) ^ ((row&3)<<4));
        uint2 v; v.x = pk2(w.x,w.y); v.y = pk2(w.z,w.w);
        *(uint2*)((char*)ws1 + off) = v;
    }
    #pragma unroll
    for (int p=0;p<8;p++){
        int id = tid + p*256;
        int row = id >> 4, c4 = (id & 15)*4;
        float4 w = *(const float4*)(w2 + row*HH + c4);
        int off = row*128 + ((c4*2) ^ ((row&7)<<4));
        uint2 v; v.x = pk2(w.x,w.y); v.y = pk2(w.z,w.w);
        *(uint2*)((char*)ws2 + off) = v;
    }
    if (tid < HH){
        float sc = bng[tid] / sqrtf(bnv[tid] + 1e-5f);
        s_sc[tid]=sc; s_sh[tid]=bnb[tid]-bnm[tid]*sc;
    }
    if (tid >= 64 && tid < 192) s_b2[tid-64] = b2[tid-64];

    {
        const size_t cstride = (size_t)NN*KK;
        const float* base = dp + (size_t)b*3*cstride + (size_t)n0*KK + tid*4;
        float4 X = *(const float4*)(base);
        float4 Y = *(const float4*)(base + cstride);
        float4 Z = *(const float4*)(base + 2*cstride);
        float i0 = 1.0f/fmaxf(sqrtf(X.x*X.x+Y.x*Y.x+Z.x*Z.x),1e-12f);
        float i1 = 1.0f/fmaxf(sqrtf(X.y*X.y+Y.y*Y.y+Z.y*Z.y),1e-12f);
        float i2 = 1.0f/fmaxf(sqrtf(X.z*X.z+Y.z*Y.z+Z.z*Z.z),1e-12f);
        float i3 = 1.0f/fmaxf(sqrtf(X.w*X.w+Y.w*Y.w+Z.w*Z.w),1e-12f);
        float4 xn = {X.x*i0, X.y*i1, X.z*i2, X.w*i3};
        float4 yn = {Y.x*i0, Y.y*i1, Y.z*i2, Y.w*i3};
        float4 zn = {Z.x*i0, Z.y*i1, Z.z*i2, Z.w*i3};
        const int np = tid >> 2;
        const int off = np*64 + (((tid&3)*16) ^ ((np&3)<<4));
        *(float4*)((char*)dnx + off) = xn;
        *(float4*)((char*)dny + off) = yn;
        *(float4*)((char*)dnz + off) = zn;
    }
    __syncthreads();

    {
        const int np = tid & 63, dg = tid >> 6;
        float vx[8], vy[8], vz[8];
        #pragma unroll
        for (int d=0;d<8;d++){ vx[d]=s_dx[dg*8+d]; vy[d]=s_dy[dg*8+d]; vz[d]=s_dz[dg*8+d]; }
        float tm[8];
        #pragma unroll
        for (int d=0;d<8;d++) tm[d] = -2.0f;
        #pragma unroll
        for (int g=0;g<4;g++){
            int off = np*64 + ((g*16) ^ ((np&3)<<4));
            float4 x4 = *(const float4*)((const char*)dnx + off);
            float4 y4 = *(const float4*)((const char*)dny + off);
            float4 z4 = *(const float4*)((const char*)dnz + off);
            const float xs[4]={x4.x,x4.y,x4.z,x4.w}, ys[4]={y4.x,y4.y,y4.z,y4.w},
                        zs[4]={z4.x,z4.y,z4.z,z4.w};
            #pragma unroll
            for (int q=0;q<4;q++)
                #pragma unroll
                for (int d=0;d<8;d++)
                    tm[d] = fmaxf(tm[d], vx[d]*xs[q]+vy[d]*ys[q]+vz[d]*zs[q]);
        }
        uint4 t4; t4.x=pk2(tm[0],tm[1]); t4.y=pk2(tm[2],tm[3]);
        t4.z=pk2(tm[4],tm[5]); t4.w=pk2(tm[6],tm[7]);
        int off = np*64 + ((dg*16) ^ ((np&3)<<4));
        *(uint4*)((char*)th + off) = t4;
    }
    __syncthreads();

    const int wid = tid >> 6, lane = tid & 63;
    const int lr = lane & 15, lg = lane >> 4;

    {
        const int arow = wid*16 + lr;
        bf16x8 afr = *(const bf16x8*)((const char*)ws1 + arow*64 + ((lg*16) ^ ((arow&3)<<4)));
        f32x4 hacc[4];
        #pragma unroll
        for (int nf=0;nf<4;nf++){
            int pt = nf*16 + lr;
            bf16x8 bfr = *(const bf16x8*)((const char*)th + pt*64 + ((lg*16) ^ ((pt&3)<<4)));
            f32x4 z = {0.f,0.f,0.f,0.f};
            hacc[nf] = __builtin_amdgcn_mfma_f32_16x16x32_bf16(afr, bfr, z, 0,0,0);
        }
        #pragma unroll
        for (int nf=0;nf<4;nf++){
            int ch0 = wid*16 + lg*4;
            int pt = nf*16 + lr;
            float g0 = gelu(hacc[nf].x*s_sc[ch0+0] + s_sh[ch0+0]);
            float g1 = gelu(hacc[nf].y*s_sc[ch0+1] + s_sh[ch0+1]);
            float g2 = gelu(hacc[nf].z*s_sc[ch0+2] + s_sh[ch0+2]);
            float g3 = gelu(hacc[nf].w*s_sc[ch0+3] + s_sh[ch0+3]);
            uint2 v; v.x = pk2(g0,g1); v.y = pk2(g2,g3);
            *(uint2*)((char*)hs + pt*128 + ((ch0*2) ^ ((pt&7)<<4))) = v;
        }
    }
    __syncthreads();

    {
        f32x4 pacc[2][4];
        #pragma unroll
        for (int mi=0;mi<2;mi++)
            #pragma unroll
            for (int nf=0;nf<4;nf++) pacc[mi][nf] = (f32x4){0.f,0.f,0.f,0.f};
        #pragma unroll
        for (int ks=0;ks<2;ks++){
            bf16x8 a[2], x[4];
            #pragma unroll
            for (int mi=0;mi<2;mi++){
                int row = (wid*2+mi)*16 + lr;
                a[mi] = *(const bf16x8*)((const char*)ws2 + row*128 + ((ks*64 + lg*16) ^ ((row&7)<<4)));
            }
            #pragma unroll
            for (int nf=0;nf<4;nf++){
                int pt = nf*16 + lr;
                x[nf] = *(const bf16x8*)((const char*)hs + pt*128 + ((ks*64 + lg*16) ^ ((pt&7)<<4)));
            }
            #pragma unroll
            for (int mi=0;mi<2;mi++)
                #pragma unroll
                for (int nf=0;nf<4;nf++)
                    pacc[mi][nf] = __builtin_amdgcn_mfma_f32_16x16x32_bf16(a[mi], x[nf], pacc[mi][nf], 0,0,0);
        }
        #pragma unroll
        for (int mi=0;mi<2;mi++){
            #pragma unroll
            for (int nf=0;nf<4;nf++){
                int ch0 = (wid*2+mi)*16 + lg*4;
                int pt = nf*16 + lr;
                u32x2 v;
                v.x = pk2(pacc[mi][nf].x + s_b2[ch0+0], pacc[mi][nf].y + s_b2[ch0+1]);
                v.y = pk2(pacc[mi][nf].z + s_b2[ch0+2], pacc[mi][nf].w + s_b2[ch0+3]);
                __builtin_nontemporal_store(v, (u32x2*)(pe + (size_t)(b*NN + n0 + pt)*CC + ch0));
            }
        }
    }
}

// ---------------- K2: f1/f2/f3 MFMA GEMM -> t1,t2,f3t (B,N,128) bf16 --------
__global__ __launch_bounds__(256) void k_lin3(
    const float* __restrict__ f,
    const float* __restrict__ w1g, const float* __restrict__ b1g,
    const float* __restrict__ w2g, const float* __restrict__ b2g,
    const float* __restrict__ w3g, const float* __restrict__ b3g,
    unsigned short* __restrict__ t1, unsigned short* __restrict__ t2,
    unsigned short* __restrict__ f3t)
{
    __shared__ alignas(16) unsigned short Xs[64*128];
    __shared__ alignas(16) unsigned short Ws[128*128];
    __shared__ float s_bias[128];
    const int tid = threadIdx.x;
    int b, tile;
    xcd_remap(blockIdx.x, b, tile);
    const int n0 = tile * 64;

    {
        const int j = (tid & 15) * 4;
        #pragma unroll
        for (int p = 0; p < 2; ++p){
            const int cb = ((tid >> 4) + p*16) * 4;
            const float* src = f + ((size_t)b*CC + cb)*NN + n0 + j;
            float4 r0 = *(const float4*)(src);
            float4 r1 = *(const float4*)(src + NN);
            float4 r2 = *(const float4*)(src + 2*(size_t)NN);
            float4 r3 = *(const float4*)(src + 3*(size_t)NN);
            const float rr[4][4] = {{r0.x,r1.x,r2.x,r3.x},{r0.y,r1.y,r2.y,r3.y},
                                    {r0.z,r1.z,r2.z,r3.z},{r0.w,r1.w,r2.w,r3.w}};
            #pragma unroll
            for (int i=0;i<4;i++){
                int n = j + i;
                int off = n*256 + ((cb*2) ^ ((n&7)<<4));
                uint2 v; v.x = pk2(rr[i][0], rr[i][1]); v.y = pk2(rr[i][2], rr[i][3]);
                *(uint2*)((char*)Xs + off) = v;
            }
        }
    }

    const int wid = tid >> 6, lane = tid & 63;
    const int lr = lane & 15, lg = lane >> 4;
    const int o0 = (wid >> 1) * 64;
    const int nl0 = (wid & 1) * 32;

    for (int mat = 0; mat < 3; ++mat){
        const float* Wg = (mat==0)? w1g : (mat==1)? w2g : w3g;
        const float* Bg = (mat==0)? b1g : (mat==1)? b2g : b3g;
        unsigned short* dst = (mat==0)? t1 : (mat==1)? t2 : f3t;
        __syncthreads();
        #pragma unroll 4
        for (int p = 0; p < 16; ++p){
            int o = (tid >> 5) + p*8;
            int c4 = (tid & 31) * 4;
            float4 w = *(const float4*)(Wg + (size_t)o*CC + c4);
            int off = o*256 + ((c4*2) ^ ((o&7)<<4));
            uint2 v; v.x = pk2(w.x, w.y); v.y = pk2(w.z, w.w);
            *(uint2*)((char*)Ws + off) = v;
        }
        if (tid < 128) s_bias[tid] = Bg[tid];
        __syncthreads();

        f32x4 acc[4][2];
        #pragma unroll
        for (int fi=0;fi<4;fi++){
            int o = o0 + fi*16 + lg*4;
            f32x4 bi = {s_bias[o], s_bias[o+1], s_bias[o+2], s_bias[o+3]};
            acc[fi][0] = bi; acc[fi][1] = bi;
        }
        #pragma unroll
        for (int kk=0; kk<4; ++kk){
            const int kb = kk*64 + lg*16;
            bf16x8 a[4], x[2];
            #pragma unroll
            for (int fi=0;fi<4;fi++){
                int row = o0 + fi*16 + lr;
                a[fi] = *(const bf16x8*)((const char*)Ws + row*256 + (kb ^ ((row&7)<<4)));
            }
            #pragma unroll
            for (int fj=0;fj<2;fj++){
                int nr = nl0 + fj*16 + lr;
                x[fj] = *(const bf16x8*)((const char*)Xs + nr*256 + (kb ^ ((nr&7)<<4)));
            }
            #pragma unroll
            for (int fi=0;fi<4;fi++)
                #pragma unroll
                for (int fj=0;fj<2;fj++)
                    acc[fi][fj] = __builtin_amdgcn_mfma_f32_16x16x32_bf16(a[fi], x[fj], acc[fi][fj], 0,0,0);
        }
        #pragma unroll
        for (int fi=0;fi<4;fi++){
            #pragma unroll
            for (int fj=0;fj<2;fj++){
                int o = o0 + fi*16 + lg*4;
                int n = n0 + nl0 + fj*16 + lr;
                ushort4 u;
                u.x = f2bf(acc[fi][fj].x); u.y = f2bf(acc[fi][fj].y);
                u.z = f2bf(acc[fi][fj].z); u.w = f2bf(acc[fi][fj].w);
                *(ushort4*)(dst + (size_t)(b*NN + n)*CC + o) = u;
            }
        }
    }
}

// ---------------- K3a: agg1 = knn_max(t1) -----------------------------------
// 2 points per wave; 32 lanes x 4ch (uint2) per point; table stays cached.
__global__ __launch_bounds__(256) void k_agg1(
    const int* __restrict__ qidx,
    const unsigned short* __restrict__ t1,
    unsigned short* __restrict__ agg1)
{
    const int lane = threadIdx.x & 63;
    const int wrp  = threadIdx.x >> 6;
    const int cl = lane & 31, pt = lane >> 5;
    int b, tile; xcd_remap(blockIdx.x, b, tile);   // 1024 tiles of 8 pts per batch
    const int n = tile*8 + wrp*2 + pt;
    const int p = b*NN + n;
    const int* idxp = qidx + (size_t)p*KK;

    float a0=-3.0e38f, a1=-3.0e38f, a2=-3.0e38f, a3=-3.0e38f;
    const unsigned short* gb = t1 + (size_t)b*NN*CC + cl*4;
    #pragma unroll
    for (int k=0;k<KK;k++){
        int j = idxp[k];
        u32x2 gv = *(const u32x2*)(gb + (size_t)j*CC);
        a0 = fmaxf(a0, lo16(gv.x)); a1 = fmaxf(a1, hi16(gv.x));
        a2 = fmaxf(a2, lo16(gv.y)); a3 = fmaxf(a3, hi16(gv.y));
    }
    u32x2 o; o.x = pk2(a0,a1); o.y = pk2(a2,a3);   // exact: inputs were bf16
    __builtin_nontemporal_store(o, (u32x2*)(agg1 + (size_t)p*CC + cl*4));
}

// ---------------- K3b: agg2=knn_max(t2)+t2; combine+BN+residual -> fmidb ----
__global__ __launch_bounds__(256) void k_agg2(
    const float* __restrict__ f,
    const int* __restrict__ qidx,
    const unsigned short* __restrict__ t2,
    const unsigned short* __restrict__ agg1,
    const unsigned short* __restrict__ f3t,
    const unsigned short* __restrict__ pe,
    const float* __restrict__ bn_g, const float* __restrict__ bn_b,
    const float* __restrict__ bn_m, const float* __restrict__ bn_v,
    unsigned short* __restrict__ fmidb)
{
    __shared__ float s_sc[CC], s_sh[CC];
    const int tid = threadIdx.x;
    if (tid < CC){
        float sc = bn_g[tid] / sqrtf(bn_v[tid] + 1e-5f);
        s_sc[tid] = sc; s_sh[tid] = bn_b[tid] - bn_m[tid]*sc;
    }
    __syncthreads();
    const int lane = tid & 63;
    const int wrp  = tid >> 6;
    const int cl = lane & 31, pt = lane >> 5;
    int b, tile; xcd_remap(blockIdx.x, b, tile);
    const int n = tile*8 + wrp*2 + pt;
    const int p = b*NN + n;
    const int* idxp = qidx + (size_t)p*KK;

    u32x2 sv = *(const u32x2*)(t2 + (size_t)p*CC + cl*4);  // self row: cached (table data)

    float a0=-3.0e38f, a1=-3.0e38f, a2=-3.0e38f, a3=-3.0e38f;
    const unsigned short* gb = t2 + (size_t)b*NN*CC + cl*4;
    #pragma unroll
    for (int k=0;k<KK;k++){
        int j = idxp[k];
        u32x2 gv = *(const u32x2*)(gb + (size_t)j*CC);
        a0 = fmaxf(a0, lo16(gv.x)); a1 = fmaxf(a1, hi16(gv.x));
        a2 = fmaxf(a2, lo16(gv.y)); a3 = fmaxf(a3, hi16(gv.y));
    }
    // agg2 = max + self
    a0 += lo16(sv.x); a1 += hi16(sv.x); a2 += lo16(sv.y); a3 += hi16(sv.y);

    u32x2 g1 = __builtin_nontemporal_load((const u32x2*)(agg1 + (size_t)p*CC + cl*4));
    u32x2 f3 = __builtin_nontemporal_load((const u32x2*)(f3t  + (size_t)p*CC + cl*4));
    u32x2 pv = __builtin_nontemporal_load((const u32x2*)(pe   + (size_t)p*CC + cl*4));
    float s[4] = { a0 + lo16(g1.x) + lo16(f3.x), a1 + hi16(g1.x) + hi16(f3.x),
                   a2 + lo16(g1.y) + lo16(f3.y), a3 + hi16(g1.y) + hi16(f3.y) };
    float pp[4] = { lo16(pv.x), hi16(pv.x), lo16(pv.y), hi16(pv.y) };
    const int ch = cl*4;
    const float* fc = f + ((size_t)b*CC + ch)*NN + n;
    float ov[4];
    #pragma unroll
    for (int i=0;i<4;i++){
        float res = __builtin_nontemporal_load(fc + (size_t)i*NN);
        ov[i] = res + s[i]*s_sc[ch+i] + s_sh[ch+i] + pp[i];
    }
    u32x2 o; o.x = pk2(ov[0],ov[1]); o.y = pk2(ov[2],ov[3]);
    __builtin_nontemporal_store(o, (u32x2*)(fmidb + (size_t)p*CC + ch));
}

// ---------------- K4: h2 = gelu(bn(m_w1 @ fmid)) MFMA -----------------------
__global__ __launch_bounds__(256) void k_h2(
    const unsigned short* __restrict__ fmidb,
    const float* __restrict__ w1g,
    const float* __restrict__ bng, const float* __restrict__ bnb,
    const float* __restrict__ bnm, const float* __restrict__ bnv,
    unsigned short* __restrict__ h2)
{
    __shared__ alignas(16) unsigned short Xs[64*128];
    __shared__ alignas(16) unsigned short Ws[128*128];
    __shared__ float s_sc[128], s_sh[128];
    const int tid = threadIdx.x;
    int b, tile;
    xcd_remap(blockIdx.x, b, tile);
    const int n0 = tile * 64;
    const int jh = blockIdx.y;

    #pragma unroll
    for (int p=0;p<4;p++){
        int n = (tid>>4) + p*16;
        int c8 = (tid&15)*8;
        uint4 v = *(const uint4*)(fmidb + (size_t)(b*NN + n0 + n)*CC + c8);
        int off = n*256 + ((c8*2) ^ ((n&7)<<4));
        *(uint4*)((char*)Xs + off) = v;
    }
    const float* Wg = w1g + (size_t)jh*128*CC;
    #pragma unroll 4
    for (int p = 0; p < 16; ++p){
        int o = (tid >> 5) + p*8;
        int c4 = (tid & 31) * 4;
        float4 w = *(const float4*)(Wg + (size_t)o*CC + c4);
        int off = o*256 + ((c4*2) ^ ((o&7)<<4));
        uint2 v; v.x = pk2(w.x, w.y); v.y = pk2(w.z, w.w);
        *(uint2*)((char*)Ws + off) = v;
    }
    if (tid < 128){
        int jg = jh*128 + tid;
        float sc = bng[jg] / sqrtf(bnv[jg] + 1e-5f);
        s_sc[tid] = sc; s_sh[tid] = bnb[jg] - bnm[jg]*sc;
    }
    __syncthreads();

    const int wid = tid >> 6, lane = tid & 63;
    const int lr = lane & 15, lg = lane >> 4;
    const int o0 = (wid >> 1) * 64;
    const int nl0 = (wid & 1) * 32;

    f32x4 acc[4][2];
    #pragma unroll
    for (int fi=0;fi<4;fi++){ acc[fi][0]=(f32x4){0,0,0,0}; acc[fi][1]=(f32x4){0,0,0,0}; }
    #pragma unroll
    for (int kk=0; kk<4; ++kk){
        const int kb = kk*64 + lg*16;
        bf16x8 a[4], x[2];
        #pragma unroll
        for (int fi=0;fi<4;fi++){
            int row = o0 + fi*16 + lr;
            a[fi] = *(const bf16x8*)((const char*)Ws + row*256 + (kb ^ ((row&7)<<4)));
        }
        #pragma unroll
        for (int fj=0;fj<2;fj++){
            int nr = nl0 + fj*16 + lr;
            x[fj] = *(const bf16x8*)((const char*)Xs + nr*256 + (kb ^ ((nr&7)<<4)));
        }
        #pragma unroll
        for (int fi=0;fi<4;fi++)
            #pragma unroll
            for (int fj=0;fj<2;fj++)
                acc[fi][fj] = __builtin_amdgcn_mfma_f32_16x16x32_bf16(a[fi], x[fj], acc[fi][fj], 0,0,0);
    }
    #pragma unroll
    for (int fi=0;fi<4;fi++){
        #pragma unroll
        for (int fj=0;fj<2;fj++){
            int o = o0 + fi*16 + lg*4;
            int n = n0 + nl0 + fj*16 + lr;
            float v0 = gelu(acc[fi][fj].x*s_sc[o+0] + s_sh[o+0]);
            float v1 = gelu(acc[fi][fj].y*s_sc[o+1] + s_sh[o+1]);
            float v2 = gelu(acc[fi][fj].z*s_sc[o+2] + s_sh[o+2]);
            float v3 = gelu(acc[fi][fj].w*s_sc[o+3] + s_sh[o+3]);
            ushort4 u; u.x=f2bf(v0); u.y=f2bf(v1); u.z=f2bf(v2); u.w=f2bf(v3);
            *(ushort4*)(h2 + (size_t)(b*NN + n)*C2 + jh*128 + o) = u;
        }
    }
}

// ---------------- K5: out = fmid + m_w2 @ h2 MFMA (K=256, chunked W) --------
__global__ __launch_bounds__(256) void k_out(
    const unsigned short* __restrict__ h2,
    const unsigned short* __restrict__ fmidb,
    const float* __restrict__ w2g,
    float* __restrict__ out)
{
    __shared__ alignas(16) unsigned short Xs[64*256];
    __shared__ alignas(16) unsigned short Wc[128*64];
    const int tid = threadIdx.x;
    int b, tile;
    xcd_remap(blockIdx.x, b, tile);
    const int n0 = tile * 64;

    #pragma unroll
    for (int p=0;p<8;p++){
        int n = (tid>>5) + p*8;
        int c8 = (tid&31)*8;
        uint4 v = *(const uint4*)(h2 + (size_t)(b*NN + n0 + n)*C2 + c8);
        int off = n*512 + ((c8*2) ^ ((n&7)<<4));
        *(uint4*)((char*)Xs + off) = v;
    }

    const int wid = tid >> 6, lane = tid & 63;
    const int lr = lane & 15, lg = lane >> 4;
    const int o0 = (wid >> 1) * 64;
    const int nl0 = (wid & 1) * 32;

    f32x4 acc[4][2];
    #pragma unroll
    for (int fi=0;fi<4;fi++){ acc[fi][0]=(f32x4){0,0,0,0}; acc[fi][1]=(f32x4){0,0,0,0}; }

    for (int kc=0; kc<4; ++kc){
        __syncthreads();
        #pragma unroll 4
        for (int p=0;p<8;p++){
            int o = (tid>>4) + p*16;
            int c4 = (tid&15)*4;
            float4 w = *(const float4*)(w2g + (size_t)o*C2 + kc*64 + c4);
            int off = o*128 + ((c4*2) ^ ((o&7)<<4));
            uint2 v; v.x=pk2(w.x,w.y); v.y=pk2(w.z,w.w);
            *(uint2*)((char*)Wc + off) = v;
        }
        __syncthreads();
        #pragma unroll
        for (int kk=0; kk<2; ++kk){
            const int kbW = kk*64 + lg*16;
            const int kbX = kc*128 + kk*64 + lg*16;
            bf16x8 a[4], x[2];
            #pragma unroll
            for (int fi=0;fi<4;fi++){
                int row = o0 + fi*16 + lr;
                a[fi] = *(const bf16x8*)((const char*)Wc + row*128 + (kbW ^ ((row&7)<<4)));
            }
            #pragma unroll
            for (int fj=0;fj<2;fj++){
                int nr = nl0 + fj*16 + lr;
                x[fj] = *(const bf16x8*)((const char*)Xs + nr*512 + (kbX ^ ((nr&7)<<4)));
            }
            #pragma unroll
            for (int fi=0;fi<4;fi++)
                #pragma unroll
                for (int fj=0;fj<2;fj++)
                    acc[fi][fj] = __builtin_amdgcn_mfma_f32_16x16x32_bf16(a[fi], x[fj], acc[fi][fj], 0,0,0);
        }
    }
    #pragma unroll
    for (int fi=0;fi<4;fi++){
        #pragma unroll
        for (int fj=0;fj<2;fj++){
            int o = o0 + fi*16 + lg*4;
            int n = n0 + nl0 + fj*16 + lr;
            ushort4 r4 = *(const ushort4*)(fmidb + (size_t)(b*NN + n)*CC + o);
            float* op = out + ((size_t)b*CC + o)*NN + n;
            op[0*(size_t)NN] = b2f(r4.x) + acc[fi][fj].x;
            op[1*(size_t)NN] = b2f(r4.y) + acc[fi][fj].y;
            op[2*(size_t)NN] = b2f(r4.z) + acc[fi][fj].z;
            op[3*(size_t)NN] = b2f(r4.w) + acc[fi][fj].w;
        }
    }
}

extern "C" void kernel_launch(void* const* d_in, const int* in_sizes, int n_in,
                              void* d_out, int out_size, void* d_ws, size_t ws_size,
                              hipStream_t stream)
{
    const float* f      = (const float*)d_in[0];
    const float* dp     = (const float*)d_in[1];
    const int*   qidx   = (const int*)  d_in[2];
    const float* dirs   = (const float*)d_in[3];
    const float* de_w1  = (const float*)d_in[4];
    const float* de_bng = (const float*)d_in[5];
    const float* de_bnb = (const float*)d_in[6];
    const float* de_bnm = (const float*)d_in[7];
    const float* de_bnv = (const float*)d_in[8];
    const float* de_w2  = (const float*)d_in[9];
    const float* de_b2  = (const float*)d_in[10];
    const float* l_w1   = (const float*)d_in[11];
    const float* l_b1   = (const float*)d_in[12];
    const float* l_w2   = (const float*)d_in[13];
    const float* l_b2   = (const float*)d_in[14];
    const float* l_w3   = (const float*)d_in[15];
    const float* l_b3   = (const float*)d_in[16];
    const float* l_bng  = (const float*)d_in[17];
    const float* l_bnb  = (const float*)d_in[18];
    const float* l_bnm  = (const float*)d_in[19];
    const float* l_bnv  = (const float*)d_in[20];
    const float* m_w1   = (const float*)d_in[21];
    const float* m_bng  = (const float*)d_in[22];
    const float* m_bnb  = (const float*)d_in[23];
    const float* m_bnm  = (const float*)d_in[24];
    const float* m_bnv  = (const float*)d_in[25];
    const float* m_w2   = (const float*)d_in[26];

    char* ws = (char*)d_ws;
    // layout (bytes), all bf16 (B,N,128) = 8 MB each unless noted:
    //   t1    [0,        8388608)
    //   t2    [8388608,  16777216)
    //   h2    (B,N,256)  [0, 16777216)  (aliases t1+t2; dead after k_agg2)
    //   f3t   [16777216, 25165824)
    //   pe    [25165824, 33554432)
    //   agg1  [33554432, 41943040)
    //   fmidb [41943040, 50331648)
    unsigned short* t1    = (unsigned short*)(ws + 0);
    unsigned short* t2    = (unsigned short*)(ws + 8388608);
    unsigned short* h2    = (unsigned short*)(ws + 0);
    unsigned short* f3t   = (unsigned short*)(ws + 16777216);
    unsigned short* pe    = (unsigned short*)(ws + 25165824);
    unsigned short* agg1  = (unsigned short*)(ws + 33554432);
    unsigned short* fmidb = (unsigned short*)(ws + 41943040);

    k_pe<<<dim3(512), dim3(256), 0, stream>>>(dp, dirs, de_w1, de_bng, de_bnb, de_bnm, de_bnv,
                                              de_w2, de_b2, pe);
    k_lin3<<<dim3(512), dim3(256), 0, stream>>>(f, l_w1, l_b1, l_w2, l_b2, l_w3, l_b3, t1, t2, f3t);
    k_agg1<<<dim3(4096), dim3(256), 0, stream>>>(qidx, t1, agg1);
    k_agg2<<<dim3(4096), dim3(256), 0, stream>>>(f, qidx, t2, agg1, f3t, pe,
                                                 l_bng, l_bnb, l_bnm, l_bnv, fmidb);
    k_h2<<<dim3(512,2), dim3(256), 0, stream>>>(fmidb, m_w1, m_bng, m_bnb, m_bnm, m_bnv, h2);
    k_out<<<dim3(512), dim3(256), 0, stream>>>(h2, fmidb, m_w2, (float*)d_out);
}

// Round 6
// 97.515 us; speedup vs baseline: 1.1890x; 1.1890x over previous
//
#include <hip/hip_runtime.h>
#include <hip/hip_bf16.h>
#include <cstdint>
#include <cstddef>

#define BB 4
#define CC 128
#define NN 8192
#define KK 16
#define HH 64
#define MM 32
#define C2 256

typedef __attribute__((ext_vector_type(8))) short bf16x8;
typedef __attribute__((ext_vector_type(4))) float f32x4;
typedef unsigned short u16x2v __attribute__((ext_vector_type(2)));

__device__ __forceinline__ unsigned short f2bf(float f){
    unsigned int x = __float_as_uint(f);
    x += 0x7fffu + ((x >> 16) & 1u);
    return (unsigned short)(x >> 16);
}
__device__ __forceinline__ unsigned int pk2(float a, float b){
    return (unsigned int)f2bf(a) | ((unsigned int)f2bf(b) << 16);
}
__device__ __forceinline__ float lo16(unsigned int u){ return __uint_as_float(u << 16); }
__device__ __forceinline__ float hi16(unsigned int u){ return __uint_as_float(u & 0xffff0000u); }
__device__ __forceinline__ float b2f(unsigned short u){ return __uint_as_float((unsigned int)u << 16); }
__device__ __forceinline__ float gelu(float a){
    return 0.5f*a*(1.0f+erff(a*0.7071067811865475f));
}
// monotone key transform: unsigned 16-bit compare on keys == float compare on bf16
// fwd: pos -> u^0x8000 ; neg -> ~u      (packed 2x16)
__device__ __forceinline__ unsigned int bf2key(unsigned int v){
    unsigned int neg = (v >> 15) & 0x10001u;
    return v ^ (0x80008000u | neg * 0x7FFFu);
}
__device__ __forceinline__ unsigned int key2bf(unsigned int k){
    unsigned int pos = (~k >> 15) & 0x10001u;
    return k ^ (0x80008000u | pos * 0x7FFFu);
}
// batch-affinity XCD remap: XCD pair {2b,2b+1} owns batch b.
__device__ __forceinline__ void xcd_remap(int bid, int& b, int& tile){
    int xcd = bid & 7;
    b = xcd >> 1;
    tile = (bid >> 3) * 2 + (xcd & 1);
}

// ---------------- K1: pe path, fused MFMA version ---------------------------
__global__ __launch_bounds__(256) void k_pe(
    const float* __restrict__ dp, const float* __restrict__ dirs,
    const float* __restrict__ w1,
    const float* __restrict__ bng, const float* __restrict__ bnb,
    const float* __restrict__ bnm, const float* __restrict__ bnv,
    const float* __restrict__ w2, const float* __restrict__ b2,
    unsigned short* __restrict__ pe)
{
    __shared__ float s_dx[MM], s_dy[MM], s_dz[MM];
    __shared__ alignas(16) float dnx[64*16], dny[64*16], dnz[64*16];
    __shared__ alignas(16) unsigned short th[64*32];
    __shared__ alignas(16) unsigned short ws1[64*32];
    __shared__ alignas(16) unsigned short hs[64*64];
    __shared__ alignas(16) unsigned short ws2[128*64];
    __shared__ float s_sc[HH], s_sh[HH], s_b2[CC];

    const int tid = threadIdx.x;
    int b, tile; xcd_remap(blockIdx.x, b, tile);
    const int n0 = tile * 64;

    if (tid < MM){
        float x=dirs[tid*3+0], y=dirs[tid*3+1], z=dirs[tid*3+2];
        float inv = 1.0f / fmaxf(sqrtf(x*x+y*y+z*z), 1e-12f);
        s_dx[tid]=x*inv; s_dy[tid]=y*inv; s_dz[tid]=z*inv;
    }
    #pragma unroll
    for (int p=0;p<2;p++){
        int id = tid + p*256;
        int row = id >> 3, c4 = (id & 7)*4;
        float4 w = *(const float4*)(w1 + row*MM + c4);
        int off = row*64 + ((c4*2) ^ ((row&3)<<4));
        uint2 v; v.x = pk2(w.x,w.y); v.y = pk2(w.z,w.w);
        *(uint2*)((char*)ws1 + off) = v;
    }
    #pragma unroll
    for (int p=0;p<8;p++){
        int id = tid + p*256;
        int row = id >> 4, c4 = (id & 15)*4;
        float4 w = *(const float4*)(w2 + row*HH + c4);
        int off = row*128 + ((c4*2) ^ ((row&7)<<4));
        uint2 v; v.x = pk2(w.x,w.y); v.y = pk2(w.z,w.w);
        *(uint2*)((char*)ws2 + off) = v;
    }
    if (tid < HH){
        float sc = bng[tid] / sqrtf(bnv[tid] + 1e-5f);
        s_sc[tid]=sc; s_sh[tid]=bnb[tid]-bnm[tid]*sc;
    }
    if (tid >= 64 && tid < 192) s_b2[tid-64] = b2[tid-64];

    {
        const size_t cstride = (size_t)NN*KK;
        const float* base = dp + (size_t)b*3*cstride + (size_t)n0*KK + tid*4;
        float4 X = *(const float4*)(base);
        float4 Y = *(const float4*)(base + cstride);
        float4 Z = *(const float4*)(base + 2*cstride);
        float i0 = 1.0f/fmaxf(sqrtf(X.x*X.x+Y.x*Y.x+Z.x*Z.x),1e-12f);
        float i1 = 1.0f/fmaxf(sqrtf(X.y*X.y+Y.y*Y.y+Z.y*Z.y),1e-12f);
        float i2 = 1.0f/fmaxf(sqrtf(X.z*X.z+Y.z*Y.z+Z.z*Z.z),1e-12f);
        float i3 = 1.0f/fmaxf(sqrtf(X.w*X.w+Y.w*Y.w+Z.w*Z.w),1e-12f);
        float4 xn = {X.x*i0, X.y*i1, X.z*i2, X.w*i3};
        float4 yn = {Y.x*i0, Y.y*i1, Y.z*i2, Y.w*i3};
        float4 zn = {Z.x*i0, Z.y*i1, Z.z*i2, Z.w*i3};
        const int np = tid >> 2;
        const int off = np*64 + (((tid&3)*16) ^ ((np&3)<<4));
        *(float4*)((char*)dnx + off) = xn;
        *(float4*)((char*)dny + off) = yn;
        *(float4*)((char*)dnz + off) = zn;
    }
    __syncthreads();

    {
        const int np = tid & 63, dg = tid >> 6;
        float vx[8], vy[8], vz[8];
        #pragma unroll
        for (int d=0;d<8;d++){ vx[d]=s_dx[dg*8+d]; vy[d]=s_dy[dg*8+d]; vz[d]=s_dz[dg*8+d]; }
        float tm[8];
        #pragma unroll
        for (int d=0;d<8;d++) tm[d] = -2.0f;
        #pragma unroll
        for (int g=0;g<4;g++){
            int off = np*64 + ((g*16) ^ ((np&3)<<4));
            float4 x4 = *(const float4*)((const char*)dnx + off);
            float4 y4 = *(const float4*)((const char*)dny + off);
            float4 z4 = *(const float4*)((const char*)dnz + off);
            const float xs[4]={x4.x,x4.y,x4.z,x4.w}, ys[4]={y4.x,y4.y,y4.z,y4.w},
                        zs[4]={z4.x,z4.y,z4.z,z4.w};
            #pragma unroll
            for (int q=0;q<4;q++)
                #pragma unroll
                for (int d=0;d<8;d++)
                    tm[d] = fmaxf(tm[d], vx[d]*xs[q]+vy[d]*ys[q]+vz[d]*zs[q]);
        }
        uint4 t4; t4.x=pk2(tm[0],tm[1]); t4.y=pk2(tm[2],tm[3]);
        t4.z=pk2(tm[4],tm[5]); t4.w=pk2(tm[6],tm[7]);
        int off = np*64 + ((dg*16) ^ ((np&3)<<4));
        *(uint4*)((char*)th + off) = t4;
    }
    __syncthreads();

    const int wid = tid >> 6, lane = tid & 63;
    const int lr = lane & 15, lg = lane >> 4;

    {
        const int arow = wid*16 + lr;
        bf16x8 afr = *(const bf16x8*)((const char*)ws1 + arow*64 + ((lg*16) ^ ((arow&3)<<4)));
        f32x4 hacc[4];
        #pragma unroll
        for (int nf=0;nf<4;nf++){
            int pt = nf*16 + lr;
            bf16x8 bfr = *(const bf16x8*)((const char*)th + pt*64 + ((lg*16) ^ ((pt&3)<<4)));
            f32x4 z = {0.f,0.f,0.f,0.f};
            hacc[nf] = __builtin_amdgcn_mfma_f32_16x16x32_bf16(afr, bfr, z, 0,0,0);
        }
        #pragma unroll
        for (int nf=0;nf<4;nf++){
            int ch0 = wid*16 + lg*4;
            int pt = nf*16 + lr;
            float g0 = gelu(hacc[nf].x*s_sc[ch0+0] + s_sh[ch0+0]);
            float g1 = gelu(hacc[nf].y*s_sc[ch0+1] + s_sh[ch0+1]);
            float g2 = gelu(hacc[nf].z*s_sc[ch0+2] + s_sh[ch0+2]);
            float g3 = gelu(hacc[nf].w*s_sc[ch0+3] + s_sh[ch0+3]);
            uint2 v; v.x = pk2(g0,g1); v.y = pk2(g2,g3);
            *(uint2*)((char*)hs + pt*128 + ((ch0*2) ^ ((pt&7)<<4))) = v;
        }
    }
    __syncthreads();

    {
        f32x4 pacc[2][4];
        #pragma unroll
        for (int mi=0;mi<2;mi++)
            #pragma unroll
            for (int nf=0;nf<4;nf++) pacc[mi][nf] = (f32x4){0.f,0.f,0.f,0.f};
        #pragma unroll
        for (int ks=0;ks<2;ks++){
            bf16x8 a[2], x[4];
            #pragma unroll
            for (int mi=0;mi<2;mi++){
                int row = (wid*2+mi)*16 + lr;
                a[mi] = *(const bf16x8*)((const char*)ws2 + row*128 + ((ks*64 + lg*16) ^ ((row&7)<<4)));
            }
            #pragma unroll
            for (int nf=0;nf<4;nf++){
                int pt = nf*16 + lr;
                x[nf] = *(const bf16x8*)((const char*)hs + pt*128 + ((ks*64 + lg*16) ^ ((pt&7)<<4)));
            }
            #pragma unroll
            for (int mi=0;mi<2;mi++)
                #pragma unroll
                for (int nf=0;nf<4;nf++)
                    pacc[mi][nf] = __builtin_amdgcn_mfma_f32_16x16x32_bf16(a[mi], x[nf], pacc[mi][nf], 0,0,0);
        }
        #pragma unroll
        for (int mi=0;mi<2;mi++){
            #pragma unroll
            for (int nf=0;nf<4;nf++){
                int ch0 = (wid*2+mi)*16 + lg*4;
                int pt = nf*16 + lr;
                ushort4 u;
                u.x = f2bf(pacc[mi][nf].x + s_b2[ch0+0]);
                u.y = f2bf(pacc[mi][nf].y + s_b2[ch0+1]);
                u.z = f2bf(pacc[mi][nf].z + s_b2[ch0+2]);
                u.w = f2bf(pacc[mi][nf].w + s_b2[ch0+3]);
                *(ushort4*)(pe + (size_t)(b*NN + n0 + pt)*CC + ch0) = u;
            }
        }
    }
}

// ---------------- K2: f1/f2/f3 MFMA GEMM ------------------------------------
// g12 (B,N,256) holds KEY-transformed f1|f2 (for packed-u16 max in gather);
// f3t (B,N,128) plain bf16.
__global__ __launch_bounds__(256) void k_lin3(
    const float* __restrict__ f,
    const float* __restrict__ w1g, const float* __restrict__ b1g,
    const float* __restrict__ w2g, const float* __restrict__ b2g,
    const float* __restrict__ w3g, const float* __restrict__ b3g,
    unsigned short* __restrict__ g12, unsigned short* __restrict__ f3t)
{
    __shared__ alignas(16) unsigned short Xs[64*128];
    __shared__ alignas(16) unsigned short Ws[128*128];
    __shared__ float s_bias[128];
    const int tid = threadIdx.x;
    int b, tile;
    xcd_remap(blockIdx.x, b, tile);
    const int n0 = tile * 64;

    {
        const int j = (tid & 15) * 4;
        #pragma unroll
        for (int p = 0; p < 2; ++p){
            const int cb = ((tid >> 4) + p*16) * 4;
            const float* src = f + ((size_t)b*CC + cb)*NN + n0 + j;
            float4 r0 = *(const float4*)(src);
            float4 r1 = *(const float4*)(src + NN);
            float4 r2 = *(const float4*)(src + 2*(size_t)NN);
            float4 r3 = *(const float4*)(src + 3*(size_t)NN);
            const float rr[4][4] = {{r0.x,r1.x,r2.x,r3.x},{r0.y,r1.y,r2.y,r3.y},
                                    {r0.z,r1.z,r2.z,r3.z},{r0.w,r1.w,r2.w,r3.w}};
            #pragma unroll
            for (int i=0;i<4;i++){
                int n = j + i;
                int off = n*256 + ((cb*2) ^ ((n&7)<<4));
                uint2 v; v.x = pk2(rr[i][0], rr[i][1]); v.y = pk2(rr[i][2], rr[i][3]);
                *(uint2*)((char*)Xs + off) = v;
            }
        }
    }

    const int wid = tid >> 6, lane = tid & 63;
    const int lr = lane & 15, lg = lane >> 4;
    const int o0 = (wid >> 1) * 64;
    const int nl0 = (wid & 1) * 32;

    for (int mat = 0; mat < 3; ++mat){
        const float* Wg = (mat==0)? w1g : (mat==1)? w2g : w3g;
        const float* Bg = (mat==0)? b1g : (mat==1)? b2g : b3g;
        __syncthreads();
        #pragma unroll 4
        for (int p = 0; p < 16; ++p){
            int o = (tid >> 5) + p*8;
            int c4 = (tid & 31) * 4;
            float4 w = *(const float4*)(Wg + (size_t)o*CC + c4);
            int off = o*256 + ((c4*2) ^ ((o&7)<<4));
            uint2 v; v.x = pk2(w.x, w.y); v.y = pk2(w.z, w.w);
            *(uint2*)((char*)Ws + off) = v;
        }
        if (tid < 128) s_bias[tid] = Bg[tid];
        __syncthreads();

        f32x4 acc[4][2];
        #pragma unroll
        for (int fi=0;fi<4;fi++){
            int o = o0 + fi*16 + lg*4;
            f32x4 bi = {s_bias[o], s_bias[o+1], s_bias[o+2], s_bias[o+3]};
            acc[fi][0] = bi; acc[fi][1] = bi;
        }
        #pragma unroll
        for (int kk=0; kk<4; ++kk){
            const int kb = kk*64 + lg*16;
            bf16x8 a[4], x[2];
            #pragma unroll
            for (int fi=0;fi<4;fi++){
                int row = o0 + fi*16 + lr;
                a[fi] = *(const bf16x8*)((const char*)Ws + row*256 + (kb ^ ((row&7)<<4)));
            }
            #pragma unroll
            for (int fj=0;fj<2;fj++){
                int nr = nl0 + fj*16 + lr;
                x[fj] = *(const bf16x8*)((const char*)Xs + nr*256 + (kb ^ ((nr&7)<<4)));
            }
            #pragma unroll
            for (int fi=0;fi<4;fi++)
                #pragma unroll
                for (int fj=0;fj<2;fj++)
                    acc[fi][fj] = __builtin_amdgcn_mfma_f32_16x16x32_bf16(a[fi], x[fj], acc[fi][fj], 0,0,0);
        }
        #pragma unroll
        for (int fi=0;fi<4;fi++){
            #pragma unroll
            for (int fj=0;fj<2;fj++){
                int o = o0 + fi*16 + lg*4;
                int n = n0 + nl0 + fj*16 + lr;
                if (mat == 2){
                    ushort4 u;
                    u.x = f2bf(acc[fi][fj].x); u.y = f2bf(acc[fi][fj].y);
                    u.z = f2bf(acc[fi][fj].z); u.w = f2bf(acc[fi][fj].w);
                    *(ushort4*)(f3t + (size_t)(b*NN + n)*CC + o) = u;
                } else {
                    uint2 kv;
                    kv.x = bf2key(pk2(acc[fi][fj].x, acc[fi][fj].y));
                    kv.y = bf2key(pk2(acc[fi][fj].z, acc[fi][fj].w));
                    *(uint2*)(g12 + (size_t)(b*NN + n)*C2 + mat*CC + o) = kv;
                }
            }
        }
    }
}

// ---------------- K3: knn gather-max (packed u16 keys) + combine ------------
__global__ __launch_bounds__(256) void k_gather(
    const float* __restrict__ f,
    const int* __restrict__ qidx,
    const unsigned short* __restrict__ g12,
    const unsigned short* __restrict__ f3t,
    const unsigned short* __restrict__ pe,
    const float* __restrict__ bn_g, const float* __restrict__ bn_b,
    const float* __restrict__ bn_m, const float* __restrict__ bn_v,
    unsigned short* __restrict__ fmidb)
{
    const int lane = threadIdx.x & 63;
    const int wrp  = threadIdx.x >> 6;
    int b, tile;
    xcd_remap(blockIdx.x, b, tile);   // 2048 tiles (of 4 points) per batch
    const int n = tile*4 + wrp;
    const int p = b*NN + n;
    // wave-uniform row -> scalar loads for the 16 indices
    const int prow = __builtin_amdgcn_readfirstlane(p);
    const int* idxp = qidx + (size_t)prow*KK;

    uint2 sv = *(const uint2*)(g12 + (size_t)p*C2 + lane*4);   // self row (keys)

    u16x2v m0 = {0,0}, m1 = {0,0};   // key 0 == most-negative bf16
    const unsigned short* gb = g12 + (size_t)b*NN*C2 + lane*4;
    #pragma unroll
    for (int k=0;k<KK;k++){
        int j = idxp[k];
        uint2 gv = *(const uint2*)(gb + (size_t)j*C2);
        m0 = __builtin_elementwise_max(m0, __builtin_bit_cast(u16x2v, gv.x));
        m1 = __builtin_elementwise_max(m1, __builtin_bit_cast(u16x2v, gv.y));
    }
    unsigned int r0 = key2bf(__builtin_bit_cast(unsigned int, m0));
    unsigned int r1 = key2bf(__builtin_bit_cast(unsigned int, m1));
    float a0 = lo16(r0), a1 = hi16(r0), a2 = lo16(r1), a3 = hi16(r1);

    if (lane >= 32){   // f2 half: agg2 = max + self
        unsigned int s0 = key2bf(sv.x), s1 = key2bf(sv.y);
        a0 += lo16(s0); a1 += hi16(s0); a2 += lo16(s1); a3 += hi16(s1);
    }
    float c0v = a0 + __shfl_xor(a0, 32);
    float c1v = a1 + __shfl_xor(a1, 32);
    float c2v = a2 + __shfl_xor(a2, 32);
    float c3v = a3 + __shfl_xor(a3, 32);
    if (lane < 32){
        const int ch = lane*4;
        uint2 f3v = *(const uint2*)(f3t + (size_t)p*CC + ch);
        uint2 pev = *(const uint2*)(pe  + (size_t)p*CC + ch);
        float s[4] = { c0v + lo16(f3v.x), c1v + hi16(f3v.x),
                       c2v + lo16(f3v.y), c3v + hi16(f3v.y) };
        float pv[4] = { lo16(pev.x), hi16(pev.x), lo16(pev.y), hi16(pev.y) };
        float4 g4 = *(const float4*)(bn_g + ch);
        float4 b4 = *(const float4*)(bn_b + ch);
        float4 m4 = *(const float4*)(bn_m + ch);
        float4 v4 = *(const float4*)(bn_v + ch);
        const float gg[4]={g4.x,g4.y,g4.z,g4.w}, bbv[4]={b4.x,b4.y,b4.z,b4.w},
                    mmv[4]={m4.x,m4.y,m4.z,m4.w}, vvv[4]={v4.x,v4.y,v4.z,v4.w};
        const float* fc = f + ((size_t)b*CC + ch)*NN + n;
        float ov[4];
        #pragma unroll
        for (int i=0;i<4;i++){
            float sc = gg[i] / sqrtf(vvv[i] + 1e-5f);
            float bnval = (s[i]-mmv[i])*sc + bbv[i];
            ov[i] = fc[(size_t)i*NN] + bnval + pv[i];
        }
        ushort4 u; u.x=f2bf(ov[0]); u.y=f2bf(ov[1]); u.z=f2bf(ov[2]); u.w=f2bf(ov[3]);
        *(ushort4*)(fmidb + (size_t)p*CC + ch) = u;
    }
}

// ---------------- K4: h2 = gelu(bn(m_w1 @ fmid)) MFMA -----------------------
__global__ __launch_bounds__(256) void k_h2(
    const unsigned short* __restrict__ fmidb,
    const float* __restrict__ w1g,
    const float* __restrict__ bng, const float* __restrict__ bnb,
    const float* __restrict__ bnm, const float* __restrict__ bnv,
    unsigned short* __restrict__ h2)
{
    __shared__ alignas(16) unsigned short Xs[64*128];
    __shared__ alignas(16) unsigned short Ws[128*128];
    __shared__ float s_sc[128], s_sh[128];
    const int tid = threadIdx.x;
    int b, tile;
    xcd_remap(blockIdx.x, b, tile);
    const int n0 = tile * 64;
    const int jh = blockIdx.y;

    #pragma unroll
    for (int p=0;p<4;p++){
        int n = (tid>>4) + p*16;
        int c8 = (tid&15)*8;
        uint4 v = *(const uint4*)(fmidb + (size_t)(b*NN + n0 + n)*CC + c8);
        int off = n*256 + ((c8*2) ^ ((n&7)<<4));
        *(uint4*)((char*)Xs + off) = v;
    }
    const float* Wg = w1g + (size_t)jh*128*CC;
    #pragma unroll 4
    for (int p = 0; p < 16; ++p){
        int o = (tid >> 5) + p*8;
        int c4 = (tid & 31) * 4;
        float4 w = *(const float4*)(Wg + (size_t)o*CC + c4);
        int off = o*256 + ((c4*2) ^ ((o&7)<<4));
        uint2 v; v.x = pk2(w.x, w.y); v.y = pk2(w.z, w.w);
        *(uint2*)((char*)Ws + off) = v;
    }
    if (tid < 128){
        int jg = jh*128 + tid;
        float sc = bng[jg] / sqrtf(bnv[jg] + 1e-5f);
        s_sc[tid] = sc; s_sh[tid] = bnb[jg] - bnm[jg]*sc;
    }
    __syncthreads();

    const int wid = tid >> 6, lane = tid & 63;
    const int lr = lane & 15, lg = lane >> 4;
    const int o0 = (wid >> 1) * 64;
    const int nl0 = (wid & 1) * 32;

    f32x4 acc[4][2];
    #pragma unroll
    for (int fi=0;fi<4;fi++){ acc[fi][0]=(f32x4){0,0,0,0}; acc[fi][1]=(f32x4){0,0,0,0}; }
    #pragma unroll
    for (int kk=0; kk<4; ++kk){
        const int kb = kk*64 + lg*16;
        bf16x8 a[4], x[2];
        #pragma unroll
        for (int fi=0;fi<4;fi++){
            int row = o0 + fi*16 + lr;
            a[fi] = *(const bf16x8*)((const char*)Ws + row*256 + (kb ^ ((row&7)<<4)));
        }
        #pragma unroll
        for (int fj=0;fj<2;fj++){
            int nr = nl0 + fj*16 + lr;
            x[fj] = *(const bf16x8*)((const char*)Xs + nr*256 + (kb ^ ((nr&7)<<4)));
        }
        #pragma unroll
        for (int fi=0;fi<4;fi++)
            #pragma unroll
            for (int fj=0;fj<2;fj++)
                acc[fi][fj] = __builtin_amdgcn_mfma_f32_16x16x32_bf16(a[fi], x[fj], acc[fi][fj], 0,0,0);
    }
    #pragma unroll
    for (int fi=0;fi<4;fi++){
        #pragma unroll
        for (int fj=0;fj<2;fj++){
            int o = o0 + fi*16 + lg*4;
            int n = n0 + nl0 + fj*16 + lr;
            float v0 = gelu(acc[fi][fj].x*s_sc[o+0] + s_sh[o+0]);
            float v1 = gelu(acc[fi][fj].y*s_sc[o+1] + s_sh[o+1]);
            float v2 = gelu(acc[fi][fj].z*s_sc[o+2] + s_sh[o+2]);
            float v3 = gelu(acc[fi][fj].w*s_sc[o+3] + s_sh[o+3]);
            ushort4 u; u.x=f2bf(v0); u.y=f2bf(v1); u.z=f2bf(v2); u.w=f2bf(v3);
            *(ushort4*)(h2 + (size_t)(b*NN + n)*C2 + jh*128 + o) = u;
        }
    }
}

// ---------------- K5: out = fmid + m_w2 @ h2 MFMA (K=256, chunked W) --------
__global__ __launch_bounds__(256) void k_out(
    const unsigned short* __restrict__ h2,
    const unsigned short* __restrict__ fmidb,
    const float* __restrict__ w2g,
    float* __restrict__ out)
{
    __shared__ alignas(16) unsigned short Xs[64*256];
    __shared__ alignas(16) unsigned short Wc[128*64];
    const int tid = threadIdx.x;
    int b, tile;
    xcd_remap(blockIdx.x, b, tile);
    const int n0 = tile * 64;

    #pragma unroll
    for (int p=0;p<8;p++){
        int n = (tid>>5) + p*8;
        int c8 = (tid&31)*8;
        uint4 v = *(const uint4*)(h2 + (size_t)(b*NN + n0 + n)*C2 + c8);
        int off = n*512 + ((c8*2) ^ ((n&7)<<4));
        *(uint4*)((char*)Xs + off) = v;
    }

    const int wid = tid >> 6, lane = tid & 63;
    const int lr = lane & 15, lg = lane >> 4;
    const int o0 = (wid >> 1) * 64;
    const int nl0 = (wid & 1) * 32;

    f32x4 acc[4][2];
    #pragma unroll
    for (int fi=0;fi<4;fi++){ acc[fi][0]=(f32x4){0,0,0,0}; acc[fi][1]=(f32x4){0,0,0,0}; }

    for (int kc=0; kc<4; ++kc){
        __syncthreads();
        #pragma unroll 4
        for (int p=0;p<8;p++){
            int o = (tid>>4) + p*16;
            int c4 = (tid&15)*4;
            float4 w = *(const float4*)(w2g + (size_t)o*C2 + kc*64 + c4);
            int off = o*128 + ((c4*2) ^ ((o&7)<<4));
            uint2 v; v.x=pk2(w.x,w.y); v.y=pk2(w.z,w.w);
            *(uint2*)((char*)Wc + off) = v;
        }
        __syncthreads();
        #pragma unroll
        for (int kk=0; kk<2; ++kk){
            const int kbW = kk*64 + lg*16;
            const int kbX = kc*128 + kk*64 + lg*16;
            bf16x8 a[4], x[2];
            #pragma unroll
            for (int fi=0;fi<4;fi++){
                int row = o0 + fi*16 + lr;
                a[fi] = *(const bf16x8*)((const char*)Wc + row*128 + (kbW ^ ((row&7)<<4)));
            }
            #pragma unroll
            for (int fj=0;fj<2;fj++){
                int nr = nl0 + fj*16 + lr;
                x[fj] = *(const bf16x8*)((const char*)Xs + nr*512 + (kbX ^ ((nr&7)<<4)));
            }
            #pragma unroll
            for (int fi=0;fi<4;fi++)
                #pragma unroll
                for (int fj=0;fj<2;fj++)
                    acc[fi][fj] = __builtin_amdgcn_mfma_f32_16x16x32_bf16(a[fi], x[fj], acc[fi][fj], 0,0,0);
        }
    }
    #pragma unroll
    for (int fi=0;fi<4;fi++){
        #pragma unroll
        for (int fj=0;fj<2;fj++){
            int o = o0 + fi*16 + lg*4;
            int n = n0 + nl0 + fj*16 + lr;
            ushort4 r4 = *(const ushort4*)(fmidb + (size_t)(b*NN + n)*CC + o);
            float* op = out + ((size_t)b*CC + o)*NN + n;
            op[0*(size_t)NN] = b2f(r4.x) + acc[fi][fj].x;
            op[1*(size_t)NN] = b2f(r4.y) + acc[fi][fj].y;
            op[2*(size_t)NN] = b2f(r4.z) + acc[fi][fj].z;
            op[3*(size_t)NN] = b2f(r4.w) + acc[fi][fj].w;
        }
    }
}

extern "C" void kernel_launch(void* const* d_in, const int* in_sizes, int n_in,
                              void* d_out, int out_size, void* d_ws, size_t ws_size,
                              hipStream_t stream)
{
    const float* f      = (const float*)d_in[0];
    const float* dp     = (const float*)d_in[1];
    const int*   qidx   = (const int*)  d_in[2];
    const float* dirs   = (const float*)d_in[3];
    const float* de_w1  = (const float*)d_in[4];
    const float* de_bng = (const float*)d_in[5];
    const float* de_bnb = (const float*)d_in[6];
    const float* de_bnm = (const float*)d_in[7];
    const float* de_bnv = (const float*)d_in[8];
    const float* de_w2  = (const float*)d_in[9];
    const float* de_b2  = (const float*)d_in[10];
    const float* l_w1   = (const float*)d_in[11];
    const float* l_b1   = (const float*)d_in[12];
    const float* l_w2   = (const float*)d_in[13];
    const float* l_b2   = (const float*)d_in[14];
    const float* l_w3   = (const float*)d_in[15];
    const float* l_b3   = (const float*)d_in[16];
    const float* l_bng  = (const float*)d_in[17];
    const float* l_bnb  = (const float*)d_in[18];
    const float* l_bnm  = (const float*)d_in[19];
    const float* l_bnv  = (const float*)d_in[20];
    const float* m_w1   = (const float*)d_in[21];
    const float* m_bng  = (const float*)d_in[22];
    const float* m_bnb  = (const float*)d_in[23];
    const float* m_bnm  = (const float*)d_in[24];
    const float* m_bnv  = (const float*)d_in[25];
    const float* m_w2   = (const float*)d_in[26];

    char* ws = (char*)d_ws;
    // layout (bytes):
    //   g12   keys(B,N,256): [0,        16777216)
    //   h2    bf16(B,N,256): [0,        16777216)  (aliases g12, dead after k_gather)
    //   pe    bf16(B,N,128): [16777216, 25165824)
    //   f3t   bf16(B,N,128): [25165824, 33554432)
    //   fmidb bf16(B,N,128): [33554432, 41943040)
    unsigned short* g12   = (unsigned short*)(ws + 0);
    unsigned short* h2    = (unsigned short*)(ws + 0);
    unsigned short* pe    = (unsigned short*)(ws + 16777216);
    unsigned short* f3t   = (unsigned short*)(ws + 25165824);
    unsigned short* fmidb = (unsigned short*)(ws + 33554432);

    k_pe<<<dim3(512), dim3(256), 0, stream>>>(dp, dirs, de_w1, de_bng, de_bnb, de_bnm, de_bnv,
                                              de_w2, de_b2, pe);
    k_lin3<<<dim3(512), dim3(256), 0, stream>>>(f, l_w1, l_b1, l_w2, l_b2, l_w3, l_b3, g12, f3t);
    k_gather<<<dim3(8192), dim3(256), 0, stream>>>(f, qidx, g12, f3t, pe,
                                                   l_bng, l_bnb, l_bnm, l_bnv, fmidb);
    k_h2<<<dim3(512,2), dim3(256), 0, stream>>>(fmidb, m_w1, m_bng, m_bnb, m_bnm, m_bnv, h2);
    k_out<<<dim3(512), dim3(256), 0, stream>>>(h2, fmidb, m_w2, (float*)d_out);
}

// Round 7
// 90.725 us; speedup vs baseline: 1.2780x; 1.0749x over previous
//
#include <hip/hip_runtime.h>
#include <hip/hip_bf16.h>
#include <cstdint>
#include <cstddef>

#define BB 4
#define CC 128
#define NN 8192
#define KK 16
#define HH 64
#define MM 32
#define C2 256

typedef __attribute__((ext_vector_type(8))) short bf16x8;
typedef __attribute__((ext_vector_type(4))) float f32x4;
typedef unsigned short u16x2v __attribute__((ext_vector_type(2)));
typedef unsigned int u32x2 __attribute__((ext_vector_type(2)));
typedef unsigned int u32x4 __attribute__((ext_vector_type(4)));

__device__ __forceinline__ unsigned short f2bf(float f){
    unsigned int x = __float_as_uint(f);
    x += 0x7fffu + ((x >> 16) & 1u);
    return (unsigned short)(x >> 16);
}
__device__ __forceinline__ unsigned int pk2(float a, float b){
    return (unsigned int)f2bf(a) | ((unsigned int)f2bf(b) << 16);
}
__device__ __forceinline__ float lo16(unsigned int u){ return __uint_as_float(u << 16); }
__device__ __forceinline__ float hi16(unsigned int u){ return __uint_as_float(u & 0xffff0000u); }
__device__ __forceinline__ float b2f(unsigned short u){ return __uint_as_float((unsigned int)u << 16); }
__device__ __forceinline__ float gelu(float a){
    return 0.5f*a*(1.0f+erff(a*0.7071067811865475f));
}
// monotone key transform: unsigned 16-bit compare on keys == float compare on bf16
__device__ __forceinline__ unsigned int bf2key(unsigned int v){
    unsigned int neg = (v >> 15) & 0x10001u;
    return v ^ (0x80008000u | neg * 0x7FFFu);
}
__device__ __forceinline__ unsigned int key2bf(unsigned int k){
    unsigned int pos = (~k >> 15) & 0x10001u;
    return k ^ (0x80008000u | pos * 0x7FFFu);
}
// batch-affinity XCD remap: XCD pair {2b,2b+1} owns batch b.
__device__ __forceinline__ void xcd_remap(int bid, int& b, int& tile){
    int xcd = bid & 7;
    b = xcd >> 1;
    tile = (bid >> 3) * 2 + (xcd & 1);
}

// ---------------- K1: pe path, fused MFMA version ---------------------------
__global__ __launch_bounds__(256) void k_pe(
    const float* __restrict__ dp, const float* __restrict__ dirs,
    const float* __restrict__ w1,
    const float* __restrict__ bng, const float* __restrict__ bnb,
    const float* __restrict__ bnm, const float* __restrict__ bnv,
    const float* __restrict__ w2, const float* __restrict__ b2,
    unsigned short* __restrict__ pe)
{
    __shared__ float s_dx[MM], s_dy[MM], s_dz[MM];
    __shared__ alignas(16) float dnx[64*16], dny[64*16], dnz[64*16];
    __shared__ alignas(16) unsigned short th[64*32];
    __shared__ alignas(16) unsigned short ws1[64*32];
    __shared__ alignas(16) unsigned short hs[64*64];
    __shared__ alignas(16) unsigned short ws2[128*64];
    __shared__ float s_sc[HH], s_sh[HH], s_b2[CC];

    const int tid = threadIdx.x;
    int b, tile; xcd_remap(blockIdx.x, b, tile);
    const int n0 = tile * 64;

    if (tid < MM){
        float x=dirs[tid*3+0], y=dirs[tid*3+1], z=dirs[tid*3+2];
        float inv = 1.0f / fmaxf(sqrtf(x*x+y*y+z*z), 1e-12f);
        s_dx[tid]=x*inv; s_dy[tid]=y*inv; s_dz[tid]=z*inv;
    }
    #pragma unroll
    for (int p=0;p<2;p++){
        int id = tid + p*256;
        int row = id >> 3, c4 = (id & 7)*4;
        float4 w = *(const float4*)(w1 + row*MM + c4);
        int off = row*64 + ((c4*2) ^ ((row&3)<<4));
        uint2 v; v.x = pk2(w.x,w.y); v.y = pk2(w.z,w.w);
        *(uint2*)((char*)ws1 + off) = v;
    }
    #pragma unroll
    for (int p=0;p<8;p++){
        int id = tid + p*256;
        int row = id >> 4, c4 = (id & 15)*4;
        float4 w = *(const float4*)(w2 + row*HH + c4);
        int off = row*128 + ((c4*2) ^ ((row&7)<<4));
        uint2 v; v.x = pk2(w.x,w.y); v.y = pk2(w.z,w.w);
        *(uint2*)((char*)ws2 + off) = v;
    }
    if (tid < HH){
        float sc = bng[tid] / sqrtf(bnv[tid] + 1e-5f);
        s_sc[tid]=sc; s_sh[tid]=bnb[tid]-bnm[tid]*sc;
    }
    if (tid >= 64 && tid < 192) s_b2[tid-64] = b2[tid-64];

    {
        const size_t cstride = (size_t)NN*KK;
        const float* base = dp + (size_t)b*3*cstride + (size_t)n0*KK + tid*4;
        float4 X = *(const float4*)(base);
        float4 Y = *(const float4*)(base + cstride);
        float4 Z = *(const float4*)(base + 2*cstride);
        float i0 = 1.0f/fmaxf(sqrtf(X.x*X.x+Y.x*Y.x+Z.x*Z.x),1e-12f);
        float i1 = 1.0f/fmaxf(sqrtf(X.y*X.y+Y.y*Y.y+Z.y*Z.y),1e-12f);
        float i2 = 1.0f/fmaxf(sqrtf(X.z*X.z+Y.z*Y.z+Z.z*Z.z),1e-12f);
        float i3 = 1.0f/fmaxf(sqrtf(X.w*X.w+Y.w*Y.w+Z.w*Z.w),1e-12f);
        float4 xn = {X.x*i0, X.y*i1, X.z*i2, X.w*i3};
        float4 yn = {Y.x*i0, Y.y*i1, Y.z*i2, Y.w*i3};
        float4 zn = {Z.x*i0, Z.y*i1, Z.z*i2, Z.w*i3};
        const int np = tid >> 2;
        const int off = np*64 + (((tid&3)*16) ^ ((np&3)<<4));
        *(float4*)((char*)dnx + off) = xn;
        *(float4*)((char*)dny + off) = yn;
        *(float4*)((char*)dnz + off) = zn;
    }
    __syncthreads();

    {
        const int np = tid & 63, dg = tid >> 6;
        float vx[8], vy[8], vz[8];
        #pragma unroll
        for (int d=0;d<8;d++){ vx[d]=s_dx[dg*8+d]; vy[d]=s_dy[dg*8+d]; vz[d]=s_dz[dg*8+d]; }
        float tm[8];
        #pragma unroll
        for (int d=0;d<8;d++) tm[d] = -2.0f;
        #pragma unroll
        for (int g=0;g<4;g++){
            int off = np*64 + ((g*16) ^ ((np&3)<<4));
            float4 x4 = *(const float4*)((const char*)dnx + off);
            float4 y4 = *(const float4*)((const char*)dny + off);
            float4 z4 = *(const float4*)((const char*)dnz + off);
            const float xs[4]={x4.x,x4.y,x4.z,x4.w}, ys[4]={y4.x,y4.y,y4.z,y4.w},
                        zs[4]={z4.x,z4.y,z4.z,z4.w};
            #pragma unroll
            for (int q=0;q<4;q++)
                #pragma unroll
                for (int d=0;d<8;d++)
                    tm[d] = fmaxf(tm[d], vx[d]*xs[q]+vy[d]*ys[q]+vz[d]*zs[q]);
        }
        uint4 t4; t4.x=pk2(tm[0],tm[1]); t4.y=pk2(tm[2],tm[3]);
        t4.z=pk2(tm[4],tm[5]); t4.w=pk2(tm[6],tm[7]);
        int off = np*64 + ((dg*16) ^ ((np&3)<<4));
        *(uint4*)((char*)th + off) = t4;
    }
    __syncthreads();

    const int wid = tid >> 6, lane = tid & 63;
    const int lr = lane & 15, lg = lane >> 4;

    {
        const int arow = wid*16 + lr;
        bf16x8 afr = *(const bf16x8*)((const char*)ws1 + arow*64 + ((lg*16) ^ ((arow&3)<<4)));
        f32x4 hacc[4];
        #pragma unroll
        for (int nf=0;nf<4;nf++){
            int pt = nf*16 + lr;
            bf16x8 bfr = *(const bf16x8*)((const char*)th + pt*64 + ((lg*16) ^ ((pt&3)<<4)));
            f32x4 z = {0.f,0.f,0.f,0.f};
            hacc[nf] = __builtin_amdgcn_mfma_f32_16x16x32_bf16(afr, bfr, z, 0,0,0);
        }
        #pragma unroll
        for (int nf=0;nf<4;nf++){
            int ch0 = wid*16 + lg*4;
            int pt = nf*16 + lr;
            float g0 = gelu(hacc[nf].x*s_sc[ch0+0] + s_sh[ch0+0]);
            float g1 = gelu(hacc[nf].y*s_sc[ch0+1] + s_sh[ch0+1]);
            float g2 = gelu(hacc[nf].z*s_sc[ch0+2] + s_sh[ch0+2]);
            float g3 = gelu(hacc[nf].w*s_sc[ch0+3] + s_sh[ch0+3]);
            uint2 v; v.x = pk2(g0,g1); v.y = pk2(g2,g3);
            *(uint2*)((char*)hs + pt*128 + ((ch0*2) ^ ((pt&7)<<4))) = v;
        }
    }
    __syncthreads();

    {
        f32x4 pacc[2][4];
        #pragma unroll
        for (int mi=0;mi<2;mi++)
            #pragma unroll
            for (int nf=0;nf<4;nf++) pacc[mi][nf] = (f32x4){0.f,0.f,0.f,0.f};
        #pragma unroll
        for (int ks=0;ks<2;ks++){
            bf16x8 a[2], x[4];
            #pragma unroll
            for (int mi=0;mi<2;mi++){
                int row = (wid*2+mi)*16 + lr;
                a[mi] = *(const bf16x8*)((const char*)ws2 + row*128 + ((ks*64 + lg*16) ^ ((row&7)<<4)));
            }
            #pragma unroll
            for (int nf=0;nf<4;nf++){
                int pt = nf*16 + lr;
                x[nf] = *(const bf16x8*)((const char*)hs + pt*128 + ((ks*64 + lg*16) ^ ((pt&7)<<4)));
            }
            #pragma unroll
            for (int mi=0;mi<2;mi++)
                #pragma unroll
                for (int nf=0;nf<4;nf++)
                    pacc[mi][nf] = __builtin_amdgcn_mfma_f32_16x16x32_bf16(a[mi], x[nf], pacc[mi][nf], 0,0,0);
        }
        #pragma unroll
        for (int mi=0;mi<2;mi++){
            #pragma unroll
            for (int nf=0;nf<4;nf++){
                int ch0 = (wid*2+mi)*16 + lg*4;
                int pt = nf*16 + lr;
                u32x2 v;
                v.x = pk2(pacc[mi][nf].x + s_b2[ch0+0], pacc[mi][nf].y + s_b2[ch0+1]);
                v.y = pk2(pacc[mi][nf].z + s_b2[ch0+2], pacc[mi][nf].w + s_b2[ch0+3]);
                __builtin_nontemporal_store(v, (u32x2*)(pe + (size_t)(b*NN + n0 + pt)*CC + ch0));
            }
        }
    }
}

// ---------------- K2: f1/f2/f3 MFMA GEMM + ft transpose dump ----------------
// g12 (B,N,256) KEY-transformed f1|f2; f3t, ft (B,N,128) plain bf16 (NT).
__global__ __launch_bounds__(256) void k_lin3(
    const float* __restrict__ f,
    const float* __restrict__ w1g, const float* __restrict__ b1g,
    const float* __restrict__ w2g, const float* __restrict__ b2g,
    const float* __restrict__ w3g, const float* __restrict__ b3g,
    unsigned short* __restrict__ g12, unsigned short* __restrict__ f3t,
    unsigned short* __restrict__ ft)
{
    __shared__ alignas(16) unsigned short Xs[64*128];
    __shared__ alignas(16) unsigned short Ws[128*128];
    __shared__ float s_bias[128];
    const int tid = threadIdx.x;
    int b, tile;
    xcd_remap(blockIdx.x, b, tile);
    const int n0 = tile * 64;

    {
        const int j = (tid & 15) * 4;
        #pragma unroll
        for (int p = 0; p < 2; ++p){
            const int cb = ((tid >> 4) + p*16) * 4;
            const float* src = f + ((size_t)b*CC + cb)*NN + n0 + j;
            float4 r0 = *(const float4*)(src);
            float4 r1 = *(const float4*)(src + NN);
            float4 r2 = *(const float4*)(src + 2*(size_t)NN);
            float4 r3 = *(const float4*)(src + 3*(size_t)NN);
            const float rr[4][4] = {{r0.x,r1.x,r2.x,r3.x},{r0.y,r1.y,r2.y,r3.y},
                                    {r0.z,r1.z,r2.z,r3.z},{r0.w,r1.w,r2.w,r3.w}};
            #pragma unroll
            for (int i=0;i<4;i++){
                int n = j + i;
                int off = n*256 + ((cb*2) ^ ((n&7)<<4));
                uint2 v; v.x = pk2(rr[i][0], rr[i][1]); v.y = pk2(rr[i][2], rr[i][3]);
                *(uint2*)((char*)Xs + off) = v;
            }
        }
    }
    __syncthreads();
    // dump transposed f tile to ft (bf16, n-major) — coalesced NT stores
    #pragma unroll
    for (int q=0;q<4;q++){
        int idx = tid + q*256;
        int n = idx >> 4, c8 = (idx & 15)*8;
        int off = n*256 + ((c8*2) ^ ((n&7)<<4));
        u32x4 v = *(const u32x4*)((const char*)Xs + off);
        __builtin_nontemporal_store(v, (u32x4*)(ft + (size_t)(b*NN + n0 + n)*CC + c8));
    }

    const int wid = tid >> 6, lane = tid & 63;
    const int lr = lane & 15, lg = lane >> 4;
    const int o0 = (wid >> 1) * 64;
    const int nl0 = (wid & 1) * 32;

    for (int mat = 0; mat < 3; ++mat){
        const float* Wg = (mat==0)? w1g : (mat==1)? w2g : w3g;
        const float* Bg = (mat==0)? b1g : (mat==1)? b2g : b3g;
        __syncthreads();
        #pragma unroll 4
        for (int p = 0; p < 16; ++p){
            int o = (tid >> 5) + p*8;
            int c4 = (tid & 31) * 4;
            float4 w = *(const float4*)(Wg + (size_t)o*CC + c4);
            int off = o*256 + ((c4*2) ^ ((o&7)<<4));
            uint2 v; v.x = pk2(w.x, w.y); v.y = pk2(w.z, w.w);
            *(uint2*)((char*)Ws + off) = v;
        }
        if (tid < 128) s_bias[tid] = Bg[tid];
        __syncthreads();

        f32x4 acc[4][2];
        #pragma unroll
        for (int fi=0;fi<4;fi++){
            int o = o0 + fi*16 + lg*4;
            f32x4 bi = {s_bias[o], s_bias[o+1], s_bias[o+2], s_bias[o+3]};
            acc[fi][0] = bi; acc[fi][1] = bi;
        }
        #pragma unroll
        for (int kk=0; kk<4; ++kk){
            const int kb = kk*64 + lg*16;
            bf16x8 a[4], x[2];
            #pragma unroll
            for (int fi=0;fi<4;fi++){
                int row = o0 + fi*16 + lr;
                a[fi] = *(const bf16x8*)((const char*)Ws + row*256 + (kb ^ ((row&7)<<4)));
            }
            #pragma unroll
            for (int fj=0;fj<2;fj++){
                int nr = nl0 + fj*16 + lr;
                x[fj] = *(const bf16x8*)((const char*)Xs + nr*256 + (kb ^ ((nr&7)<<4)));
            }
            #pragma unroll
            for (int fi=0;fi<4;fi++)
                #pragma unroll
                for (int fj=0;fj<2;fj++)
                    acc[fi][fj] = __builtin_amdgcn_mfma_f32_16x16x32_bf16(a[fi], x[fj], acc[fi][fj], 0,0,0);
        }
        #pragma unroll
        for (int fi=0;fi<4;fi++){
            #pragma unroll
            for (int fj=0;fj<2;fj++){
                int o = o0 + fi*16 + lg*4;
                int n = n0 + nl0 + fj*16 + lr;
                if (mat == 2){
                    u32x2 u;
                    u.x = pk2(acc[fi][fj].x, acc[fi][fj].y);
                    u.y = pk2(acc[fi][fj].z, acc[fi][fj].w);
                    __builtin_nontemporal_store(u, (u32x2*)(f3t + (size_t)(b*NN + n)*CC + o));
                } else {
                    uint2 kv;
                    kv.x = bf2key(pk2(acc[fi][fj].x, acc[fi][fj].y));
                    kv.y = bf2key(pk2(acc[fi][fj].z, acc[fi][fj].w));
                    *(uint2*)(g12 + (size_t)(b*NN + n)*C2 + mat*CC + o) = kv;  // table: keep in L2
                }
            }
        }
    }
}

// ---------------- K3: pure knn gather-max (packed u16 keys) -----------------
// reads ONLY qidx + g12; writes agg = agg1+agg2 (B,N,128) bf16 NT.
__global__ __launch_bounds__(256) void k_gather(
    const int* __restrict__ qidx,
    const unsigned short* __restrict__ g12,
    unsigned short* __restrict__ agg)
{
    const int lane = threadIdx.x & 63;
    const int wrp  = threadIdx.x >> 6;
    int b, tile;
    xcd_remap(blockIdx.x, b, tile);   // 2048 tiles (of 4 points) per batch
    const int n = tile*4 + wrp;
    const int p = b*NN + n;
    const int prow = __builtin_amdgcn_readfirstlane(p);
    const int* idxp = qidx + (size_t)prow*KK;

    uint2 sv = *(const uint2*)(g12 + (size_t)p*C2 + lane*4);   // self row (keys)

    u16x2v m0 = {0,0}, m1 = {0,0};   // key 0 == most-negative bf16
    const unsigned short* gb = g12 + (size_t)b*NN*C2 + lane*4;
    #pragma unroll
    for (int k=0;k<KK;k++){
        int j = idxp[k];
        uint2 gv = *(const uint2*)(gb + (size_t)j*C2);
        m0 = __builtin_elementwise_max(m0, __builtin_bit_cast(u16x2v, gv.x));
        m1 = __builtin_elementwise_max(m1, __builtin_bit_cast(u16x2v, gv.y));
    }
    unsigned int r0 = key2bf(__builtin_bit_cast(unsigned int, m0));
    unsigned int r1 = key2bf(__builtin_bit_cast(unsigned int, m1));
    float a0 = lo16(r0), a1 = hi16(r0), a2 = lo16(r1), a3 = hi16(r1);

    if (lane >= 32){   // f2 half: agg2 = max + self
        unsigned int s0 = key2bf(sv.x), s1 = key2bf(sv.y);
        a0 += lo16(s0); a1 += hi16(s0); a2 += lo16(s1); a3 += hi16(s1);
    }
    float c0v = a0 + __shfl_xor(a0, 32);
    float c1v = a1 + __shfl_xor(a1, 32);
    float c2v = a2 + __shfl_xor(a2, 32);
    float c3v = a3 + __shfl_xor(a3, 32);
    if (lane < 32){
        u32x2 o; o.x = pk2(c0v,c1v); o.y = pk2(c2v,c3v);
        __builtin_nontemporal_store(o, (u32x2*)(agg + (size_t)p*CC + lane*4));
    }
}

// ---------------- K4: combine + h2 = gelu(bn(m_w1 @ fmid)) ------------------
// stages fmid = ft + bn_l(agg+f3) + pe into Xs AND fmidb; jh-loop over 256 out ch.
__global__ __launch_bounds__(256) void k_h2(
    const unsigned short* __restrict__ agg,
    const unsigned short* __restrict__ ft,
    const unsigned short* __restrict__ f3t,
    const unsigned short* __restrict__ pe,
    const float* __restrict__ l_bng, const float* __restrict__ l_bnb,
    const float* __restrict__ l_bnm, const float* __restrict__ l_bnv,
    const float* __restrict__ w1g,
    const float* __restrict__ bng, const float* __restrict__ bnb,
    const float* __restrict__ bnm, const float* __restrict__ bnv,
    unsigned short* __restrict__ h2, unsigned short* __restrict__ fmidb)
{
    __shared__ alignas(16) unsigned short Xs[64*128];
    __shared__ alignas(16) unsigned short Ws[128*128];
    __shared__ float s_lsc[128], s_lsh[128];
    __shared__ float s_sc[256], s_sh[256];
    const int tid = threadIdx.x;
    int b, tile;
    xcd_remap(blockIdx.x, b, tile);
    const int n0 = tile * 64;

    if (tid < 128){
        float sc = l_bng[tid] / sqrtf(l_bnv[tid] + 1e-5f);
        s_lsc[tid] = sc; s_lsh[tid] = l_bnb[tid] - l_bnm[tid]*sc;
    }
    {
        float sc = bng[tid] / sqrtf(bnv[tid] + 1e-5f);
        s_sc[tid] = sc; s_sh[tid] = bnb[tid] - bnm[tid]*sc;
    }
    __syncthreads();

    // combine-stage: fmid tile -> Xs (swizzled) + fmidb
    #pragma unroll
    for (int q=0;q<4;q++){
        int idx = tid + q*256;
        int n = idx >> 4, c8 = (idx & 15)*8;
        size_t base = (size_t)(b*NN + n0 + n)*CC + c8;
        u32x4 av = __builtin_nontemporal_load((const u32x4*)(agg + base));
        u32x4 fv = __builtin_nontemporal_load((const u32x4*)(ft  + base));
        u32x4 f3 = __builtin_nontemporal_load((const u32x4*)(f3t + base));
        u32x4 pv = __builtin_nontemporal_load((const u32x4*)(pe  + base));
        u32x4 r;
        #pragma unroll
        for (int e=0;e<4;e++){
            int c = c8 + e*2;
            float slo = lo16(av[e]) + lo16(f3[e]);
            float shi = hi16(av[e]) + hi16(f3[e]);
            float vlo = lo16(fv[e]) + slo*s_lsc[c]   + s_lsh[c]   + lo16(pv[e]);
            float vhi = hi16(fv[e]) + shi*s_lsc[c+1] + s_lsh[c+1] + hi16(pv[e]);
            r[e] = pk2(vlo, vhi);
        }
        int off = n*256 + ((c8*2) ^ ((n&7)<<4));
        *(u32x4*)((char*)Xs + off) = r;
        *(u32x4*)(fmidb + base) = r;
    }

    const int wid = tid >> 6, lane = tid & 63;
    const int lr = lane & 15, lg = lane >> 4;
    const int o0 = (wid >> 1) * 64;
    const int nl0 = (wid & 1) * 32;

    for (int jh = 0; jh < 2; ++jh){
        __syncthreads();   // Xs ready (jh=0) / prev Ws reads done (jh=1)
        const float* Wg = w1g + (size_t)jh*128*CC;
        #pragma unroll 4
        for (int p = 0; p < 16; ++p){
            int o = (tid >> 5) + p*8;
            int c4 = (tid & 31) * 4;
            float4 w = *(const float4*)(Wg + (size_t)o*CC + c4);
            int off = o*256 + ((c4*2) ^ ((o&7)<<4));
            uint2 v; v.x = pk2(w.x, w.y); v.y = pk2(w.z, w.w);
            *(uint2*)((char*)Ws + off) = v;
        }
        __syncthreads();

        f32x4 acc[4][2];
        #pragma unroll
        for (int fi=0;fi<4;fi++){ acc[fi][0]=(f32x4){0,0,0,0}; acc[fi][1]=(f32x4){0,0,0,0}; }
        #pragma unroll
        for (int kk=0; kk<4; ++kk){
            const int kb = kk*64 + lg*16;
            bf16x8 a[4], x[2];
            #pragma unroll
            for (int fi=0;fi<4;fi++){
                int row = o0 + fi*16 + lr;
                a[fi] = *(const bf16x8*)((const char*)Ws + row*256 + (kb ^ ((row&7)<<4)));
            }
            #pragma unroll
            for (int fj=0;fj<2;fj++){
                int nr = nl0 + fj*16 + lr;
                x[fj] = *(const bf16x8*)((const char*)Xs + nr*256 + (kb ^ ((nr&7)<<4)));
            }
            #pragma unroll
            for (int fi=0;fi<4;fi++)
                #pragma unroll
                for (int fj=0;fj<2;fj++)
                    acc[fi][fj] = __builtin_amdgcn_mfma_f32_16x16x32_bf16(a[fi], x[fj], acc[fi][fj], 0,0,0);
        }
        #pragma unroll
        for (int fi=0;fi<4;fi++){
            #pragma unroll
            for (int fj=0;fj<2;fj++){
                int o = o0 + fi*16 + lg*4;
                int jo = jh*128 + o;
                int n = n0 + nl0 + fj*16 + lr;
                float v0 = gelu(acc[fi][fj].x*s_sc[jo+0] + s_sh[jo+0]);
                float v1 = gelu(acc[fi][fj].y*s_sc[jo+1] + s_sh[jo+1]);
                float v2 = gelu(acc[fi][fj].z*s_sc[jo+2] + s_sh[jo+2]);
                float v3 = gelu(acc[fi][fj].w*s_sc[jo+3] + s_sh[jo+3]);
                ushort4 u; u.x=f2bf(v0); u.y=f2bf(v1); u.z=f2bf(v2); u.w=f2bf(v3);
                *(ushort4*)(h2 + (size_t)(b*NN + n)*C2 + jo) = u;
            }
        }
    }
}

// ---------------- K5: out = fmid + m_w2 @ h2 MFMA (K=256, chunked W) --------
__global__ __launch_bounds__(256) void k_out(
    const unsigned short* __restrict__ h2,
    const unsigned short* __restrict__ fmidb,
    const float* __restrict__ w2g,
    float* __restrict__ out)
{
    __shared__ alignas(16) unsigned short Xs[64*256];
    __shared__ alignas(16) unsigned short Wc[128*64];
    const int tid = threadIdx.x;
    int b, tile;
    xcd_remap(blockIdx.x, b, tile);
    const int n0 = tile * 64;

    #pragma unroll
    for (int p=0;p<8;p++){
        int n = (tid>>5) + p*8;
        int c8 = (tid&31)*8;
        uint4 v = *(const uint4*)(h2 + (size_t)(b*NN + n0 + n)*C2 + c8);
        int off = n*512 + ((c8*2) ^ ((n&7)<<4));
        *(uint4*)((char*)Xs + off) = v;
    }

    const int wid = tid >> 6, lane = tid & 63;
    const int lr = lane & 15, lg = lane >> 4;
    const int o0 = (wid >> 1) * 64;
    const int nl0 = (wid & 1) * 32;

    f32x4 acc[4][2];
    #pragma unroll
    for (int fi=0;fi<4;fi++){ acc[fi][0]=(f32x4){0,0,0,0}; acc[fi][1]=(f32x4){0,0,0,0}; }

    for (int kc=0; kc<4; ++kc){
        __syncthreads();
        #pragma unroll 4
        for (int p=0;p<8;p++){
            int o = (tid>>4) + p*16;
            int c4 = (tid&15)*4;
            float4 w = *(const float4*)(w2g + (size_t)o*C2 + kc*64 + c4);
            int off = o*128 + ((c4*2) ^ ((o&7)<<4));
            uint2 v; v.x=pk2(w.x,w.y); v.y=pk2(w.z,w.w);
            *(uint2*)((char*)Wc + off) = v;
        }
        __syncthreads();
        #pragma unroll
        for (int kk=0; kk<2; ++kk){
            const int kbW = kk*64 + lg*16;
            const int kbX = kc*128 + kk*64 + lg*16;
            bf16x8 a[4], x[2];
            #pragma unroll
            for (int fi=0;fi<4;fi++){
                int row = o0 + fi*16 + lr;
                a[fi] = *(const bf16x8*)((const char*)Wc + row*128 + (kbW ^ ((row&7)<<4)));
            }
            #pragma unroll
            for (int fj=0;fj<2;fj++){
                int nr = nl0 + fj*16 + lr;
                x[fj] = *(const bf16x8*)((const char*)Xs + nr*512 + (kbX ^ ((nr&7)<<4)));
            }
            #pragma unroll
            for (int fi=0;fi<4;fi++)
                #pragma unroll
                for (int fj=0;fj<2;fj++)
                    acc[fi][fj] = __builtin_amdgcn_mfma_f32_16x16x32_bf16(a[fi], x[fj], acc[fi][fj], 0,0,0);
        }
    }
    #pragma unroll
    for (int fi=0;fi<4;fi++){
        #pragma unroll
        for (int fj=0;fj<2;fj++){
            int o = o0 + fi*16 + lg*4;
            int n = n0 + nl0 + fj*16 + lr;
            ushort4 r4 = *(const ushort4*)(fmidb + (size_t)(b*NN + n)*CC + o);
            float* op = out + ((size_t)b*CC + o)*NN + n;
            op[0*(size_t)NN] = b2f(r4.x) + acc[fi][fj].x;
            op[1*(size_t)NN] = b2f(r4.y) + acc[fi][fj].y;
            op[2*(size_t)NN] = b2f(r4.z) + acc[fi][fj].z;
            op[3*(size_t)NN] = b2f(r4.w) + acc[fi][fj].w;
        }
    }
}

extern "C" void kernel_launch(void* const* d_in, const int* in_sizes, int n_in,
                              void* d_out, int out_size, void* d_ws, size_t ws_size,
                              hipStream_t stream)
{
    const float* f      = (const float*)d_in[0];
    const float* dp     = (const float*)d_in[1];
    const int*   qidx   = (const int*)  d_in[2];
    const float* dirs   = (const float*)d_in[3];
    const float* de_w1  = (const float*)d_in[4];
    const float* de_bng = (const float*)d_in[5];
    const float* de_bnb = (const float*)d_in[6];
    const float* de_bnm = (const float*)d_in[7];
    const float* de_bnv = (const float*)d_in[8];
    const float* de_w2  = (const float*)d_in[9];
    const float* de_b2  = (const float*)d_in[10];
    const float* l_w1   = (const float*)d_in[11];
    const float* l_b1   = (const float*)d_in[12];
    const float* l_w2   = (const float*)d_in[13];
    const float* l_b2   = (const float*)d_in[14];
    const float* l_w3   = (const float*)d_in[15];
    const float* l_b3   = (const float*)d_in[16];
    const float* l_bng  = (const float*)d_in[17];
    const float* l_bnb  = (const float*)d_in[18];
    const float* l_bnm  = (const float*)d_in[19];
    const float* l_bnv  = (const float*)d_in[20];
    const float* m_w1   = (const float*)d_in[21];
    const float* m_bng  = (const float*)d_in[22];
    const float* m_bnb  = (const float*)d_in[23];
    const float* m_bnm  = (const float*)d_in[24];
    const float* m_bnv  = (const float*)d_in[25];
    const float* m_w2   = (const float*)d_in[26];

    char* ws = (char*)d_ws;
    // layout (bytes):
    //   g12   keys(B,N,256): [0,        16777216)
    //   h2    bf16(B,N,256): [0,        16777216)  (aliases g12; g12 dead after k_gather)
    //   agg   bf16(B,N,128): [16777216, 25165824)
    //   ft    bf16(B,N,128): [25165824, 33554432)
    //   f3t   bf16(B,N,128): [33554432, 41943040)
    //   pe    bf16(B,N,128): [41943040, 50331648)
    //   fmidb bf16(B,N,128): [50331648, 58720256)
    unsigned short* g12   = (unsigned short*)(ws + 0);
    unsigned short* h2    = (unsigned short*)(ws + 0);
    unsigned short* agg   = (unsigned short*)(ws + 16777216);
    unsigned short* ft    = (unsigned short*)(ws + 25165824);
    unsigned short* f3t   = (unsigned short*)(ws + 33554432);
    unsigned short* pe    = (unsigned short*)(ws + 41943040);
    unsigned short* fmidb = (unsigned short*)(ws + 50331648);

    k_pe<<<dim3(512), dim3(256), 0, stream>>>(dp, dirs, de_w1, de_bng, de_bnb, de_bnm, de_bnv,
                                              de_w2, de_b2, pe);
    k_lin3<<<dim3(512), dim3(256), 0, stream>>>(f, l_w1, l_b1, l_w2, l_b2, l_w3, l_b3,
                                                g12, f3t, ft);
    k_gather<<<dim3(8192), dim3(256), 0, stream>>>(qidx, g12, agg);
    k_h2<<<dim3(512), dim3(256), 0, stream>>>(agg, ft, f3t, pe,
                                              l_bng, l_bnb, l_bnm, l_bnv,
                                              m_w1, m_bng, m_bnb, m_bnm, m_bnv, h2, fmidb);
    k_out<<<dim3(512), dim3(256), 0, stream>>>(h2, fmidb, m_w2, (float*)d_out);
}

// Round 8
// 90.692 us; speedup vs baseline: 1.2784x; 1.0004x over previous
//
#include <hip/hip_runtime.h>
#include <hip/hip_bf16.h>
#include <cstdint>
#include <cstddef>

#define BB 4
#define CC 128
#define NN 8192
#define KK 16
#define HH 64
#define MM 32
#define C2 256

typedef __attribute__((ext_vector_type(8))) short bf16x8;
typedef __attribute__((ext_vector_type(4))) float f32x4;
typedef unsigned short u16x2v __attribute__((ext_vector_type(2)));
typedef unsigned int u32x2 __attribute__((ext_vector_type(2)));
typedef unsigned int u32x4 __attribute__((ext_vector_type(4)));

__device__ __forceinline__ unsigned short f2bf(float f){
    unsigned int x = __float_as_uint(f);
    x += 0x7fffu + ((x >> 16) & 1u);
    return (unsigned short)(x >> 16);
}
__device__ __forceinline__ unsigned int pk2(float a, float b){
    return (unsigned int)f2bf(a) | ((unsigned int)f2bf(b) << 16);
}
__device__ __forceinline__ float lo16(unsigned int u){ return __uint_as_float(u << 16); }
__device__ __forceinline__ float hi16(unsigned int u){ return __uint_as_float(u & 0xffff0000u); }
__device__ __forceinline__ float b2f(unsigned short u){ return __uint_as_float((unsigned int)u << 16); }
__device__ __forceinline__ float gelu(float a){
    return 0.5f*a*(1.0f+erff(a*0.7071067811865475f));
}
// monotone key transform: unsigned 16-bit compare on keys == float compare on bf16
__device__ __forceinline__ unsigned int bf2key(unsigned int v){
    unsigned int neg = (v >> 15) & 0x10001u;
    return v ^ (0x80008000u | neg * 0x7FFFu);
}
__device__ __forceinline__ unsigned int key2bf(unsigned int k){
    unsigned int pos = (~k >> 15) & 0x10001u;
    return k ^ (0x80008000u | pos * 0x7FFFu);
}
// batch-affinity XCD remap: XCD pair {2b,2b+1} owns batch b.
__device__ __forceinline__ void xcd_remap(int bid, int& b, int& tile){
    int xcd = bid & 7;
    b = xcd >> 1;
    tile = (bid >> 3) * 2 + (xcd & 1);
}

// ---------------- K1: pe path, fused MFMA version ---------------------------
__global__ __launch_bounds__(256) void k_pe(
    const float* __restrict__ dp, const float* __restrict__ dirs,
    const float* __restrict__ w1,
    const float* __restrict__ bng, const float* __restrict__ bnb,
    const float* __restrict__ bnm, const float* __restrict__ bnv,
    const float* __restrict__ w2, const float* __restrict__ b2,
    unsigned short* __restrict__ pe)
{
    __shared__ float s_dx[MM], s_dy[MM], s_dz[MM];
    __shared__ alignas(16) float dnx[64*16], dny[64*16], dnz[64*16];
    __shared__ alignas(16) unsigned short th[64*32];
    __shared__ alignas(16) unsigned short ws1[64*32];
    __shared__ alignas(16) unsigned short hs[64*64];
    __shared__ alignas(16) unsigned short ws2[128*64];
    __shared__ float s_sc[HH], s_sh[HH], s_b2[CC];

    const int tid = threadIdx.x;
    int b, tile; xcd_remap(blockIdx.x, b, tile);
    const int n0 = tile * 64;

    if (tid < MM){
        float x=dirs[tid*3+0], y=dirs[tid*3+1], z=dirs[tid*3+2];
        float inv = 1.0f / fmaxf(sqrtf(x*x+y*y+z*z), 1e-12f);
        s_dx[tid]=x*inv; s_dy[tid]=y*inv; s_dz[tid]=z*inv;
    }
    #pragma unroll
    for (int p=0;p<2;p++){
        int id = tid + p*256;
        int row = id >> 3, c4 = (id & 7)*4;
        float4 w = *(const float4*)(w1 + row*MM + c4);
        int off = row*64 + ((c4*2) ^ ((row&3)<<4));
        uint2 v; v.x = pk2(w.x,w.y); v.y = pk2(w.z,w.w);
        *(uint2*)((char*)ws1 + off) = v;
    }
    #pragma unroll
    for (int p=0;p<8;p++){
        int id = tid + p*256;
        int row = id >> 4, c4 = (id & 15)*4;
        float4 w = *(const float4*)(w2 + row*HH + c4);
        int off = row*128 + ((c4*2) ^ ((row&7)<<4));
        uint2 v; v.x = pk2(w.x,w.y); v.y = pk2(w.z,w.w);
        *(uint2*)((char*)ws2 + off) = v;
    }
    if (tid < HH){
        float sc = bng[tid] / sqrtf(bnv[tid] + 1e-5f);
        s_sc[tid]=sc; s_sh[tid]=bnb[tid]-bnm[tid]*sc;
    }
    if (tid >= 64 && tid < 192) s_b2[tid-64] = b2[tid-64];

    {
        const size_t cstride = (size_t)NN*KK;
        const float* base = dp + (size_t)b*3*cstride + (size_t)n0*KK + tid*4;
        float4 X = *(const float4*)(base);
        float4 Y = *(const float4*)(base + cstride);
        float4 Z = *(const float4*)(base + 2*cstride);
        float i0 = 1.0f/fmaxf(sqrtf(X.x*X.x+Y.x*Y.x+Z.x*Z.x),1e-12f);
        float i1 = 1.0f/fmaxf(sqrtf(X.y*X.y+Y.y*Y.y+Z.y*Z.y),1e-12f);
        float i2 = 1.0f/fmaxf(sqrtf(X.z*X.z+Y.z*Y.z+Z.z*Z.z),1e-12f);
        float i3 = 1.0f/fmaxf(sqrtf(X.w*X.w+Y.w*Y.w+Z.w*Z.w),1e-12f);
        float4 xn = {X.x*i0, X.y*i1, X.z*i2, X.w*i3};
        float4 yn = {Y.x*i0, Y.y*i1, Y.z*i2, Y.w*i3};
        float4 zn = {Z.x*i0, Z.y*i1, Z.z*i2, Z.w*i3};
        const int np = tid >> 2;
        const int off = np*64 + (((tid&3)*16) ^ ((np&3)<<4));
        *(float4*)((char*)dnx + off) = xn;
        *(float4*)((char*)dny + off) = yn;
        *(float4*)((char*)dnz + off) = zn;
    }
    __syncthreads();

    {
        const int np = tid & 63, dg = tid >> 6;
        float vx[8], vy[8], vz[8];
        #pragma unroll
        for (int d=0;d<8;d++){ vx[d]=s_dx[dg*8+d]; vy[d]=s_dy[dg*8+d]; vz[d]=s_dz[dg*8+d]; }
        float tm[8];
        #pragma unroll
        for (int d=0;d<8;d++) tm[d] = -2.0f;
        #pragma unroll
        for (int g=0;g<4;g++){
            int off = np*64 + ((g*16) ^ ((np&3)<<4));
            float4 x4 = *(const float4*)((const char*)dnx + off);
            float4 y4 = *(const float4*)((const char*)dny + off);
            float4 z4 = *(const float4*)((const char*)dnz + off);
            const float xs[4]={x4.x,x4.y,x4.z,x4.w}, ys[4]={y4.x,y4.y,y4.z,y4.w},
                        zs[4]={z4.x,z4.y,z4.z,z4.w};
            #pragma unroll
            for (int q=0;q<4;q++)
                #pragma unroll
                for (int d=0;d<8;d++)
                    tm[d] = fmaxf(tm[d], vx[d]*xs[q]+vy[d]*ys[q]+vz[d]*zs[q]);
        }
        uint4 t4; t4.x=pk2(tm[0],tm[1]); t4.y=pk2(tm[2],tm[3]);
        t4.z=pk2(tm[4],tm[5]); t4.w=pk2(tm[6],tm[7]);
        int off = np*64 + ((dg*16) ^ ((np&3)<<4));
        *(uint4*)((char*)th + off) = t4;
    }
    __syncthreads();

    const int wid = tid >> 6, lane = tid & 63;
    const int lr = lane & 15, lg = lane >> 4;

    {
        const int arow = wid*16 + lr;
        bf16x8 afr = *(const bf16x8*)((const char*)ws1 + arow*64 + ((lg*16) ^ ((arow&3)<<4)));
        f32x4 hacc[4];
        #pragma unroll
        for (int nf=0;nf<4;nf++){
            int pt = nf*16 + lr;
            bf16x8 bfr = *(const bf16x8*)((const char*)th + pt*64 + ((lg*16) ^ ((pt&3)<<4)));
            f32x4 z = {0.f,0.f,0.f,0.f};
            hacc[nf] = __builtin_amdgcn_mfma_f32_16x16x32_bf16(afr, bfr, z, 0,0,0);
        }
        #pragma unroll
        for (int nf=0;nf<4;nf++){
            int ch0 = wid*16 + lg*4;
            int pt = nf*16 + lr;
            float g0 = gelu(hacc[nf].x*s_sc[ch0+0] + s_sh[ch0+0]);
            float g1 = gelu(hacc[nf].y*s_sc[ch0+1] + s_sh[ch0+1]);
            float g2 = gelu(hacc[nf].z*s_sc[ch0+2] + s_sh[ch0+2]);
            float g3 = gelu(hacc[nf].w*s_sc[ch0+3] + s_sh[ch0+3]);
            uint2 v; v.x = pk2(g0,g1); v.y = pk2(g2,g3);
            *(uint2*)((char*)hs + pt*128 + ((ch0*2) ^ ((pt&7)<<4))) = v;
        }
    }
    __syncthreads();

    {
        f32x4 pacc[2][4];
        #pragma unroll
        for (int mi=0;mi<2;mi++)
            #pragma unroll
            for (int nf=0;nf<4;nf++) pacc[mi][nf] = (f32x4){0.f,0.f,0.f,0.f};
        #pragma unroll
        for (int ks=0;ks<2;ks++){
            bf16x8 a[2], x[4];
            #pragma unroll
            for (int mi=0;mi<2;mi++){
                int row = (wid*2+mi)*16 + lr;
                a[mi] = *(const bf16x8*)((const char*)ws2 + row*128 + ((ks*64 + lg*16) ^ ((row&7)<<4)));
            }
            #pragma unroll
            for (int nf=0;nf<4;nf++){
                int pt = nf*16 + lr;
                x[nf] = *(const bf16x8*)((const char*)hs + pt*128 + ((ks*64 + lg*16) ^ ((pt&7)<<4)));
            }
            #pragma unroll
            for (int mi=0;mi<2;mi++)
                #pragma unroll
                for (int nf=0;nf<4;nf++)
                    pacc[mi][nf] = __builtin_amdgcn_mfma_f32_16x16x32_bf16(a[mi], x[nf], pacc[mi][nf], 0,0,0);
        }
        #pragma unroll
        for (int mi=0;mi<2;mi++){
            #pragma unroll
            for (int nf=0;nf<4;nf++){
                int ch0 = (wid*2+mi)*16 + lg*4;
                int pt = nf*16 + lr;
                u32x2 v;
                v.x = pk2(pacc[mi][nf].x + s_b2[ch0+0], pacc[mi][nf].y + s_b2[ch0+1]);
                v.y = pk2(pacc[mi][nf].z + s_b2[ch0+2], pacc[mi][nf].w + s_b2[ch0+3]);
                __builtin_nontemporal_store(v, (u32x2*)(pe + (size_t)(b*NN + n0 + pt)*CC + ch0));
            }
        }
    }
}

// ---------------- K2: f1/f2/f3 MFMA GEMM + ft transpose dump ----------------
__global__ __launch_bounds__(256) void k_lin3(
    const float* __restrict__ f,
    const float* __restrict__ w1g, const float* __restrict__ b1g,
    const float* __restrict__ w2g, const float* __restrict__ b2g,
    const float* __restrict__ w3g, const float* __restrict__ b3g,
    unsigned short* __restrict__ g12, unsigned short* __restrict__ f3t,
    unsigned short* __restrict__ ft)
{
    __shared__ alignas(16) unsigned short Xs[64*128];
    __shared__ alignas(16) unsigned short Ws[128*128];
    __shared__ float s_bias[128];
    const int tid = threadIdx.x;
    int b, tile;
    xcd_remap(blockIdx.x, b, tile);
    const int n0 = tile * 64;

    {
        const int j = (tid & 15) * 4;
        #pragma unroll
        for (int p = 0; p < 2; ++p){
            const int cb = ((tid >> 4) + p*16) * 4;
            const float* src = f + ((size_t)b*CC + cb)*NN + n0 + j;
            float4 r0 = *(const float4*)(src);
            float4 r1 = *(const float4*)(src + NN);
            float4 r2 = *(const float4*)(src + 2*(size_t)NN);
            float4 r3 = *(const float4*)(src + 3*(size_t)NN);
            const float rr[4][4] = {{r0.x,r1.x,r2.x,r3.x},{r0.y,r1.y,r2.y,r3.y},
                                    {r0.z,r1.z,r2.z,r3.z},{r0.w,r1.w,r2.w,r3.w}};
            #pragma unroll
            for (int i=0;i<4;i++){
                int n = j + i;
                int off = n*256 + ((cb*2) ^ ((n&7)<<4));
                uint2 v; v.x = pk2(rr[i][0], rr[i][1]); v.y = pk2(rr[i][2], rr[i][3]);
                *(uint2*)((char*)Xs + off) = v;
            }
        }
    }
    __syncthreads();
    // dump transposed f tile to ft (bf16, n-major) — coalesced NT stores
    #pragma unroll
    for (int q=0;q<4;q++){
        int idx = tid + q*256;
        int n = idx >> 4, c8 = (idx & 15)*8;
        int off = n*256 + ((c8*2) ^ ((n&7)<<4));
        u32x4 v = *(const u32x4*)((const char*)Xs + off);
        __builtin_nontemporal_store(v, (u32x4*)(ft + (size_t)(b*NN + n0 + n)*CC + c8));
    }

    const int wid = tid >> 6, lane = tid & 63;
    const int lr = lane & 15, lg = lane >> 4;
    const int o0 = (wid >> 1) * 64;
    const int nl0 = (wid & 1) * 32;

    for (int mat = 0; mat < 3; ++mat){
        const float* Wg = (mat==0)? w1g : (mat==1)? w2g : w3g;
        const float* Bg = (mat==0)? b1g : (mat==1)? b2g : b3g;
        __syncthreads();
        #pragma unroll 4
        for (int p = 0; p < 16; ++p){
            int o = (tid >> 5) + p*8;
            int c4 = (tid & 31) * 4;
            float4 w = *(const float4*)(Wg + (size_t)o*CC + c4);
            int off = o*256 + ((c4*2) ^ ((o&7)<<4));
            uint2 v; v.x = pk2(w.x, w.y); v.y = pk2(w.z, w.w);
            *(uint2*)((char*)Ws + off) = v;
        }
        if (tid < 128) s_bias[tid] = Bg[tid];
        __syncthreads();

        f32x4 acc[4][2];
        #pragma unroll
        for (int fi=0;fi<4;fi++){
            int o = o0 + fi*16 + lg*4;
            f32x4 bi = {s_bias[o], s_bias[o+1], s_bias[o+2], s_bias[o+3]};
            acc[fi][0] = bi; acc[fi][1] = bi;
        }
        #pragma unroll
        for (int kk=0; kk<4; ++kk){
            const int kb = kk*64 + lg*16;
            bf16x8 a[4], x[2];
            #pragma unroll
            for (int fi=0;fi<4;fi++){
                int row = o0 + fi*16 + lr;
                a[fi] = *(const bf16x8*)((const char*)Ws + row*256 + (kb ^ ((row&7)<<4)));
            }
            #pragma unroll
            for (int fj=0;fj<2;fj++){
                int nr = nl0 + fj*16 + lr;
                x[fj] = *(const bf16x8*)((const char*)Xs + nr*256 + (kb ^ ((nr&7)<<4)));
            }
            #pragma unroll
            for (int fi=0;fi<4;fi++)
                #pragma unroll
                for (int fj=0;fj<2;fj++)
                    acc[fi][fj] = __builtin_amdgcn_mfma_f32_16x16x32_bf16(a[fi], x[fj], acc[fi][fj], 0,0,0);
        }
        #pragma unroll
        for (int fi=0;fi<4;fi++){
            #pragma unroll
            for (int fj=0;fj<2;fj++){
                int o = o0 + fi*16 + lg*4;
                int n = n0 + nl0 + fj*16 + lr;
                if (mat == 2){
                    u32x2 u;
                    u.x = pk2(acc[fi][fj].x, acc[fi][fj].y);
                    u.y = pk2(acc[fi][fj].z, acc[fi][fj].w);
                    __builtin_nontemporal_store(u, (u32x2*)(f3t + (size_t)(b*NN + n)*CC + o));
                } else {
                    uint2 kv;
                    kv.x = bf2key(pk2(acc[fi][fj].x, acc[fi][fj].y));
                    kv.y = bf2key(pk2(acc[fi][fj].z, acc[fi][fj].w));
                    *(uint2*)(g12 + (size_t)(b*NN + n)*C2 + mat*CC + o) = kv;  // table: keep in L2
                }
            }
        }
    }
}

// ---------------- K3: fused gather + combine + h2 + out ---------------------
// per 64-pt tile: gather->fmid(Xs LDS); h2 half in Hs per jh; out accumulated.
__global__ __launch_bounds__(256) void k_tail(
    const int* __restrict__ qidx,
    const unsigned short* __restrict__ g12,
    const unsigned short* __restrict__ ft,
    const unsigned short* __restrict__ f3t,
    const unsigned short* __restrict__ pe,
    const float* __restrict__ l_bng, const float* __restrict__ l_bnb,
    const float* __restrict__ l_bnm, const float* __restrict__ l_bnv,
    const float* __restrict__ w1g,
    const float* __restrict__ bng, const float* __restrict__ bnb,
    const float* __restrict__ bnm, const float* __restrict__ bnv,
    const float* __restrict__ w2g,
    float* __restrict__ out)
{
    __shared__ alignas(16) unsigned short Xs[64*128];   // fmid tile [n][c]
    __shared__ alignas(16) unsigned short Ws[128*128];  // m_w1 half / m_w2 half
    __shared__ alignas(16) unsigned short Hs[64*128];   // h2 half  [n][jo_local]
    __shared__ float s_lsc[128], s_lsh[128];
    __shared__ float s_msc[256], s_msh[256];
    const int tid = threadIdx.x;
    int b, tile;
    xcd_remap(blockIdx.x, b, tile);
    const int n0 = tile * 64;

    if (tid < 128){
        float sc = l_bng[tid] / sqrtf(l_bnv[tid] + 1e-5f);
        s_lsc[tid] = sc; s_lsh[tid] = l_bnb[tid] - l_bnm[tid]*sc;
    }
    {
        float sc = bng[tid] / sqrtf(bnv[tid] + 1e-5f);
        s_msc[tid] = sc; s_msh[tid] = bnb[tid] - bnm[tid]*sc;
    }
    __syncthreads();

    const int lane = tid & 63, wrp = tid >> 6;
    // ---- gather + combine: each wave owns 16 points ----
    {
        const unsigned short* gb = g12 + (size_t)b*NN*C2 + lane*4;
        for (int it = 0; it < 16; ++it){
            const int pt = wrp*16 + it;
            const int p = b*NN + n0 + pt;
            const int prow = __builtin_amdgcn_readfirstlane(p);
            const int* idxp = qidx + (size_t)prow*KK;
            uint2 sv = *(const uint2*)(g12 + (size_t)p*C2 + lane*4);
            u16x2v m0 = {0,0}, m1 = {0,0};
            #pragma unroll
            for (int k=0;k<KK;k++){
                int j = idxp[k];
                uint2 gv = *(const uint2*)(gb + (size_t)j*C2);
                m0 = __builtin_elementwise_max(m0, __builtin_bit_cast(u16x2v, gv.x));
                m1 = __builtin_elementwise_max(m1, __builtin_bit_cast(u16x2v, gv.y));
            }
            unsigned int r0 = key2bf(__builtin_bit_cast(unsigned int, m0));
            unsigned int r1 = key2bf(__builtin_bit_cast(unsigned int, m1));
            float a0 = lo16(r0), a1 = hi16(r0), a2 = lo16(r1), a3 = hi16(r1);
            if (lane >= 32){   // f2 half: agg2 = max + self
                unsigned int s0 = key2bf(sv.x), s1 = key2bf(sv.y);
                a0 += lo16(s0); a1 += hi16(s0); a2 += lo16(s1); a3 += hi16(s1);
            }
            float c0v = a0 + __shfl_xor(a0, 32);
            float c1v = a1 + __shfl_xor(a1, 32);
            float c2v = a2 + __shfl_xor(a2, 32);
            float c3v = a3 + __shfl_xor(a3, 32);
            if (lane < 32){
                const int c = lane*4;
                size_t base = (size_t)p*CC + c;
                u32x2 fv = __builtin_nontemporal_load((const u32x2*)(ft  + base));
                u32x2 f3 = __builtin_nontemporal_load((const u32x2*)(f3t + base));
                u32x2 pv = __builtin_nontemporal_load((const u32x2*)(pe  + base));
                float s0v = c0v + lo16(f3.x), s1v = c1v + hi16(f3.x);
                float s2v = c2v + lo16(f3.y), s3v = c3v + hi16(f3.y);
                float v0 = lo16(fv.x) + s0v*s_lsc[c+0] + s_lsh[c+0] + lo16(pv.x);
                float v1 = hi16(fv.x) + s1v*s_lsc[c+1] + s_lsh[c+1] + hi16(pv.x);
                float v2 = lo16(fv.y) + s2v*s_lsc[c+2] + s_lsh[c+2] + lo16(pv.y);
                float v3 = hi16(fv.y) + s3v*s_lsc[c+3] + s_lsh[c+3] + hi16(pv.y);
                u32x2 r; r.x = pk2(v0,v1); r.y = pk2(v2,v3);
                *(u32x2*)((char*)Xs + pt*256 + ((c*2) ^ ((pt&7)<<4))) = r;
            }
        }
    }

    const int lr = lane & 15, lg = lane >> 4;
    const int o0 = (wrp >> 1) * 64;
    const int nl0 = (wrp & 1) * 32;

    f32x4 oacc[4][2];
    #pragma unroll
    for (int fi=0;fi<4;fi++){ oacc[fi][0]=(f32x4){0,0,0,0}; oacc[fi][1]=(f32x4){0,0,0,0}; }

    for (int jh = 0; jh < 2; ++jh){
        __syncthreads();   // Xs ready (jh=0) / Hs+Ws consumed by prev phase-O
        // stage m_w1 half
        {
            const float* Wg = w1g + (size_t)jh*128*CC;
            #pragma unroll 4
            for (int p = 0; p < 16; ++p){
                int o = (tid >> 5) + p*8;
                int c4 = (tid & 31) * 4;
                float4 w = *(const float4*)(Wg + (size_t)o*CC + c4);
                int off = o*256 + ((c4*2) ^ ((o&7)<<4));
                uint2 v; v.x = pk2(w.x, w.y); v.y = pk2(w.z, w.w);
                *(uint2*)((char*)Ws + off) = v;
            }
        }
        __syncthreads();
        // h2 half = gelu(bn(m_w1_half @ fmid))
        {
            f32x4 hacc[4][2];
            #pragma unroll
            for (int fi=0;fi<4;fi++){ hacc[fi][0]=(f32x4){0,0,0,0}; hacc[fi][1]=(f32x4){0,0,0,0}; }
            #pragma unroll
            for (int kk=0; kk<4; ++kk){
                const int kb = kk*64 + lg*16;
                bf16x8 a[4], x[2];
                #pragma unroll
                for (int fi=0;fi<4;fi++){
                    int row = o0 + fi*16 + lr;
                    a[fi] = *(const bf16x8*)((const char*)Ws + row*256 + (kb ^ ((row&7)<<4)));
                }
                #pragma unroll
                for (int fj=0;fj<2;fj++){
                    int nr = nl0 + fj*16 + lr;
                    x[fj] = *(const bf16x8*)((const char*)Xs + nr*256 + (kb ^ ((nr&7)<<4)));
                }
                #pragma unroll
                for (int fi=0;fi<4;fi++)
                    #pragma unroll
                    for (int fj=0;fj<2;fj++)
                        hacc[fi][fj] = __builtin_amdgcn_mfma_f32_16x16x32_bf16(a[fi], x[fj], hacc[fi][fj], 0,0,0);
            }
            #pragma unroll
            for (int fi=0;fi<4;fi++){
                #pragma unroll
                for (int fj=0;fj<2;fj++){
                    int o = o0 + fi*16 + lg*4;
                    int jo = jh*128 + o;
                    int nl = nl0 + fj*16 + lr;
                    float v0 = gelu(hacc[fi][fj].x*s_msc[jo+0] + s_msh[jo+0]);
                    float v1 = gelu(hacc[fi][fj].y*s_msc[jo+1] + s_msh[jo+1]);
                    float v2 = gelu(hacc[fi][fj].z*s_msc[jo+2] + s_msh[jo+2]);
                    float v3 = gelu(hacc[fi][fj].w*s_msc[jo+3] + s_msh[jo+3]);
                    u32x2 v; v.x = pk2(v0,v1); v.y = pk2(v2,v3);
                    *(u32x2*)((char*)Hs + nl*256 + ((o*2) ^ ((nl&7)<<4))) = v;
                }
            }
        }
        __syncthreads();   // Hs ready; Ws reads done
        // stage m_w2 half: Wc[o][ck] = w2g[o*C2 + jh*128 + ck]
        {
            #pragma unroll 4
            for (int p = 0; p < 16; ++p){
                int o = (tid >> 5) + p*8;
                int c4 = (tid & 31) * 4;
                float4 w = *(const float4*)(w2g + (size_t)o*C2 + jh*128 + c4);
                int off = o*256 + ((c4*2) ^ ((o&7)<<4));
                uint2 v; v.x = pk2(w.x, w.y); v.y = pk2(w.z, w.w);
                *(uint2*)((char*)Ws + off) = v;
            }
        }
        __syncthreads();
        // out += m_w2_half @ h2_half
        #pragma unroll
        for (int kk=0; kk<4; ++kk){
            const int kb = kk*64 + lg*16;
            bf16x8 a[4], x[2];
            #pragma unroll
            for (int fi=0;fi<4;fi++){
                int row = o0 + fi*16 + lr;
                a[fi] = *(const bf16x8*)((const char*)Ws + row*256 + (kb ^ ((row&7)<<4)));
            }
            #pragma unroll
            for (int fj=0;fj<2;fj++){
                int nr = nl0 + fj*16 + lr;
                x[fj] = *(const bf16x8*)((const char*)Hs + nr*256 + (kb ^ ((nr&7)<<4)));
            }
            #pragma unroll
            for (int fi=0;fi<4;fi++)
                #pragma unroll
                for (int fj=0;fj<2;fj++)
                    oacc[fi][fj] = __builtin_amdgcn_mfma_f32_16x16x32_bf16(a[fi], x[fj], oacc[fi][fj], 0,0,0);
        }
    }
    // epilogue: out = fmid(Xs) + oacc
    #pragma unroll
    for (int fi=0;fi<4;fi++){
        #pragma unroll
        for (int fj=0;fj<2;fj++){
            int o = o0 + fi*16 + lg*4;
            int nl = nl0 + fj*16 + lr;
            int n = n0 + nl;
            u32x2 fm = *(const u32x2*)((const char*)Xs + nl*256 + ((o*2) ^ ((nl&7)<<4)));
            float* op = out + ((size_t)b*CC + o)*NN + n;
            op[0*(size_t)NN] = lo16(fm.x) + oacc[fi][fj].x;
            op[1*(size_t)NN] = hi16(fm.x) + oacc[fi][fj].y;
            op[2*(size_t)NN] = lo16(fm.y) + oacc[fi][fj].z;
            op[3*(size_t)NN] = hi16(fm.y) + oacc[fi][fj].w;
        }
    }
}

extern "C" void kernel_launch(void* const* d_in, const int* in_sizes, int n_in,
                              void* d_out, int out_size, void* d_ws, size_t ws_size,
                              hipStream_t stream)
{
    const float* f      = (const float*)d_in[0];
    const float* dp     = (const float*)d_in[1];
    const int*   qidx   = (const int*)  d_in[2];
    const float* dirs   = (const float*)d_in[3];
    const float* de_w1  = (const float*)d_in[4];
    const float* de_bng = (const float*)d_in[5];
    const float* de_bnb = (const float*)d_in[6];
    const float* de_bnm = (const float*)d_in[7];
    const float* de_bnv = (const float*)d_in[8];
    const float* de_w2  = (const float*)d_in[9];
    const float* de_b2  = (const float*)d_in[10];
    const float* l_w1   = (const float*)d_in[11];
    const float* l_b1   = (const float*)d_in[12];
    const float* l_w2   = (const float*)d_in[13];
    const float* l_b2   = (const float*)d_in[14];
    const float* l_w3   = (const float*)d_in[15];
    const float* l_b3   = (const float*)d_in[16];
    const float* l_bng  = (const float*)d_in[17];
    const float* l_bnb  = (const float*)d_in[18];
    const float* l_bnm  = (const float*)d_in[19];
    const float* l_bnv  = (const float*)d_in[20];
    const float* m_w1   = (const float*)d_in[21];
    const float* m_bng  = (const float*)d_in[22];
    const float* m_bnb  = (const float*)d_in[23];
    const float* m_bnm  = (const float*)d_in[24];
    const float* m_bnv  = (const float*)d_in[25];
    const float* m_w2   = (const float*)d_in[26];

    char* ws = (char*)d_ws;
    // layout (bytes):
    //   g12   keys(B,N,256): [0,        16777216)
    //   ft    bf16(B,N,128): [16777216, 25165824)
    //   f3t   bf16(B,N,128): [25165824, 33554432)
    //   pe    bf16(B,N,128): [33554432, 41943040)
    unsigned short* g12   = (unsigned short*)(ws + 0);
    unsigned short* ft    = (unsigned short*)(ws + 16777216);
    unsigned short* f3t   = (unsigned short*)(ws + 25165824);
    unsigned short* pe    = (unsigned short*)(ws + 33554432);

    k_pe<<<dim3(512), dim3(256), 0, stream>>>(dp, dirs, de_w1, de_bng, de_bnb, de_bnm, de_bnv,
                                              de_w2, de_b2, pe);
    k_lin3<<<dim3(512), dim3(256), 0, stream>>>(f, l_w1, l_b1, l_w2, l_b2, l_w3, l_b3,
                                                g12, f3t, ft);
    k_tail<<<dim3(512), dim3(256), 0, stream>>>(qidx, g12, ft, f3t, pe,
                                                l_bng, l_bnb, l_bnm, l_bnv,
                                                m_w1, m_bng, m_bnb, m_bnm, m_bnv,
                                                m_w2, (float*)d_out);
}

// Round 9
// 77.866 us; speedup vs baseline: 1.4890x; 1.1647x over previous
//
#include <hip/hip_runtime.h>
#include <hip/hip_bf16.h>
#include <cstdint>
#include <cstddef>

#define BB 4
#define CC 128
#define NN 8192
#define KK 16
#define HH 64
#define MM 32
#define C2 256

typedef __attribute__((ext_vector_type(8))) short bf16x8;
typedef __attribute__((ext_vector_type(4))) float f32x4;
typedef unsigned short u16x2v __attribute__((ext_vector_type(2)));
typedef unsigned int u32x2 __attribute__((ext_vector_type(2)));
typedef unsigned int u32x4 __attribute__((ext_vector_type(4)));

__device__ __forceinline__ unsigned short f2bf(float f){
    unsigned int x = __float_as_uint(f);
    x += 0x7fffu + ((x >> 16) & 1u);
    return (unsigned short)(x >> 16);
}
__device__ __forceinline__ unsigned int pk2(float a, float b){
    return (unsigned int)f2bf(a) | ((unsigned int)f2bf(b) << 16);
}
__device__ __forceinline__ float lo16(unsigned int u){ return __uint_as_float(u << 16); }
__device__ __forceinline__ float hi16(unsigned int u){ return __uint_as_float(u & 0xffff0000u); }
__device__ __forceinline__ float gelu(float a){
    return 0.5f*a*(1.0f+erff(a*0.7071067811865475f));
}
// monotone key transform: unsigned 16-bit compare on keys == float compare on bf16
__device__ __forceinline__ unsigned int bf2key(unsigned int v){
    unsigned int neg = (v >> 15) & 0x10001u;
    return v ^ (0x80008000u | neg * 0x7FFFu);
}
__device__ __forceinline__ unsigned int key2bf(unsigned int k){
    unsigned int pos = (~k >> 15) & 0x10001u;
    return k ^ (0x80008000u | pos * 0x7FFFu);
}
__device__ __forceinline__ unsigned int pkmax(unsigned int a, unsigned int b){
    u16x2v r = __builtin_elementwise_max(__builtin_bit_cast(u16x2v, a),
                                         __builtin_bit_cast(u16x2v, b));
    return __builtin_bit_cast(unsigned int, r);
}
// batch-affinity XCD remap: XCD pair {2b,2b+1} owns batch b.
__device__ __forceinline__ void xcd_remap(int bid, int& b, int& tile){
    int xcd = bid & 7;
    b = xcd >> 1;
    tile = (bid >> 3) * 2 + (xcd & 1);
}

// ---------------- K1: pe path, fused MFMA version ---------------------------
__global__ __launch_bounds__(256) void k_pe(
    const float* __restrict__ dp, const float* __restrict__ dirs,
    const float* __restrict__ w1,
    const float* __restrict__ bng, const float* __restrict__ bnb,
    const float* __restrict__ bnm, const float* __restrict__ bnv,
    const float* __restrict__ w2, const float* __restrict__ b2,
    unsigned short* __restrict__ pe)
{
    __shared__ float s_dx[MM], s_dy[MM], s_dz[MM];
    __shared__ alignas(16) float dnx[64*16], dny[64*16], dnz[64*16];
    __shared__ alignas(16) unsigned short th[64*32];
    __shared__ alignas(16) unsigned short ws1[64*32];
    __shared__ alignas(16) unsigned short hs[64*64];
    __shared__ alignas(16) unsigned short ws2[128*64];
    __shared__ float s_sc[HH], s_sh[HH], s_b2[CC];

    const int tid = threadIdx.x;
    int b, tile; xcd_remap(blockIdx.x, b, tile);
    const int n0 = tile * 64;

    if (tid < MM){
        float x=dirs[tid*3+0], y=dirs[tid*3+1], z=dirs[tid*3+2];
        float inv = 1.0f / fmaxf(sqrtf(x*x+y*y+z*z), 1e-12f);
        s_dx[tid]=x*inv; s_dy[tid]=y*inv; s_dz[tid]=z*inv;
    }
    #pragma unroll
    for (int p=0;p<2;p++){
        int id = tid + p*256;
        int row = id >> 3, c4 = (id & 7)*4;
        float4 w = *(const float4*)(w1 + row*MM + c4);
        int off = row*64 + ((c4*2) ^ ((row&3)<<4));
        uint2 v; v.x = pk2(w.x,w.y); v.y = pk2(w.z,w.w);
        *(uint2*)((char*)ws1 + off) = v;
    }
    #pragma unroll
    for (int p=0;p<8;p++){
        int id = tid + p*256;
        int row = id >> 4, c4 = (id & 15)*4;
        float4 w = *(const float4*)(w2 + row*HH + c4);
        int off = row*128 + ((c4*2) ^ ((row&7)<<4));
        uint2 v; v.x = pk2(w.x,w.y); v.y = pk2(w.z,w.w);
        *(uint2*)((char*)ws2 + off) = v;
    }
    if (tid < HH){
        float sc = bng[tid] / sqrtf(bnv[tid] + 1e-5f);
        s_sc[tid]=sc; s_sh[tid]=bnb[tid]-bnm[tid]*sc;
    }
    if (tid >= 64 && tid < 192) s_b2[tid-64] = b2[tid-64];

    {
        const size_t cstride = (size_t)NN*KK;
        const float* base = dp + (size_t)b*3*cstride + (size_t)n0*KK + tid*4;
        float4 X = *(const float4*)(base);
        float4 Y = *(const float4*)(base + cstride);
        float4 Z = *(const float4*)(base + 2*cstride);
        float i0 = 1.0f/fmaxf(sqrtf(X.x*X.x+Y.x*Y.x+Z.x*Z.x),1e-12f);
        float i1 = 1.0f/fmaxf(sqrtf(X.y*X.y+Y.y*Y.y+Z.y*Z.y),1e-12f);
        float i2 = 1.0f/fmaxf(sqrtf(X.z*X.z+Y.z*Y.z+Z.z*Z.z),1e-12f);
        float i3 = 1.0f/fmaxf(sqrtf(X.w*X.w+Y.w*Y.w+Z.w*Z.w),1e-12f);
        float4 xn = {X.x*i0, X.y*i1, X.z*i2, X.w*i3};
        float4 yn = {Y.x*i0, Y.y*i1, Y.z*i2, Y.w*i3};
        float4 zn = {Z.x*i0, Z.y*i1, Z.z*i2, Z.w*i3};
        const int np = tid >> 2;
        const int off = np*64 + (((tid&3)*16) ^ ((np&3)<<4));
        *(float4*)((char*)dnx + off) = xn;
        *(float4*)((char*)dny + off) = yn;
        *(float4*)((char*)dnz + off) = zn;
    }
    __syncthreads();

    {
        const int np = tid & 63, dg = tid >> 6;
        float vx[8], vy[8], vz[8];
        #pragma unroll
        for (int d=0;d<8;d++){ vx[d]=s_dx[dg*8+d]; vy[d]=s_dy[dg*8+d]; vz[d]=s_dz[dg*8+d]; }
        float tm[8];
        #pragma unroll
        for (int d=0;d<8;d++) tm[d] = -2.0f;
        #pragma unroll
        for (int g=0;g<4;g++){
            int off = np*64 + ((g*16) ^ ((np&3)<<4));
            float4 x4 = *(const float4*)((const char*)dnx + off);
            float4 y4 = *(const float4*)((const char*)dny + off);
            float4 z4 = *(const float4*)((const char*)dnz + off);
            const float xs[4]={x4.x,x4.y,x4.z,x4.w}, ys[4]={y4.x,y4.y,y4.z,y4.w},
                        zs[4]={z4.x,z4.y,z4.z,z4.w};
            #pragma unroll
            for (int q=0;q<4;q++)
                #pragma unroll
                for (int d=0;d<8;d++)
                    tm[d] = fmaxf(tm[d], vx[d]*xs[q]+vy[d]*ys[q]+vz[d]*zs[q]);
        }
        uint4 t4; t4.x=pk2(tm[0],tm[1]); t4.y=pk2(tm[2],tm[3]);
        t4.z=pk2(tm[4],tm[5]); t4.w=pk2(tm[6],tm[7]);
        int off = np*64 + ((dg*16) ^ ((np&3)<<4));
        *(uint4*)((char*)th + off) = t4;
    }
    __syncthreads();

    const int wid = tid >> 6, lane = tid & 63;
    const int lr = lane & 15, lg = lane >> 4;

    {
        const int arow = wid*16 + lr;
        bf16x8 afr = *(const bf16x8*)((const char*)ws1 + arow*64 + ((lg*16) ^ ((arow&3)<<4)));
        f32x4 hacc[4];
        #pragma unroll
        for (int nf=0;nf<4;nf++){
            int pt = nf*16 + lr;
            bf16x8 bfr = *(const bf16x8*)((const char*)th + pt*64 + ((lg*16) ^ ((pt&3)<<4)));
            f32x4 z = {0.f,0.f,0.f,0.f};
            hacc[nf] = __builtin_amdgcn_mfma_f32_16x16x32_bf16(afr, bfr, z, 0,0,0);
        }
        #pragma unroll
        for (int nf=0;nf<4;nf++){
            int ch0 = wid*16 + lg*4;
            int pt = nf*16 + lr;
            float g0 = gelu(hacc[nf].x*s_sc[ch0+0] + s_sh[ch0+0]);
            float g1 = gelu(hacc[nf].y*s_sc[ch0+1] + s_sh[ch0+1]);
            float g2 = gelu(hacc[nf].z*s_sc[ch0+2] + s_sh[ch0+2]);
            float g3 = gelu(hacc[nf].w*s_sc[ch0+3] + s_sh[ch0+3]);
            uint2 v; v.x = pk2(g0,g1); v.y = pk2(g2,g3);
            *(uint2*)((char*)hs + pt*128 + ((ch0*2) ^ ((pt&7)<<4))) = v;
        }
    }
    __syncthreads();

    {
        f32x4 pacc[2][4];
        #pragma unroll
        for (int mi=0;mi<2;mi++)
            #pragma unroll
            for (int nf=0;nf<4;nf++) pacc[mi][nf] = (f32x4){0.f,0.f,0.f,0.f};
        #pragma unroll
        for (int ks=0;ks<2;ks++){
            bf16x8 a[2], x[4];
            #pragma unroll
            for (int mi=0;mi<2;mi++){
                int row = (wid*2+mi)*16 + lr;
                a[mi] = *(const bf16x8*)((const char*)ws2 + row*128 + ((ks*64 + lg*16) ^ ((row&7)<<4)));
            }
            #pragma unroll
            for (int nf=0;nf<4;nf++){
                int pt = nf*16 + lr;
                x[nf] = *(const bf16x8*)((const char*)hs + pt*128 + ((ks*64 + lg*16) ^ ((pt&7)<<4)));
            }
            #pragma unroll
            for (int mi=0;mi<2;mi++)
                #pragma unroll
                for (int nf=0;nf<4;nf++)
                    pacc[mi][nf] = __builtin_amdgcn_mfma_f32_16x16x32_bf16(a[mi], x[nf], pacc[mi][nf], 0,0,0);
        }
        #pragma unroll
        for (int mi=0;mi<2;mi++){
            #pragma unroll
            for (int nf=0;nf<4;nf++){
                int ch0 = (wid*2+mi)*16 + lg*4;
                int pt = nf*16 + lr;
                u32x2 v;
                v.x = pk2(pacc[mi][nf].x + s_b2[ch0+0], pacc[mi][nf].y + s_b2[ch0+1]);
                v.y = pk2(pacc[mi][nf].z + s_b2[ch0+2], pacc[mi][nf].w + s_b2[ch0+3]);
                __builtin_nontemporal_store(v, (u32x2*)(pe + (size_t)(b*NN + n0 + pt)*CC + ch0));
            }
        }
    }
}

// ---------------- K2: f1/f2/f3 MFMA GEMM + ft transpose dump ----------------
// t1,t2 (B,N,128) KEY-transformed f1,f2; f3t, ft (B,N,128) plain bf16 (NT).
__global__ __launch_bounds__(256) void k_lin3(
    const float* __restrict__ f,
    const float* __restrict__ w1g, const float* __restrict__ b1g,
    const float* __restrict__ w2g, const float* __restrict__ b2g,
    const float* __restrict__ w3g, const float* __restrict__ b3g,
    unsigned short* __restrict__ t1, unsigned short* __restrict__ t2,
    unsigned short* __restrict__ f3t, unsigned short* __restrict__ ft)
{
    __shared__ alignas(16) unsigned short Xs[64*128];
    __shared__ alignas(16) unsigned short Ws[128*128];
    __shared__ float s_bias[128];
    const int tid = threadIdx.x;
    int b, tile;
    xcd_remap(blockIdx.x, b, tile);
    const int n0 = tile * 64;

    {
        const int j = (tid & 15) * 4;
        #pragma unroll
        for (int p = 0; p < 2; ++p){
            const int cb = ((tid >> 4) + p*16) * 4;
            const float* src = f + ((size_t)b*CC + cb)*NN + n0 + j;
            float4 r0 = *(const float4*)(src);
            float4 r1 = *(const float4*)(src + NN);
            float4 r2 = *(const float4*)(src + 2*(size_t)NN);
            float4 r3 = *(const float4*)(src + 3*(size_t)NN);
            const float rr[4][4] = {{r0.x,r1.x,r2.x,r3.x},{r0.y,r1.y,r2.y,r3.y},
                                    {r0.z,r1.z,r2.z,r3.z},{r0.w,r1.w,r2.w,r3.w}};
            #pragma unroll
            for (int i=0;i<4;i++){
                int n = j + i;
                int off = n*256 + ((cb*2) ^ ((n&7)<<4));
                uint2 v; v.x = pk2(rr[i][0], rr[i][1]); v.y = pk2(rr[i][2], rr[i][3]);
                *(uint2*)((char*)Xs + off) = v;
            }
        }
    }
    __syncthreads();
    // dump transposed f tile to ft (bf16, n-major) — coalesced NT stores
    #pragma unroll
    for (int q=0;q<4;q++){
        int idx = tid + q*256;
        int n = idx >> 4, c8 = (idx & 15)*8;
        int off = n*256 + ((c8*2) ^ ((n&7)<<4));
        u32x4 v = *(const u32x4*)((const char*)Xs + off);
        __builtin_nontemporal_store(v, (u32x4*)(ft + (size_t)(b*NN + n0 + n)*CC + c8));
    }

    const int wid = tid >> 6, lane = tid & 63;
    const int lr = lane & 15, lg = lane >> 4;
    const int o0 = (wid >> 1) * 64;
    const int nl0 = (wid & 1) * 32;

    for (int mat = 0; mat < 3; ++mat){
        const float* Wg = (mat==0)? w1g : (mat==1)? w2g : w3g;
        const float* Bg = (mat==0)? b1g : (mat==1)? b2g : b3g;
        __syncthreads();
        #pragma unroll 4
        for (int p = 0; p < 16; ++p){
            int o = (tid >> 5) + p*8;
            int c4 = (tid & 31) * 4;
            float4 w = *(const float4*)(Wg + (size_t)o*CC + c4);
            int off = o*256 + ((c4*2) ^ ((o&7)<<4));
            uint2 v; v.x = pk2(w.x, w.y); v.y = pk2(w.z, w.w);
            *(uint2*)((char*)Ws + off) = v;
        }
        if (tid < 128) s_bias[tid] = Bg[tid];
        __syncthreads();

        f32x4 acc[4][2];
        #pragma unroll
        for (int fi=0;fi<4;fi++){
            int o = o0 + fi*16 + lg*4;
            f32x4 bi = {s_bias[o], s_bias[o+1], s_bias[o+2], s_bias[o+3]};
            acc[fi][0] = bi; acc[fi][1] = bi;
        }
        #pragma unroll
        for (int kk=0; kk<4; ++kk){
            const int kb = kk*64 + lg*16;
            bf16x8 a[4], x[2];
            #pragma unroll
            for (int fi=0;fi<4;fi++){
                int row = o0 + fi*16 + lr;
                a[fi] = *(const bf16x8*)((const char*)Ws + row*256 + (kb ^ ((row&7)<<4)));
            }
            #pragma unroll
            for (int fj=0;fj<2;fj++){
                int nr = nl0 + fj*16 + lr;
                x[fj] = *(const bf16x8*)((const char*)Xs + nr*256 + (kb ^ ((nr&7)<<4)));
            }
            #pragma unroll
            for (int fi=0;fi<4;fi++)
                #pragma unroll
                for (int fj=0;fj<2;fj++)
                    acc[fi][fj] = __builtin_amdgcn_mfma_f32_16x16x32_bf16(a[fi], x[fj], acc[fi][fj], 0,0,0);
        }
        #pragma unroll
        for (int fi=0;fi<4;fi++){
            #pragma unroll
            for (int fj=0;fj<2;fj++){
                int o = o0 + fi*16 + lg*4;
                int n = n0 + nl0 + fj*16 + lr;
                if (mat == 2){
                    u32x2 u;
                    u.x = pk2(acc[fi][fj].x, acc[fi][fj].y);
                    u.y = pk2(acc[fi][fj].z, acc[fi][fj].w);
                    __builtin_nontemporal_store(u, (u32x2*)(f3t + (size_t)(b*NN + n)*CC + o));
                } else {
                    unsigned short* dst = (mat==0)? t1 : t2;
                    uint2 kv;
                    kv.x = bf2key(pk2(acc[fi][fj].x, acc[fi][fj].y));
                    kv.y = bf2key(pk2(acc[fi][fj].z, acc[fi][fj].w));
                    *(uint2*)(dst + (size_t)(b*NN + n)*CC + o) = kv;  // table: keep in L2
                }
            }
        }
    }
}

// ---------------- K3: split-half knn gather-max ------------------------------
// XCD 2b: t1 -> agg1; XCD 2b+1: t2(+self) -> agg2. Per-XCD table = 2 MB (L2-fit).
// 8192 blocks x 256 thr; wave handles 2 points (32 dword loads in flight).
__global__ __launch_bounds__(256) void k_gather(
    const int* __restrict__ qidx,
    const unsigned short* __restrict__ t1,
    const unsigned short* __restrict__ t2,
    unsigned short* __restrict__ agg1,
    unsigned short* __restrict__ agg2)
{
    const int tid = threadIdx.x;
    const int lane = tid & 63, wrp = tid >> 6;
    const int bid = blockIdx.x;
    const int xcd = bid & 7;
    const int b = xcd >> 1, half = xcd & 1;
    const int tile = bid >> 3;                    // 1024 tiles per (b,half)
    const int p0 = b*NN + tile*8 + wrp*2;
    const unsigned short* tab = half ? t2 : t1;
    const unsigned int* gb = (const unsigned int*)(tab + (size_t)b*NN*CC) + lane;
    const int prow = __builtin_amdgcn_readfirstlane(p0);
    const int* i0 = qidx + (size_t)prow*KK;

    unsigned int m0 = 0, m1 = 0;                  // key 0 == most-negative bf16
    #pragma unroll
    for (int k=0;k<KK;k++){
        int j0 = i0[k];
        int j1 = i0[KK + k];
        unsigned int g0 = gb[(size_t)j0*64];
        unsigned int g1 = gb[(size_t)j1*64];
        m0 = pkmax(m0, g0);
        m1 = pkmax(m1, g1);
    }
    unsigned int r0 = key2bf(m0), r1 = key2bf(m1);
    float a00 = lo16(r0), a01 = hi16(r0);
    float a10 = lo16(r1), a11 = hi16(r1);
    if (half){   // agg2 = max + self
        unsigned int s0 = key2bf(((const unsigned int*)(tab + (size_t)p0*CC))[lane]);
        unsigned int s1 = key2bf(((const unsigned int*)(tab + (size_t)(p0+1)*CC))[lane]);
        a00 += lo16(s0); a01 += hi16(s0);
        a10 += lo16(s1); a11 += hi16(s1);
    }
    unsigned short* aout = half ? agg2 : agg1;
    __builtin_nontemporal_store(pk2(a00,a01), (unsigned int*)(aout + (size_t)p0*CC) + lane);
    __builtin_nontemporal_store(pk2(a10,a11), (unsigned int*)(aout + (size_t)(p0+1)*CC) + lane);
}

// ---------------- K4: combine + h2 + out (fused GEMM tail) -------------------
__global__ __launch_bounds__(256) void k_h2o(
    const unsigned short* __restrict__ agg1,
    const unsigned short* __restrict__ agg2,
    const unsigned short* __restrict__ ft,
    const unsigned short* __restrict__ f3t,
    const unsigned short* __restrict__ pe,
    const float* __restrict__ l_bng, const float* __restrict__ l_bnb,
    const float* __restrict__ l_bnm, const float* __restrict__ l_bnv,
    const float* __restrict__ w1g,
    const float* __restrict__ bng, const float* __restrict__ bnb,
    const float* __restrict__ bnm, const float* __restrict__ bnv,
    const float* __restrict__ w2g,
    float* __restrict__ out)
{
    __shared__ alignas(16) unsigned short Xs[64*128];   // fmid tile [n][c]
    __shared__ alignas(16) unsigned short Ws[128*128];  // m_w1 half / m_w2 half
    __shared__ alignas(16) unsigned short Hs[64*128];   // h2 half  [n][jo_local]
    __shared__ float s_lsc[128], s_lsh[128];
    __shared__ float s_msc[256], s_msh[256];
    const int tid = threadIdx.x;
    int b, tile;
    xcd_remap(blockIdx.x, b, tile);
    const int n0 = tile * 64;

    if (tid < 128){
        float sc = l_bng[tid] / sqrtf(l_bnv[tid] + 1e-5f);
        s_lsc[tid] = sc; s_lsh[tid] = l_bnb[tid] - l_bnm[tid]*sc;
    }
    {
        float sc = bng[tid] / sqrtf(bnv[tid] + 1e-5f);
        s_msc[tid] = sc; s_msh[tid] = bnb[tid] - bnm[tid]*sc;
    }
    __syncthreads();

    // combine-stage: fmid = ft + bn_l(agg1+agg2+f3) + pe -> Xs (swizzled)
    #pragma unroll
    for (int q=0;q<4;q++){
        int idx = tid + q*256;
        int n = idx >> 4, c8 = (idx & 15)*8;
        size_t base = (size_t)(b*NN + n0 + n)*CC + c8;
        u32x4 a1 = __builtin_nontemporal_load((const u32x4*)(agg1 + base));
        u32x4 a2 = __builtin_nontemporal_load((const u32x4*)(agg2 + base));
        u32x4 fv = __builtin_nontemporal_load((const u32x4*)(ft   + base));
        u32x4 f3 = __builtin_nontemporal_load((const u32x4*)(f3t  + base));
        u32x4 pv = __builtin_nontemporal_load((const u32x4*)(pe   + base));
        u32x4 r;
        #pragma unroll
        for (int e=0;e<4;e++){
            int c = c8 + e*2;
            float slo = lo16(a1[e]) + lo16(a2[e]) + lo16(f3[e]);
            float shi = hi16(a1[e]) + hi16(a2[e]) + hi16(f3[e]);
            float vlo = lo16(fv[e]) + slo*s_lsc[c]   + s_lsh[c]   + lo16(pv[e]);
            float vhi = hi16(fv[e]) + shi*s_lsc[c+1] + s_lsh[c+1] + hi16(pv[e]);
            r[e] = pk2(vlo, vhi);
        }
        int off = n*256 + ((c8*2) ^ ((n&7)<<4));
        *(u32x4*)((char*)Xs + off) = r;
    }

    const int lane = tid & 63, wrp = tid >> 6;
    const int lr = lane & 15, lg = lane >> 4;
    const int o0 = (wrp >> 1) * 64;
    const int nl0 = (wrp & 1) * 32;

    f32x4 oacc[4][2];
    #pragma unroll
    for (int fi=0;fi<4;fi++){ oacc[fi][0]=(f32x4){0,0,0,0}; oacc[fi][1]=(f32x4){0,0,0,0}; }

    for (int jh = 0; jh < 2; ++jh){
        __syncthreads();   // Xs ready (jh=0) / Hs+Ws consumed by prev phase
        {
            const float* Wg = w1g + (size_t)jh*128*CC;
            #pragma unroll 4
            for (int p = 0; p < 16; ++p){
                int o = (tid >> 5) + p*8;
                int c4 = (tid & 31) * 4;
                float4 w = *(const float4*)(Wg + (size_t)o*CC + c4);
                int off = o*256 + ((c4*2) ^ ((o&7)<<4));
                uint2 v; v.x = pk2(w.x, w.y); v.y = pk2(w.z, w.w);
                *(uint2*)((char*)Ws + off) = v;
            }
        }
        __syncthreads();
        // h2 half = gelu(bn(m_w1_half @ fmid))
        {
            f32x4 hacc[4][2];
            #pragma unroll
            for (int fi=0;fi<4;fi++){ hacc[fi][0]=(f32x4){0,0,0,0}; hacc[fi][1]=(f32x4){0,0,0,0}; }
            #pragma unroll
            for (int kk=0; kk<4; ++kk){
                const int kb = kk*64 + lg*16;
                bf16x8 a[4], x[2];
                #pragma unroll
                for (int fi=0;fi<4;fi++){
                    int row = o0 + fi*16 + lr;
                    a[fi] = *(const bf16x8*)((const char*)Ws + row*256 + (kb ^ ((row&7)<<4)));
                }
                #pragma unroll
                for (int fj=0;fj<2;fj++){
                    int nr = nl0 + fj*16 + lr;
                    x[fj] = *(const bf16x8*)((const char*)Xs + nr*256 + (kb ^ ((nr&7)<<4)));
                }
                #pragma unroll
                for (int fi=0;fi<4;fi++)
                    #pragma unroll
                    for (int fj=0;fj<2;fj++)
                        hacc[fi][fj] = __builtin_amdgcn_mfma_f32_16x16x32_bf16(a[fi], x[fj], hacc[fi][fj], 0,0,0);
            }
            #pragma unroll
            for (int fi=0;fi<4;fi++){
                #pragma unroll
                for (int fj=0;fj<2;fj++){
                    int o = o0 + fi*16 + lg*4;
                    int jo = jh*128 + o;
                    int nl = nl0 + fj*16 + lr;
                    float v0 = gelu(hacc[fi][fj].x*s_msc[jo+0] + s_msh[jo+0]);
                    float v1 = gelu(hacc[fi][fj].y*s_msc[jo+1] + s_msh[jo+1]);
                    float v2 = gelu(hacc[fi][fj].z*s_msc[jo+2] + s_msh[jo+2]);
                    float v3 = gelu(hacc[fi][fj].w*s_msc[jo+3] + s_msh[jo+3]);
                    u32x2 v; v.x = pk2(v0,v1); v.y = pk2(v2,v3);
                    *(u32x2*)((char*)Hs + nl*256 + ((o*2) ^ ((nl&7)<<4))) = v;
                }
            }
        }
        __syncthreads();   // Hs ready; Ws reads done
        {
            #pragma unroll 4
            for (int p = 0; p < 16; ++p){
                int o = (tid >> 5) + p*8;
                int c4 = (tid & 31) * 4;
                float4 w = *(const float4*)(w2g + (size_t)o*C2 + jh*128 + c4);
                int off = o*256 + ((c4*2) ^ ((o&7)<<4));
                uint2 v; v.x = pk2(w.x, w.y); v.y = pk2(w.z, w.w);
                *(uint2*)((char*)Ws + off) = v;
            }
        }
        __syncthreads();
        // out += m_w2_half @ h2_half
        #pragma unroll
        for (int kk=0; kk<4; ++kk){
            const int kb = kk*64 + lg*16;
            bf16x8 a[4], x[2];
            #pragma unroll
            for (int fi=0;fi<4;fi++){
                int row = o0 + fi*16 + lr;
                a[fi] = *(const bf16x8*)((const char*)Ws + row*256 + (kb ^ ((row&7)<<4)));
            }
            #pragma unroll
            for (int fj=0;fj<2;fj++){
                int nr = nl0 + fj*16 + lr;
                x[fj] = *(const bf16x8*)((const char*)Hs + nr*256 + (kb ^ ((nr&7)<<4)));
            }
            #pragma unroll
            for (int fi=0;fi<4;fi++)
                #pragma unroll
                for (int fj=0;fj<2;fj++)
                    oacc[fi][fj] = __builtin_amdgcn_mfma_f32_16x16x32_bf16(a[fi], x[fj], oacc[fi][fj], 0,0,0);
        }
    }
    // epilogue: out = fmid(Xs) + oacc
    #pragma unroll
    for (int fi=0;fi<4;fi++){
        #pragma unroll
        for (int fj=0;fj<2;fj++){
            int o = o0 + fi*16 + lg*4;
            int nl = nl0 + fj*16 + lr;
            int n = n0 + nl;
            u32x2 fm = *(const u32x2*)((const char*)Xs + nl*256 + ((o*2) ^ ((nl&7)<<4)));
            float* op = out + ((size_t)b*CC + o)*NN + n;
            op[0*(size_t)NN] = lo16(fm.x) + oacc[fi][fj].x;
            op[1*(size_t)NN] = hi16(fm.x) + oacc[fi][fj].y;
            op[2*(size_t)NN] = lo16(fm.y) + oacc[fi][fj].z;
            op[3*(size_t)NN] = hi16(fm.y) + oacc[fi][fj].w;
        }
    }
}

extern "C" void kernel_launch(void* const* d_in, const int* in_sizes, int n_in,
                              void* d_out, int out_size, void* d_ws, size_t ws_size,
                              hipStream_t stream)
{
    const float* f      = (const float*)d_in[0];
    const float* dp     = (const float*)d_in[1];
    const int*   qidx   = (const int*)  d_in[2];
    const float* dirs   = (const float*)d_in[3];
    const float* de_w1  = (const float*)d_in[4];
    const float* de_bng = (const float*)d_in[5];
    const float* de_bnb = (const float*)d_in[6];
    const float* de_bnm = (const float*)d_in[7];
    const float* de_bnv = (const float*)d_in[8];
    const float* de_w2  = (const float*)d_in[9];
    const float* de_b2  = (const float*)d_in[10];
    const float* l_w1   = (const float*)d_in[11];
    const float* l_b1   = (const float*)d_in[12];
    const float* l_w2   = (const float*)d_in[13];
    const float* l_b2   = (const float*)d_in[14];
    const float* l_w3   = (const float*)d_in[15];
    const float* l_b3   = (const float*)d_in[16];
    const float* l_bng  = (const float*)d_in[17];
    const float* l_bnb  = (const float*)d_in[18];
    const float* l_bnm  = (const float*)d_in[19];
    const float* l_bnv  = (const float*)d_in[20];
    const float* m_w1   = (const float*)d_in[21];
    const float* m_bng  = (const float*)d_in[22];
    const float* m_bnb  = (const float*)d_in[23];
    const float* m_bnm  = (const float*)d_in[24];
    const float* m_bnv  = (const float*)d_in[25];
    const float* m_w2   = (const float*)d_in[26];

    char* ws = (char*)d_ws;
    // layout (bytes), all bf16/keys (B,N,128) = 8 MB each:
    //   t1    [0,        8388608)
    //   t2    [8388608,  16777216)
    //   ft    [16777216, 25165824)
    //   f3t   [25165824, 33554432)
    //   pe    [33554432, 41943040)
    //   agg1  [41943040, 50331648)
    //   agg2  [50331648, 58720256)
    unsigned short* t1    = (unsigned short*)(ws + 0);
    unsigned short* t2    = (unsigned short*)(ws + 8388608);
    unsigned short* ft    = (unsigned short*)(ws + 16777216);
    unsigned short* f3t   = (unsigned short*)(ws + 25165824);
    unsigned short* pe    = (unsigned short*)(ws + 33554432);
    unsigned short* agg1  = (unsigned short*)(ws + 41943040);
    unsigned short* agg2  = (unsigned short*)(ws + 50331648);

    k_pe<<<dim3(512), dim3(256), 0, stream>>>(dp, dirs, de_w1, de_bng, de_bnb, de_bnm, de_bnv,
                                              de_w2, de_b2, pe);
    k_lin3<<<dim3(512), dim3(256), 0, stream>>>(f, l_w1, l_b1, l_w2, l_b2, l_w3, l_b3,
                                                t1, t2, f3t, ft);
    k_gather<<<dim3(8192), dim3(256), 0, stream>>>(qidx, t1, t2, agg1, agg2);
    k_h2o<<<dim3(512), dim3(256), 0, stream>>>(agg1, agg2, ft, f3t, pe,
                                               l_bng, l_bnb, l_bnm, l_bnv,
                                               m_w1, m_bng, m_bnb, m_bnm, m_bnv,
                                               m_w2, (float*)d_out);
}

// Round 10
// 66.595 us; speedup vs baseline: 1.7410x; 1.1692x over previous
//
#include <hip/hip_runtime.h>
#include <hip/hip_bf16.h>
#include <cstdint>
#include <cstddef>

#define BB 4
#define CC 128
#define NN 8192
#define KK 16
#define HH 64
#define MM 32
#define C2 256

typedef __attribute__((ext_vector_type(8))) short bf16x8;
typedef __attribute__((ext_vector_type(4))) float f32x4;
typedef unsigned short u16x2v __attribute__((ext_vector_type(2)));
typedef unsigned int u32x2 __attribute__((ext_vector_type(2)));
typedef unsigned int u32x4 __attribute__((ext_vector_type(4)));

__device__ __forceinline__ unsigned short f2bf(float f){
    unsigned int x = __float_as_uint(f);
    x += 0x7fffu + ((x >> 16) & 1u);
    return (unsigned short)(x >> 16);
}
__device__ __forceinline__ unsigned int pk2(float a, float b){
    return (unsigned int)f2bf(a) | ((unsigned int)f2bf(b) << 16);
}
__device__ __forceinline__ float lo16(unsigned int u){ return __uint_as_float(u << 16); }
__device__ __forceinline__ float hi16(unsigned int u){ return __uint_as_float(u & 0xffff0000u); }
__device__ __forceinline__ float gelu(float a){
    return 0.5f*a*(1.0f+erff(a*0.7071067811865475f));
}
// monotone key transform: unsigned 16-bit compare on keys == float compare on bf16
__device__ __forceinline__ unsigned int bf2key(unsigned int v){
    unsigned int neg = (v >> 15) & 0x10001u;
    return v ^ (0x80008000u | neg * 0x7FFFu);
}
__device__ __forceinline__ unsigned int key2bf(unsigned int k){
    unsigned int pos = (~k >> 15) & 0x10001u;
    return k ^ (0x80008000u | pos * 0x7FFFu);
}
__device__ __forceinline__ unsigned int pkmax(unsigned int a, unsigned int b){
    u16x2v r = __builtin_elementwise_max(__builtin_bit_cast(u16x2v, a),
                                         __builtin_bit_cast(u16x2v, b));
    return __builtin_bit_cast(unsigned int, r);
}
// batch-affinity XCD remap: XCD pair {2b,2b+1} owns batch b.
__device__ __forceinline__ void xcd_remap(int bid, int& b, int& tile){
    int xcd = bid & 7;
    b = xcd >> 1;
    tile = (bid >> 3) * 2 + (xcd & 1);
}

// ---------------- K0: weight convert + pre-swizzle to LDS image layout ------
// images (32 KB each, bf16): 0..2 = l_w1..3; 3,4 = m_w1 halves; 5,6 = m_w2 halves
__global__ __launch_bounds__(256) void k_wcv(
    const float* __restrict__ lw1, const float* __restrict__ lw2,
    const float* __restrict__ lw3, const float* __restrict__ mw1,
    const float* __restrict__ mw2, unsigned short* __restrict__ wb)
{
    const int tid = threadIdx.x;
    const int img = blockIdx.x >> 4;
    const int chunk = blockIdx.x & 15;
    const int o = chunk*8 + (tid >> 5);
    const int c4 = (tid & 31)*4;
    const float* src;
    if (img < 3)      src = (img==0? lw1 : img==1? lw2 : lw3) + (size_t)o*128 + c4;
    else if (img < 5) src = mw1 + ((size_t)(img-3)*128 + o)*128 + c4;
    else              src = mw2 + (size_t)o*256 + (size_t)(img-5)*128 + c4;
    float4 w = *(const float4*)src;
    uint2 v; v.x = pk2(w.x, w.y); v.y = pk2(w.z, w.w);
    *(uint2*)((char*)wb + (size_t)img*32768 + o*256 + ((c4*2) ^ ((o&7)<<4))) = v;
}

// ---------------- K1: merged pe + lin3 ---------------------------------------
// phase A: pe path (MFMA) -> peL (LDS). phase B: f1/f2/f3 GEMMs ->
// t1,t2 (keys) + base = f + f3*lsc + lsh + pe (NT).
__global__ __launch_bounds__(256) void k_linpe(
    const float* __restrict__ f,
    const float* __restrict__ dp, const float* __restrict__ dirs,
    const float* __restrict__ de_w1,
    const float* __restrict__ de_bng, const float* __restrict__ de_bnb,
    const float* __restrict__ de_bnm, const float* __restrict__ de_bnv,
    const float* __restrict__ de_w2, const float* __restrict__ de_b2,
    const unsigned short* __restrict__ wb,
    const float* __restrict__ b1g, const float* __restrict__ b2g,
    const float* __restrict__ b3g,
    const float* __restrict__ l_bng, const float* __restrict__ l_bnb,
    const float* __restrict__ l_bnm, const float* __restrict__ l_bnv,
    unsigned short* __restrict__ t1, unsigned short* __restrict__ t2,
    unsigned short* __restrict__ baseb)
{
    // raw region: pe-phase arrays (45056 B) aliased with lin3's Ws (32768 B)
    __shared__ alignas(16) char sraw[45056];
    __shared__ alignas(16) unsigned short Xs[64*128];   // f tile [n][c], swizzled
    __shared__ alignas(16) unsigned short peL[64*128];  // pe tile [n][c], swizzled
    __shared__ float s_dx[MM], s_dy[MM], s_dz[MM];
    __shared__ float s_sc[HH], s_sh[HH], s_b2[CC];
    __shared__ float s_lsc[CC], s_lsh[CC];
    __shared__ float s_bias[128];

    float* dnx = (float*)(sraw + 0);
    float* dny = (float*)(sraw + 4096);
    float* dnz = (float*)(sraw + 8192);
    unsigned short* th  = (unsigned short*)(sraw + 12288);
    unsigned short* ws1 = (unsigned short*)(sraw + 16384);
    unsigned short* ws2 = (unsigned short*)(sraw + 20480);
    unsigned short* hs  = (unsigned short*)(sraw + 36864);
    unsigned short* Ws  = (unsigned short*)(sraw + 0);

    const int tid = threadIdx.x;
    int b, tile; xcd_remap(blockIdx.x, b, tile);
    const int n0 = tile * 64;

    // ---- phase 1: stage everything ----
    if (tid < MM){
        float x=dirs[tid*3+0], y=dirs[tid*3+1], z=dirs[tid*3+2];
        float inv = 1.0f / fmaxf(sqrtf(x*x+y*y+z*z), 1e-12f);
        s_dx[tid]=x*inv; s_dy[tid]=y*inv; s_dz[tid]=z*inv;
    }
    #pragma unroll
    for (int p=0;p<2;p++){
        int id = tid + p*256;
        int row = id >> 3, c4 = (id & 7)*4;
        float4 w = *(const float4*)(de_w1 + row*MM + c4);
        int off = row*64 + ((c4*2) ^ ((row&3)<<4));
        uint2 v; v.x = pk2(w.x,w.y); v.y = pk2(w.z,w.w);
        *(uint2*)((char*)ws1 + off) = v;
    }
    #pragma unroll
    for (int p=0;p<8;p++){
        int id = tid + p*256;
        int row = id >> 4, c4 = (id & 15)*4;
        float4 w = *(const float4*)(de_w2 + row*HH + c4);
        int off = row*128 + ((c4*2) ^ ((row&7)<<4));
        uint2 v; v.x = pk2(w.x,w.y); v.y = pk2(w.z,w.w);
        *(uint2*)((char*)ws2 + off) = v;
    }
    if (tid < HH){
        float sc = de_bng[tid] / sqrtf(de_bnv[tid] + 1e-5f);
        s_sc[tid]=sc; s_sh[tid]=de_bnb[tid]-de_bnm[tid]*sc;
    }
    if (tid >= 64 && tid < 192) s_b2[tid-64] = de_b2[tid-64];
    if (tid < CC){
        float sc = l_bng[tid] / sqrtf(l_bnv[tid] + 1e-5f);
        s_lsc[tid] = sc; s_lsh[tid] = l_bnb[tid] - l_bnm[tid]*sc;
    }
    // stage f tile transposed into Xs (reg 4x4 transpose)
    {
        const int j = (tid & 15) * 4;
        #pragma unroll
        for (int p = 0; p < 2; ++p){
            const int cb = ((tid >> 4) + p*16) * 4;
            const float* src = f + ((size_t)b*CC + cb)*NN + n0 + j;
            float4 r0 = *(const float4*)(src);
            float4 r1 = *(const float4*)(src + NN);
            float4 r2 = *(const float4*)(src + 2*(size_t)NN);
            float4 r3 = *(const float4*)(src + 3*(size_t)NN);
            const float rr[4][4] = {{r0.x,r1.x,r2.x,r3.x},{r0.y,r1.y,r2.y,r3.y},
                                    {r0.z,r1.z,r2.z,r3.z},{r0.w,r1.w,r2.w,r3.w}};
            #pragma unroll
            for (int i=0;i<4;i++){
                int n = j + i;
                int off = n*256 + ((cb*2) ^ ((n&7)<<4));
                uint2 v; v.x = pk2(rr[i][0], rr[i][1]); v.y = pk2(rr[i][2], rr[i][3]);
                *(uint2*)((char*)Xs + off) = v;
            }
        }
    }
    // stage + normalize dp tile
    {
        const size_t cstride = (size_t)NN*KK;
        const float* base = dp + (size_t)b*3*cstride + (size_t)n0*KK + tid*4;
        float4 X = *(const float4*)(base);
        float4 Y = *(const float4*)(base + cstride);
        float4 Z = *(const float4*)(base + 2*cstride);
        float i0 = 1.0f/fmaxf(sqrtf(X.x*X.x+Y.x*Y.x+Z.x*Z.x),1e-12f);
        float i1 = 1.0f/fmaxf(sqrtf(X.y*X.y+Y.y*Y.y+Z.y*Z.y),1e-12f);
        float i2 = 1.0f/fmaxf(sqrtf(X.z*X.z+Y.z*Y.z+Z.z*Z.z),1e-12f);
        float i3 = 1.0f/fmaxf(sqrtf(X.w*X.w+Y.w*Y.w+Z.w*Z.w),1e-12f);
        float4 xn = {X.x*i0, X.y*i1, X.z*i2, X.w*i3};
        float4 yn = {Y.x*i0, Y.y*i1, Y.z*i2, Y.w*i3};
        float4 zn = {Z.x*i0, Z.y*i1, Z.z*i2, Z.w*i3};
        const int np = tid >> 2;
        const int off = np*64 + (((tid&3)*16) ^ ((np&3)<<4));
        *(float4*)((char*)dnx + off) = xn;
        *(float4*)((char*)dny + off) = yn;
        *(float4*)((char*)dnz + off) = zn;
    }
    __syncthreads();

    // ---- phase 2: theta_max (8 dirs/thread) ----
    {
        const int np = tid & 63, dg = tid >> 6;
        float vx[8], vy[8], vz[8];
        #pragma unroll
        for (int d=0;d<8;d++){ vx[d]=s_dx[dg*8+d]; vy[d]=s_dy[dg*8+d]; vz[d]=s_dz[dg*8+d]; }
        float tm[8];
        #pragma unroll
        for (int d=0;d<8;d++) tm[d] = -2.0f;
        #pragma unroll
        for (int g=0;g<4;g++){
            int off = np*64 + ((g*16) ^ ((np&3)<<4));
            float4 x4 = *(const float4*)((const char*)dnx + off);
            float4 y4 = *(const float4*)((const char*)dny + off);
            float4 z4 = *(const float4*)((const char*)dnz + off);
            const float xs[4]={x4.x,x4.y,x4.z,x4.w}, ys[4]={y4.x,y4.y,y4.z,y4.w},
                        zs[4]={z4.x,z4.y,z4.z,z4.w};
            #pragma unroll
            for (int q=0;q<4;q++)
                #pragma unroll
                for (int d=0;d<8;d++)
                    tm[d] = fmaxf(tm[d], vx[d]*xs[q]+vy[d]*ys[q]+vz[d]*zs[q]);
        }
        uint4 t4; t4.x=pk2(tm[0],tm[1]); t4.y=pk2(tm[2],tm[3]);
        t4.z=pk2(tm[4],tm[5]); t4.w=pk2(tm[6],tm[7]);
        int off = np*64 + ((dg*16) ^ ((np&3)<<4));
        *(uint4*)((char*)th + off) = t4;
    }
    __syncthreads();

    const int wid = tid >> 6, lane = tid & 63;
    const int lr = lane & 15, lg = lane >> 4;

    // ---- phase 3: GEMM1 h = gelu(bn(W1 @ theta)) ----
    {
        const int arow = wid*16 + lr;
        bf16x8 afr = *(const bf16x8*)((const char*)ws1 + arow*64 + ((lg*16) ^ ((arow&3)<<4)));
        f32x4 hacc[4];
        #pragma unroll
        for (int nf=0;nf<4;nf++){
            int pt = nf*16 + lr;
            bf16x8 bfr = *(const bf16x8*)((const char*)th + pt*64 + ((lg*16) ^ ((pt&3)<<4)));
            f32x4 z = {0.f,0.f,0.f,0.f};
            hacc[nf] = __builtin_amdgcn_mfma_f32_16x16x32_bf16(afr, bfr, z, 0,0,0);
        }
        #pragma unroll
        for (int nf=0;nf<4;nf++){
            int ch0 = wid*16 + lg*4;
            int pt = nf*16 + lr;
            float g0 = gelu(hacc[nf].x*s_sc[ch0+0] + s_sh[ch0+0]);
            float g1 = gelu(hacc[nf].y*s_sc[ch0+1] + s_sh[ch0+1]);
            float g2 = gelu(hacc[nf].z*s_sc[ch0+2] + s_sh[ch0+2]);
            float g3 = gelu(hacc[nf].w*s_sc[ch0+3] + s_sh[ch0+3]);
            uint2 v; v.x = pk2(g0,g1); v.y = pk2(g2,g3);
            *(uint2*)((char*)hs + pt*128 + ((ch0*2) ^ ((pt&7)<<4))) = v;
        }
    }
    __syncthreads();

    // ---- phase 4: GEMM2 pe = W2 @ h + b2 -> peL (LDS only) ----
    {
        f32x4 pacc[2][4];
        #pragma unroll
        for (int mi=0;mi<2;mi++)
            #pragma unroll
            for (int nf=0;nf<4;nf++) pacc[mi][nf] = (f32x4){0.f,0.f,0.f,0.f};
        #pragma unroll
        for (int ks=0;ks<2;ks++){
            bf16x8 a[2], x[4];
            #pragma unroll
            for (int mi=0;mi<2;mi++){
                int row = (wid*2+mi)*16 + lr;
                a[mi] = *(const bf16x8*)((const char*)ws2 + row*128 + ((ks*64 + lg*16) ^ ((row&7)<<4)));
            }
            #pragma unroll
            for (int nf=0;nf<4;nf++){
                int pt = nf*16 + lr;
                x[nf] = *(const bf16x8*)((const char*)hs + pt*128 + ((ks*64 + lg*16) ^ ((pt&7)<<4)));
            }
            #pragma unroll
            for (int mi=0;mi<2;mi++)
                #pragma unroll
                for (int nf=0;nf<4;nf++)
                    pacc[mi][nf] = __builtin_amdgcn_mfma_f32_16x16x32_bf16(a[mi], x[nf], pacc[mi][nf], 0,0,0);
        }
        #pragma unroll
        for (int mi=0;mi<2;mi++){
            #pragma unroll
            for (int nf=0;nf<4;nf++){
                int ch0 = (wid*2+mi)*16 + lg*4;
                int pt = nf*16 + lr;
                uint2 v;
                v.x = pk2(pacc[mi][nf].x + s_b2[ch0+0], pacc[mi][nf].y + s_b2[ch0+1]);
                v.y = pk2(pacc[mi][nf].z + s_b2[ch0+2], pacc[mi][nf].w + s_b2[ch0+3]);
                *(uint2*)((char*)peL + pt*256 + ((ch0*2) ^ ((pt&7)<<4))) = v;
            }
        }
    }

    // ---- phase 5: lin3 GEMMs (Ws overwrites pe-phase arrays) ----
    const int o0 = (wid >> 1) * 64;
    const int nl0 = (wid & 1) * 32;

    for (int mat = 0; mat < 3; ++mat){
        const float* Bg = (mat==0)? b1g : (mat==1)? b2g : b3g;
        __syncthreads();   // mat0: pe-phase reads of ws2/hs done; later: prev Ws reads done
        {
            const char* img = (const char*)wb + (size_t)mat*32768;
            #pragma unroll
            for (int p=0;p<8;p++){
                int off = tid*16 + p*4096;
                *(u32x4*)((char*)Ws + off) = *(const u32x4*)(img + off);
            }
        }
        if (tid < 128) s_bias[tid] = Bg[tid];
        __syncthreads();

        f32x4 acc[4][2];
        #pragma unroll
        for (int fi=0;fi<4;fi++){
            int o = o0 + fi*16 + lg*4;
            f32x4 bi = {s_bias[o], s_bias[o+1], s_bias[o+2], s_bias[o+3]};
            acc[fi][0] = bi; acc[fi][1] = bi;
        }
        #pragma unroll
        for (int kk=0; kk<4; ++kk){
            const int kb = kk*64 + lg*16;
            bf16x8 a[4], x[2];
            #pragma unroll
            for (int fi=0;fi<4;fi++){
                int row = o0 + fi*16 + lr;
                a[fi] = *(const bf16x8*)((const char*)Ws + row*256 + (kb ^ ((row&7)<<4)));
            }
            #pragma unroll
            for (int fj=0;fj<2;fj++){
                int nr = nl0 + fj*16 + lr;
                x[fj] = *(const bf16x8*)((const char*)Xs + nr*256 + (kb ^ ((nr&7)<<4)));
            }
            #pragma unroll
            for (int fi=0;fi<4;fi++)
                #pragma unroll
                for (int fj=0;fj<2;fj++)
                    acc[fi][fj] = __builtin_amdgcn_mfma_f32_16x16x32_bf16(a[fi], x[fj], acc[fi][fj], 0,0,0);
        }
        #pragma unroll
        for (int fi=0;fi<4;fi++){
            #pragma unroll
            for (int fj=0;fj<2;fj++){
                int o = o0 + fi*16 + lg*4;
                int nl = nl0 + fj*16 + lr;
                int n = n0 + nl;
                if (mat == 2){
                    // base = f + f3*lsc + lsh + pe  (f3 = acc, f32)
                    u32x2 fm = *(const u32x2*)((const char*)Xs  + nl*256 + ((o*2) ^ ((nl&7)<<4)));
                    u32x2 pv = *(const u32x2*)((const char*)peL + nl*256 + ((o*2) ^ ((nl&7)<<4)));
                    float v0 = lo16(fm.x) + acc[fi][fj].x*s_lsc[o+0] + s_lsh[o+0] + lo16(pv.x);
                    float v1 = hi16(fm.x) + acc[fi][fj].y*s_lsc[o+1] + s_lsh[o+1] + hi16(pv.x);
                    float v2 = lo16(fm.y) + acc[fi][fj].z*s_lsc[o+2] + s_lsh[o+2] + lo16(pv.y);
                    float v3 = hi16(fm.y) + acc[fi][fj].w*s_lsc[o+3] + s_lsh[o+3] + hi16(pv.y);
                    u32x2 r; r.x = pk2(v0,v1); r.y = pk2(v2,v3);
                    __builtin_nontemporal_store(r, (u32x2*)(baseb + (size_t)(b*NN + n)*CC + o));
                } else {
                    unsigned short* dst = (mat==0)? t1 : t2;
                    uint2 kv;
                    kv.x = bf2key(pk2(acc[fi][fj].x, acc[fi][fj].y));
                    kv.y = bf2key(pk2(acc[fi][fj].z, acc[fi][fj].w));
                    *(uint2*)(dst + (size_t)(b*NN + n)*CC + o) = kv;  // table: keep in L2
                }
            }
        }
    }
}

// ---------------- K3: split-half knn gather-max ------------------------------
// XCD 2b: t1 -> agg1; XCD 2b+1: t2(+self) -> agg2. Per-XCD table = 2 MB (L2-fit).
__global__ __launch_bounds__(256) void k_gather(
    const int* __restrict__ qidx,
    const unsigned short* __restrict__ t1,
    const unsigned short* __restrict__ t2,
    unsigned short* __restrict__ agg1,
    unsigned short* __restrict__ agg2)
{
    const int tid = threadIdx.x;
    const int lane = tid & 63, wrp = tid >> 6;
    const int bid = blockIdx.x;
    const int xcd = bid & 7;
    const int b = xcd >> 1, half = xcd & 1;
    const int tile = bid >> 3;
    const int p0 = b*NN + tile*8 + wrp*2;
    const unsigned short* tab = half ? t2 : t1;
    const unsigned int* gb = (const unsigned int*)(tab + (size_t)b*NN*CC) + lane;
    const int prow = __builtin_amdgcn_readfirstlane(p0);
    const int* i0 = qidx + (size_t)prow*KK;

    unsigned int m0 = 0, m1 = 0;                  // key 0 == most-negative bf16
    #pragma unroll
    for (int k=0;k<KK;k++){
        int j0 = i0[k];
        int j1 = i0[KK + k];
        unsigned int g0 = gb[(size_t)j0*64];
        unsigned int g1 = gb[(size_t)j1*64];
        m0 = pkmax(m0, g0);
        m1 = pkmax(m1, g1);
    }
    unsigned int r0 = key2bf(m0), r1 = key2bf(m1);
    float a00 = lo16(r0), a01 = hi16(r0);
    float a10 = lo16(r1), a11 = hi16(r1);
    if (half){   // agg2 = max + self
        unsigned int s0 = key2bf(((const unsigned int*)(tab + (size_t)p0*CC))[lane]);
        unsigned int s1 = key2bf(((const unsigned int*)(tab + (size_t)(p0+1)*CC))[lane]);
        a00 += lo16(s0); a01 += hi16(s0);
        a10 += lo16(s1); a11 += hi16(s1);
    }
    unsigned short* aout = half ? agg2 : agg1;
    __builtin_nontemporal_store(pk2(a00,a01), (unsigned int*)(aout + (size_t)p0*CC) + lane);
    __builtin_nontemporal_store(pk2(a10,a11), (unsigned int*)(aout + (size_t)(p0+1)*CC) + lane);
}

// ---------------- K4: combine + h2 + out (fused GEMM tail) -------------------
__global__ __launch_bounds__(256) void k_h2o(
    const unsigned short* __restrict__ agg1,
    const unsigned short* __restrict__ agg2,
    const unsigned short* __restrict__ baseb,
    const float* __restrict__ l_bng, const float* __restrict__ l_bnv,
    const unsigned short* __restrict__ wb,
    const float* __restrict__ bng, const float* __restrict__ bnb,
    const float* __restrict__ bnm, const float* __restrict__ bnv,
    float* __restrict__ out)
{
    __shared__ alignas(16) unsigned short Xs[64*128];   // fmid tile [n][c]
    __shared__ alignas(16) unsigned short Ws[128*128];  // m_w1 half / m_w2 half
    __shared__ alignas(16) unsigned short Hs[64*128];   // h2 half  [n][jo_local]
    __shared__ float s_lsc[128];
    __shared__ float s_msc[256], s_msh[256];
    const int tid = threadIdx.x;
    int b, tile;
    xcd_remap(blockIdx.x, b, tile);
    const int n0 = tile * 64;

    if (tid < 128) s_lsc[tid] = l_bng[tid] / sqrtf(l_bnv[tid] + 1e-5f);
    {
        float sc = bng[tid] / sqrtf(bnv[tid] + 1e-5f);
        s_msc[tid] = sc; s_msh[tid] = bnb[tid] - bnm[tid]*sc;
    }
    __syncthreads();

    // combine-stage: fmid = base + (agg1+agg2)*lsc -> Xs (swizzled)
    #pragma unroll
    for (int q=0;q<4;q++){
        int idx = tid + q*256;
        int n = idx >> 4, c8 = (idx & 15)*8;
        size_t base = (size_t)(b*NN + n0 + n)*CC + c8;
        u32x4 a1 = __builtin_nontemporal_load((const u32x4*)(agg1 + base));
        u32x4 a2 = __builtin_nontemporal_load((const u32x4*)(agg2 + base));
        u32x4 bv = __builtin_nontemporal_load((const u32x4*)(baseb + base));
        u32x4 r;
        #pragma unroll
        for (int e=0;e<4;e++){
            int c = c8 + e*2;
            float vlo = lo16(bv[e]) + (lo16(a1[e]) + lo16(a2[e]))*s_lsc[c];
            float vhi = hi16(bv[e]) + (hi16(a1[e]) + hi16(a2[e]))*s_lsc[c+1];
            r[e] = pk2(vlo, vhi);
        }
        int off = n*256 + ((c8*2) ^ ((n&7)<<4));
        *(u32x4*)((char*)Xs + off) = r;
    }

    const int lane = tid & 63, wrp = tid >> 6;
    const int lr = lane & 15, lg = lane >> 4;
    const int o0 = (wrp >> 1) * 64;
    const int nl0 = (wrp & 1) * 32;

    f32x4 oacc[4][2];
    #pragma unroll
    for (int fi=0;fi<4;fi++){ oacc[fi][0]=(f32x4){0,0,0,0}; oacc[fi][1]=(f32x4){0,0,0,0}; }

    for (int jh = 0; jh < 2; ++jh){
        __syncthreads();   // Xs ready (jh=0) / Hs+Ws consumed by prev phase
        {
            const char* img = (const char*)wb + (size_t)(3+jh)*32768;
            #pragma unroll
            for (int p=0;p<8;p++){
                int off = tid*16 + p*4096;
                *(u32x4*)((char*)Ws + off) = *(const u32x4*)(img + off);
            }
        }
        __syncthreads();
        // h2 half = gelu(bn(m_w1_half @ fmid))
        {
            f32x4 hacc[4][2];
            #pragma unroll
            for (int fi=0;fi<4;fi++){ hacc[fi][0]=(f32x4){0,0,0,0}; hacc[fi][1]=(f32x4){0,0,0,0}; }
            #pragma unroll
            for (int kk=0; kk<4; ++kk){
                const int kb = kk*64 + lg*16;
                bf16x8 a[4], x[2];
                #pragma unroll
                for (int fi=0;fi<4;fi++){
                    int row = o0 + fi*16 + lr;
                    a[fi] = *(const bf16x8*)((const char*)Ws + row*256 + (kb ^ ((row&7)<<4)));
                }
                #pragma unroll
                for (int fj=0;fj<2;fj++){
                    int nr = nl0 + fj*16 + lr;
                    x[fj] = *(const bf16x8*)((const char*)Xs + nr*256 + (kb ^ ((nr&7)<<4)));
                }
                #pragma unroll
                for (int fi=0;fi<4;fi++)
                    #pragma unroll
                    for (int fj=0;fj<2;fj++)
                        hacc[fi][fj] = __builtin_amdgcn_mfma_f32_16x16x32_bf16(a[fi], x[fj], hacc[fi][fj], 0,0,0);
            }
            #pragma unroll
            for (int fi=0;fi<4;fi++){
                #pragma unroll
                for (int fj=0;fj<2;fj++){
                    int o = o0 + fi*16 + lg*4;
                    int jo = jh*128 + o;
                    int nl = nl0 + fj*16 + lr;
                    float v0 = gelu(hacc[fi][fj].x*s_msc[jo+0] + s_msh[jo+0]);
                    float v1 = gelu(hacc[fi][fj].y*s_msc[jo+1] + s_msh[jo+1]);
                    float v2 = gelu(hacc[fi][fj].z*s_msc[jo+2] + s_msh[jo+2]);
                    float v3 = gelu(hacc[fi][fj].w*s_msc[jo+3] + s_msh[jo+3]);
                    u32x2 v; v.x = pk2(v0,v1); v.y = pk2(v2,v3);
                    *(u32x2*)((char*)Hs + nl*256 + ((o*2) ^ ((nl&7)<<4))) = v;
                }
            }
        }
        __syncthreads();   // Hs ready; Ws reads done
        {
            const char* img = (const char*)wb + (size_t)(5+jh)*32768;
            #pragma unroll
            for (int p=0;p<8;p++){
                int off = tid*16 + p*4096;
                *(u32x4*)((char*)Ws + off) = *(const u32x4*)(img + off);
            }
        }
        __syncthreads();
        // out += m_w2_half @ h2_half
        #pragma unroll
        for (int kk=0; kk<4; ++kk){
            const int kb = kk*64 + lg*16;
            bf16x8 a[4], x[2];
            #pragma unroll
            for (int fi=0;fi<4;fi++){
                int row = o0 + fi*16 + lr;
                a[fi] = *(const bf16x8*)((const char*)Ws + row*256 + (kb ^ ((row&7)<<4)));
            }
            #pragma unroll
            for (int fj=0;fj<2;fj++){
                int nr = nl0 + fj*16 + lr;
                x[fj] = *(const bf16x8*)((const char*)Hs + nr*256 + (kb ^ ((nr&7)<<4)));
            }
            #pragma unroll
            for (int fi=0;fi<4;fi++)
                #pragma unroll
                for (int fj=0;fj<2;fj++)
                    oacc[fi][fj] = __builtin_amdgcn_mfma_f32_16x16x32_bf16(a[fi], x[fj], oacc[fi][fj], 0,0,0);
        }
    }
    // epilogue: out = fmid(Xs) + oacc
    #pragma unroll
    for (int fi=0;fi<4;fi++){
        #pragma unroll
        for (int fj=0;fj<2;fj++){
            int o = o0 + fi*16 + lg*4;
            int nl = nl0 + fj*16 + lr;
            int n = n0 + nl;
            u32x2 fm = *(const u32x2*)((const char*)Xs + nl*256 + ((o*2) ^ ((nl&7)<<4)));
            float* op = out + ((size_t)b*CC + o)*NN + n;
            op[0*(size_t)NN] = lo16(fm.x) + oacc[fi][fj].x;
            op[1*(size_t)NN] = hi16(fm.x) + oacc[fi][fj].y;
            op[2*(size_t)NN] = lo16(fm.y) + oacc[fi][fj].z;
            op[3*(size_t)NN] = hi16(fm.y) + oacc[fi][fj].w;
        }
    }
}

extern "C" void kernel_launch(void* const* d_in, const int* in_sizes, int n_in,
                              void* d_out, int out_size, void* d_ws, size_t ws_size,
                              hipStream_t stream)
{
    const float* f      = (const float*)d_in[0];
    const float* dp     = (const float*)d_in[1];
    const int*   qidx   = (const int*)  d_in[2];
    const float* dirs   = (const float*)d_in[3];
    const float* de_w1  = (const float*)d_in[4];
    const float* de_bng = (const float*)d_in[5];
    const float* de_bnb = (const float*)d_in[6];
    const float* de_bnm = (const float*)d_in[7];
    const float* de_bnv = (const float*)d_in[8];
    const float* de_w2  = (const float*)d_in[9];
    const float* de_b2  = (const float*)d_in[10];
    const float* l_w1   = (const float*)d_in[11];
    const float* l_b1   = (const float*)d_in[12];
    const float* l_w2   = (const float*)d_in[13];
    const float* l_b2   = (const float*)d_in[14];
    const float* l_w3   = (const float*)d_in[15];
    const float* l_b3   = (const float*)d_in[16];
    const float* l_bng  = (const float*)d_in[17];
    const float* l_bnb  = (const float*)d_in[18];
    const float* l_bnm  = (const float*)d_in[19];
    const float* l_bnv  = (const float*)d_in[20];
    const float* m_w1   = (const float*)d_in[21];
    const float* m_bng  = (const float*)d_in[22];
    const float* m_bnb  = (const float*)d_in[23];
    const float* m_bnm  = (const float*)d_in[24];
    const float* m_bnv  = (const float*)d_in[25];
    const float* m_w2   = (const float*)d_in[26];

    char* ws = (char*)d_ws;
    // layout (bytes), bf16/keys (B,N,128) = 8 MB each:
    //   t1    [0,        8388608)
    //   t2    [8388608,  16777216)
    //   baseb [16777216, 25165824)
    //   agg1  [25165824, 33554432)
    //   agg2  [33554432, 41943040)
    //   wb    [41943040, 42172416)   7 x 32KB weight images
    unsigned short* t1    = (unsigned short*)(ws + 0);
    unsigned short* t2    = (unsigned short*)(ws + 8388608);
    unsigned short* baseb = (unsigned short*)(ws + 16777216);
    unsigned short* agg1  = (unsigned short*)(ws + 25165824);
    unsigned short* agg2  = (unsigned short*)(ws + 33554432);
    unsigned short* wb    = (unsigned short*)(ws + 41943040);

    k_wcv<<<dim3(112), dim3(256), 0, stream>>>(l_w1, l_w2, l_w3, m_w1, m_w2, wb);
    k_linpe<<<dim3(512), dim3(256), 0, stream>>>(f, dp, dirs,
                                                 de_w1, de_bng, de_bnb, de_bnm, de_bnv,
                                                 de_w2, de_b2, wb,
                                                 l_b1, l_b2, l_b3,
                                                 l_bng, l_bnb, l_bnm, l_bnv,
                                                 t1, t2, baseb);
    k_gather<<<dim3(8192), dim3(256), 0, stream>>>(qidx, t1, t2, agg1, agg2);
    k_h2o<<<dim3(512), dim3(256), 0, stream>>>(agg1, agg2, baseb,
                                               l_bng, l_bnv, wb,
                                               m_bng, m_bnb, m_bnm, m_bnv,
                                               (float*)d_out);
}

// Round 11
// 66.429 us; speedup vs baseline: 1.7454x; 1.0025x over previous
//
#include <hip/hip_runtime.h>
#include <hip/hip_bf16.h>
#include <cstdint>
#include <cstddef>

#define BB 4
#define CC 128
#define NN 8192
#define KK 16
#define HH 64
#define MM 32
#define C2 256

typedef __attribute__((ext_vector_type(8))) short bf16x8;
typedef __attribute__((ext_vector_type(4))) float f32x4;
typedef unsigned short u16x2v __attribute__((ext_vector_type(2)));
typedef unsigned int u32x2 __attribute__((ext_vector_type(2)));
typedef unsigned int u32x4 __attribute__((ext_vector_type(4)));

__device__ __forceinline__ unsigned short f2bf(float f){
    unsigned int x = __float_as_uint(f);
    x += 0x7fffu + ((x >> 16) & 1u);
    return (unsigned short)(x >> 16);
}
__device__ __forceinline__ unsigned int pk2(float a, float b){
    return (unsigned int)f2bf(a) | ((unsigned int)f2bf(b) << 16);
}
__device__ __forceinline__ float lo16(unsigned int u){ return __uint_as_float(u << 16); }
__device__ __forceinline__ float hi16(unsigned int u){ return __uint_as_float(u & 0xffff0000u); }
__device__ __forceinline__ float gelu(float a){
    return 0.5f*a*(1.0f+erff(a*0.7071067811865475f));
}
// monotone key transform: unsigned 16-bit compare on keys == float compare on bf16
__device__ __forceinline__ unsigned int bf2key(unsigned int v){
    unsigned int neg = (v >> 15) & 0x10001u;
    return v ^ (0x80008000u | neg * 0x7FFFu);
}
__device__ __forceinline__ unsigned int key2bf(unsigned int k){
    unsigned int pos = (~k >> 15) & 0x10001u;
    return k ^ (0x80008000u | pos * 0x7FFFu);
}
__device__ __forceinline__ unsigned int pkmax(unsigned int a, unsigned int b){
    u16x2v r = __builtin_elementwise_max(__builtin_bit_cast(u16x2v, a),
                                         __builtin_bit_cast(u16x2v, b));
    return __builtin_bit_cast(unsigned int, r);
}
// batch-affinity XCD remap: XCD pair {2b,2b+1} owns batch b.
__device__ __forceinline__ void xcd_remap(int bid, int& b, int& tile){
    int xcd = bid & 7;
    b = xcd >> 1;
    tile = (bid >> 3) * 2 + (xcd & 1);
}

// ---------------- K0: weight convert + pre-swizzle to LDS image layout ------
// images (32 KB each, bf16): 0..2 = l_w1..3; 3,4 = m_w1 halves; 5,6 = m_w2 halves
__global__ __launch_bounds__(256) void k_wcv(
    const float* __restrict__ lw1, const float* __restrict__ lw2,
    const float* __restrict__ lw3, const float* __restrict__ mw1,
    const float* __restrict__ mw2, unsigned short* __restrict__ wb)
{
    const int tid = threadIdx.x;
    const int img = blockIdx.x >> 4;
    const int chunk = blockIdx.x & 15;
    const int o = chunk*8 + (tid >> 5);
    const int c4 = (tid & 31)*4;
    const float* src;
    if (img < 3)      src = (img==0? lw1 : img==1? lw2 : lw3) + (size_t)o*128 + c4;
    else if (img < 5) src = mw1 + ((size_t)(img-3)*128 + o)*128 + c4;
    else              src = mw2 + (size_t)o*256 + (size_t)(img-5)*128 + c4;
    float4 w = *(const float4*)src;
    uint2 v; v.x = pk2(w.x, w.y); v.y = pk2(w.z, w.w);
    *(uint2*)((char*)wb + (size_t)img*32768 + o*256 + ((c4*2) ^ ((o&7)<<4))) = v;
}

// ---------------- K1: merged pe + lin3 ---------------------------------------
__global__ __launch_bounds__(256) void k_linpe(
    const float* __restrict__ f,
    const float* __restrict__ dp, const float* __restrict__ dirs,
    const float* __restrict__ de_w1,
    const float* __restrict__ de_bng, const float* __restrict__ de_bnb,
    const float* __restrict__ de_bnm, const float* __restrict__ de_bnv,
    const float* __restrict__ de_w2, const float* __restrict__ de_b2,
    const unsigned short* __restrict__ wb,
    const float* __restrict__ b1g, const float* __restrict__ b2g,
    const float* __restrict__ b3g,
    const float* __restrict__ l_bng, const float* __restrict__ l_bnb,
    const float* __restrict__ l_bnm, const float* __restrict__ l_bnv,
    unsigned short* __restrict__ t1, unsigned short* __restrict__ t2,
    unsigned short* __restrict__ baseb)
{
    __shared__ alignas(16) char sraw[45056];
    __shared__ alignas(16) unsigned short Xs[64*128];
    __shared__ alignas(16) unsigned short peL[64*128];
    __shared__ float s_dx[MM], s_dy[MM], s_dz[MM];
    __shared__ float s_sc[HH], s_sh[HH], s_b2[CC];
    __shared__ float s_lsc[CC], s_lsh[CC];
    __shared__ float s_bias[128];

    float* dnx = (float*)(sraw + 0);
    float* dny = (float*)(sraw + 4096);
    float* dnz = (float*)(sraw + 8192);
    unsigned short* th  = (unsigned short*)(sraw + 12288);
    unsigned short* ws1 = (unsigned short*)(sraw + 16384);
    unsigned short* ws2 = (unsigned short*)(sraw + 20480);
    unsigned short* hs  = (unsigned short*)(sraw + 36864);
    unsigned short* Ws  = (unsigned short*)(sraw + 0);

    const int tid = threadIdx.x;
    int b, tile; xcd_remap(blockIdx.x, b, tile);
    const int n0 = tile * 64;

    if (tid < MM){
        float x=dirs[tid*3+0], y=dirs[tid*3+1], z=dirs[tid*3+2];
        float inv = 1.0f / fmaxf(sqrtf(x*x+y*y+z*z), 1e-12f);
        s_dx[tid]=x*inv; s_dy[tid]=y*inv; s_dz[tid]=z*inv;
    }
    #pragma unroll
    for (int p=0;p<2;p++){
        int id = tid + p*256;
        int row = id >> 3, c4 = (id & 7)*4;
        float4 w = *(const float4*)(de_w1 + row*MM + c4);
        int off = row*64 + ((c4*2) ^ ((row&3)<<4));
        uint2 v; v.x = pk2(w.x,w.y); v.y = pk2(w.z,w.w);
        *(uint2*)((char*)ws1 + off) = v;
    }
    #pragma unroll
    for (int p=0;p<8;p++){
        int id = tid + p*256;
        int row = id >> 4, c4 = (id & 15)*4;
        float4 w = *(const float4*)(de_w2 + row*HH + c4);
        int off = row*128 + ((c4*2) ^ ((row&7)<<4));
        uint2 v; v.x = pk2(w.x,w.y); v.y = pk2(w.z,w.w);
        *(uint2*)((char*)ws2 + off) = v;
    }
    if (tid < HH){
        float sc = de_bng[tid] / sqrtf(de_bnv[tid] + 1e-5f);
        s_sc[tid]=sc; s_sh[tid]=de_bnb[tid]-de_bnm[tid]*sc;
    }
    if (tid >= 64 && tid < 192) s_b2[tid-64] = de_b2[tid-64];
    if (tid < CC){
        float sc = l_bng[tid] / sqrtf(l_bnv[tid] + 1e-5f);
        s_lsc[tid] = sc; s_lsh[tid] = l_bnb[tid] - l_bnm[tid]*sc;
    }
    {
        const int j = (tid & 15) * 4;
        #pragma unroll
        for (int p = 0; p < 2; ++p){
            const int cb = ((tid >> 4) + p*16) * 4;
            const float* src = f + ((size_t)b*CC + cb)*NN + n0 + j;
            float4 r0 = *(const float4*)(src);
            float4 r1 = *(const float4*)(src + NN);
            float4 r2 = *(const float4*)(src + 2*(size_t)NN);
            float4 r3 = *(const float4*)(src + 3*(size_t)NN);
            const float rr[4][4] = {{r0.x,r1.x,r2.x,r3.x},{r0.y,r1.y,r2.y,r3.y},
                                    {r0.z,r1.z,r2.z,r3.z},{r0.w,r1.w,r2.w,r3.w}};
            #pragma unroll
            for (int i=0;i<4;i++){
                int n = j + i;
                int off = n*256 + ((cb*2) ^ ((n&7)<<4));
                uint2 v; v.x = pk2(rr[i][0], rr[i][1]); v.y = pk2(rr[i][2], rr[i][3]);
                *(uint2*)((char*)Xs + off) = v;
            }
        }
    }
    {
        const size_t cstride = (size_t)NN*KK;
        const float* base = dp + (size_t)b*3*cstride + (size_t)n0*KK + tid*4;
        float4 X = *(const float4*)(base);
        float4 Y = *(const float4*)(base + cstride);
        float4 Z = *(const float4*)(base + 2*cstride);
        float i0 = 1.0f/fmaxf(sqrtf(X.x*X.x+Y.x*Y.x+Z.x*Z.x),1e-12f);
        float i1 = 1.0f/fmaxf(sqrtf(X.y*X.y+Y.y*Y.y+Z.y*Z.y),1e-12f);
        float i2 = 1.0f/fmaxf(sqrtf(X.z*X.z+Y.z*Y.z+Z.z*Z.z),1e-12f);
        float i3 = 1.0f/fmaxf(sqrtf(X.w*X.w+Y.w*Y.w+Z.w*Z.w),1e-12f);
        float4 xn = {X.x*i0, X.y*i1, X.z*i2, X.w*i3};
        float4 yn = {Y.x*i0, Y.y*i1, Y.z*i2, Y.w*i3};
        float4 zn = {Z.x*i0, Z.y*i1, Z.z*i2, Z.w*i3};
        const int np = tid >> 2;
        const int off = np*64 + (((tid&3)*16) ^ ((np&3)<<4));
        *(float4*)((char*)dnx + off) = xn;
        *(float4*)((char*)dny + off) = yn;
        *(float4*)((char*)dnz + off) = zn;
    }
    __syncthreads();

    {
        const int np = tid & 63, dg = tid >> 6;
        float vx[8], vy[8], vz[8];
        #pragma unroll
        for (int d=0;d<8;d++){ vx[d]=s_dx[dg*8+d]; vy[d]=s_dy[dg*8+d]; vz[d]=s_dz[dg*8+d]; }
        float tm[8];
        #pragma unroll
        for (int d=0;d<8;d++) tm[d] = -2.0f;
        #pragma unroll
        for (int g=0;g<4;g++){
            int off = np*64 + ((g*16) ^ ((np&3)<<4));
            float4 x4 = *(const float4*)((const char*)dnx + off);
            float4 y4 = *(const float4*)((const char*)dny + off);
            float4 z4 = *(const float4*)((const char*)dnz + off);
            const float xs[4]={x4.x,x4.y,x4.z,x4.w}, ys[4]={y4.x,y4.y,y4.z,y4.w},
                        zs[4]={z4.x,z4.y,z4.z,z4.w};
            #pragma unroll
            for (int q=0;q<4;q++)
                #pragma unroll
                for (int d=0;d<8;d++)
                    tm[d] = fmaxf(tm[d], vx[d]*xs[q]+vy[d]*ys[q]+vz[d]*zs[q]);
        }
        uint4 t4; t4.x=pk2(tm[0],tm[1]); t4.y=pk2(tm[2],tm[3]);
        t4.z=pk2(tm[4],tm[5]); t4.w=pk2(tm[6],tm[7]);
        int off = np*64 + ((dg*16) ^ ((np&3)<<4));
        *(uint4*)((char*)th + off) = t4;
    }
    __syncthreads();

    const int wid = tid >> 6, lane = tid & 63;
    const int lr = lane & 15, lg = lane >> 4;

    {
        const int arow = wid*16 + lr;
        bf16x8 afr = *(const bf16x8*)((const char*)ws1 + arow*64 + ((lg*16) ^ ((arow&3)<<4)));
        f32x4 hacc[4];
        #pragma unroll
        for (int nf=0;nf<4;nf++){
            int pt = nf*16 + lr;
            bf16x8 bfr = *(const bf16x8*)((const char*)th + pt*64 + ((lg*16) ^ ((pt&3)<<4)));
            f32x4 z = {0.f,0.f,0.f,0.f};
            hacc[nf] = __builtin_amdgcn_mfma_f32_16x16x32_bf16(afr, bfr, z, 0,0,0);
        }
        #pragma unroll
        for (int nf=0;nf<4;nf++){
            int ch0 = wid*16 + lg*4;
            int pt = nf*16 + lr;
            float g0 = gelu(hacc[nf].x*s_sc[ch0+0] + s_sh[ch0+0]);
            float g1 = gelu(hacc[nf].y*s_sc[ch0+1] + s_sh[ch0+1]);
            float g2 = gelu(hacc[nf].z*s_sc[ch0+2] + s_sh[ch0+2]);
            float g3 = gelu(hacc[nf].w*s_sc[ch0+3] + s_sh[ch0+3]);
            uint2 v; v.x = pk2(g0,g1); v.y = pk2(g2,g3);
            *(uint2*)((char*)hs + pt*128 + ((ch0*2) ^ ((pt&7)<<4))) = v;
        }
    }
    __syncthreads();

    {
        f32x4 pacc[2][4];
        #pragma unroll
        for (int mi=0;mi<2;mi++)
            #pragma unroll
            for (int nf=0;nf<4;nf++) pacc[mi][nf] = (f32x4){0.f,0.f,0.f,0.f};
        #pragma unroll
        for (int ks=0;ks<2;ks++){
            bf16x8 a[2], x[4];
            #pragma unroll
            for (int mi=0;mi<2;mi++){
                int row = (wid*2+mi)*16 + lr;
                a[mi] = *(const bf16x8*)((const char*)ws2 + row*128 + ((ks*64 + lg*16) ^ ((row&7)<<4)));
            }
            #pragma unroll
            for (int nf=0;nf<4;nf++){
                int pt = nf*16 + lr;
                x[nf] = *(const bf16x8*)((const char*)hs + pt*128 + ((ks*64 + lg*16) ^ ((pt&7)<<4)));
            }
            #pragma unroll
            for (int mi=0;mi<2;mi++)
                #pragma unroll
                for (int nf=0;nf<4;nf++)
                    pacc[mi][nf] = __builtin_amdgcn_mfma_f32_16x16x32_bf16(a[mi], x[nf], pacc[mi][nf], 0,0,0);
        }
        #pragma unroll
        for (int mi=0;mi<2;mi++){
            #pragma unroll
            for (int nf=0;nf<4;nf++){
                int ch0 = (wid*2+mi)*16 + lg*4;
                int pt = nf*16 + lr;
                uint2 v;
                v.x = pk2(pacc[mi][nf].x + s_b2[ch0+0], pacc[mi][nf].y + s_b2[ch0+1]);
                v.y = pk2(pacc[mi][nf].z + s_b2[ch0+2], pacc[mi][nf].w + s_b2[ch0+3]);
                *(uint2*)((char*)peL + pt*256 + ((ch0*2) ^ ((pt&7)<<4))) = v;
            }
        }
    }

    const int o0 = (wid >> 1) * 64;
    const int nl0 = (wid & 1) * 32;

    for (int mat = 0; mat < 3; ++mat){
        const float* Bg = (mat==0)? b1g : (mat==1)? b2g : b3g;
        __syncthreads();
        {
            const char* img = (const char*)wb + (size_t)mat*32768;
            #pragma unroll
            for (int p=0;p<8;p++){
                int off = tid*16 + p*4096;
                *(u32x4*)((char*)Ws + off) = *(const u32x4*)(img + off);
            }
        }
        if (tid < 128) s_bias[tid] = Bg[tid];
        __syncthreads();

        f32x4 acc[4][2];
        #pragma unroll
        for (int fi=0;fi<4;fi++){
            int o = o0 + fi*16 + lg*4;
            f32x4 bi = {s_bias[o], s_bias[o+1], s_bias[o+2], s_bias[o+3]};
            acc[fi][0] = bi; acc[fi][1] = bi;
        }
        #pragma unroll
        for (int kk=0; kk<4; ++kk){
            const int kb = kk*64 + lg*16;
            bf16x8 a[4], x[2];
            #pragma unroll
            for (int fi=0;fi<4;fi++){
                int row = o0 + fi*16 + lr;
                a[fi] = *(const bf16x8*)((const char*)Ws + row*256 + (kb ^ ((row&7)<<4)));
            }
            #pragma unroll
            for (int fj=0;fj<2;fj++){
                int nr = nl0 + fj*16 + lr;
                x[fj] = *(const bf16x8*)((const char*)Xs + nr*256 + (kb ^ ((nr&7)<<4)));
            }
            #pragma unroll
            for (int fi=0;fi<4;fi++)
                #pragma unroll
                for (int fj=0;fj<2;fj++)
                    acc[fi][fj] = __builtin_amdgcn_mfma_f32_16x16x32_bf16(a[fi], x[fj], acc[fi][fj], 0,0,0);
        }
        #pragma unroll
        for (int fi=0;fi<4;fi++){
            #pragma unroll
            for (int fj=0;fj<2;fj++){
                int o = o0 + fi*16 + lg*4;
                int nl = nl0 + fj*16 + lr;
                int n = n0 + nl;
                if (mat == 2){
                    u32x2 fm = *(const u32x2*)((const char*)Xs  + nl*256 + ((o*2) ^ ((nl&7)<<4)));
                    u32x2 pv = *(const u32x2*)((const char*)peL + nl*256 + ((o*2) ^ ((nl&7)<<4)));
                    float v0 = lo16(fm.x) + acc[fi][fj].x*s_lsc[o+0] + s_lsh[o+0] + lo16(pv.x);
                    float v1 = hi16(fm.x) + acc[fi][fj].y*s_lsc[o+1] + s_lsh[o+1] + hi16(pv.x);
                    float v2 = lo16(fm.y) + acc[fi][fj].z*s_lsc[o+2] + s_lsh[o+2] + lo16(pv.y);
                    float v3 = hi16(fm.y) + acc[fi][fj].w*s_lsc[o+3] + s_lsh[o+3] + hi16(pv.y);
                    u32x2 r; r.x = pk2(v0,v1); r.y = pk2(v2,v3);
                    *(u32x2*)(baseb + (size_t)(b*NN + n)*CC + o) = r;
                } else {
                    unsigned short* dst = (mat==0)? t1 : t2;
                    uint2 kv;
                    kv.x = bf2key(pk2(acc[fi][fj].x, acc[fi][fj].y));
                    kv.y = bf2key(pk2(acc[fi][fj].z, acc[fi][fj].w));
                    *(uint2*)(dst + (size_t)(b*NN + n)*CC + o) = kv;
                }
            }
        }
    }
}

// ---------------- K3: split-half knn gather-max ------------------------------
__global__ __launch_bounds__(256) void k_gather(
    const int* __restrict__ qidx,
    const unsigned short* __restrict__ t1,
    const unsigned short* __restrict__ t2,
    unsigned short* __restrict__ agg1,
    unsigned short* __restrict__ agg2)
{
    const int tid = threadIdx.x;
    const int lane = tid & 63, wrp = tid >> 6;
    const int bid = blockIdx.x;
    const int xcd = bid & 7;
    const int b = xcd >> 1, half = xcd & 1;
    const int tile = bid >> 3;
    const int p0 = b*NN + tile*8 + wrp*2;
    const unsigned short* tab = half ? t2 : t1;
    const unsigned int* gb = (const unsigned int*)(tab + (size_t)b*NN*CC) + lane;
    const int prow = __builtin_amdgcn_readfirstlane(p0);
    const int* i0 = qidx + (size_t)prow*KK;

    unsigned int m0 = 0, m1 = 0;                  // key 0 == most-negative bf16
    #pragma unroll
    for (int k=0;k<KK;k++){
        int j0 = i0[k];
        int j1 = i0[KK + k];
        unsigned int g0 = gb[(size_t)j0*64];
        unsigned int g1 = gb[(size_t)j1*64];
        m0 = pkmax(m0, g0);
        m1 = pkmax(m1, g1);
    }
    unsigned int r0 = key2bf(m0), r1 = key2bf(m1);
    float a00 = lo16(r0), a01 = hi16(r0);
    float a10 = lo16(r1), a11 = hi16(r1);
    if (half){   // agg2 = max + self
        unsigned int s0 = key2bf(((const unsigned int*)(tab + (size_t)p0*CC))[lane]);
        unsigned int s1 = key2bf(((const unsigned int*)(tab + (size_t)(p0+1)*CC))[lane]);
        a00 += lo16(s0); a01 += hi16(s0);
        a10 += lo16(s1); a11 += hi16(s1);
    }
    unsigned short* aout = half ? agg2 : agg1;
    ((unsigned int*)(aout + (size_t)p0*CC))[lane]     = pk2(a00,a01);
    ((unsigned int*)(aout + (size_t)(p0+1)*CC))[lane] = pk2(a10,a11);
}

// ---------------- K4: combine + h2 + out (fused GEMM tail) -------------------
__global__ __launch_bounds__(256) void k_h2o(
    const unsigned short* __restrict__ agg1,
    const unsigned short* __restrict__ agg2,
    const unsigned short* __restrict__ baseb,
    const float* __restrict__ l_bng, const float* __restrict__ l_bnv,
    const unsigned short* __restrict__ wb,
    const float* __restrict__ bng, const float* __restrict__ bnb,
    const float* __restrict__ bnm, const float* __restrict__ bnv,
    float* __restrict__ out)
{
    __shared__ alignas(16) unsigned short Xs[64*128];   // fmid tile [n][c]
    __shared__ alignas(16) unsigned short Ws[128*128];  // m_w1 half / m_w2 half
    __shared__ alignas(16) unsigned short Hs[64*128];   // h2 half  [n][jo_local]
    __shared__ float s_lsc[128];
    __shared__ float s_msc[256], s_msh[256];
    const int tid = threadIdx.x;
    int b, tile;
    xcd_remap(blockIdx.x, b, tile);
    const int n0 = tile * 64;

    if (tid < 128) s_lsc[tid] = l_bng[tid] / sqrtf(l_bnv[tid] + 1e-5f);
    {
        float sc = bng[tid] / sqrtf(bnv[tid] + 1e-5f);
        s_msc[tid] = sc; s_msh[tid] = bnb[tid] - bnm[tid]*sc;
    }
    __syncthreads();

    // combine-stage: fmid = base + (agg1+agg2)*lsc -> Xs (swizzled)
    // overlapped with W1(jh=0) staging (independent)
    #pragma unroll
    for (int q=0;q<4;q++){
        int idx = tid + q*256;
        int n = idx >> 4, c8 = (idx & 15)*8;
        size_t base = (size_t)(b*NN + n0 + n)*CC + c8;
        u32x4 a1 = *(const u32x4*)(agg1 + base);
        u32x4 a2 = *(const u32x4*)(agg2 + base);
        u32x4 bv = *(const u32x4*)(baseb + base);
        u32x4 r;
        #pragma unroll
        for (int e=0;e<4;e++){
            int c = c8 + e*2;
            float vlo = lo16(bv[e]) + (lo16(a1[e]) + lo16(a2[e]))*s_lsc[c];
            float vhi = hi16(bv[e]) + (hi16(a1[e]) + hi16(a2[e]))*s_lsc[c+1];
            r[e] = pk2(vlo, vhi);
        }
        int off = n*256 + ((c8*2) ^ ((n&7)<<4));
        *(u32x4*)((char*)Xs + off) = r;
    }
    {
        const char* img = (const char*)wb + (size_t)3*32768;   // W1 half 0
        #pragma unroll
        for (int p=0;p<8;p++){
            int off = tid*16 + p*4096;
            *(u32x4*)((char*)Ws + off) = *(const u32x4*)(img + off);
        }
    }

    const int lane = tid & 63, wrp = tid >> 6;
    const int lr = lane & 15, lg = lane >> 4;
    const int o0 = (wrp >> 1) * 64;
    const int nl0 = (wrp & 1) * 32;

    f32x4 oacc[4][2];
    #pragma unroll
    for (int fi=0;fi<4;fi++){ oacc[fi][0]=(f32x4){0,0,0,0}; oacc[fi][1]=(f32x4){0,0,0,0}; }

    for (int jh = 0; jh < 2; ++jh){
        if (jh == 1){
            __syncthreads();   // GEMMout(0) done reading Ws
            const char* img = (const char*)wb + (size_t)4*32768;   // W1 half 1
            #pragma unroll
            for (int p=0;p<8;p++){
                int off = tid*16 + p*4096;
                *(u32x4*)((char*)Ws + off) = *(const u32x4*)(img + off);
            }
        }
        __syncthreads();   // Xs+Ws ready
        // h2 half = gelu(bn(m_w1_half @ fmid))
        {
            f32x4 hacc[4][2];
            #pragma unroll
            for (int fi=0;fi<4;fi++){ hacc[fi][0]=(f32x4){0,0,0,0}; hacc[fi][1]=(f32x4){0,0,0,0}; }
            #pragma unroll
            for (int kk=0; kk<4; ++kk){
                const int kb = kk*64 + lg*16;
                bf16x8 a[4], x[2];
                #pragma unroll
                for (int fi=0;fi<4;fi++){
                    int row = o0 + fi*16 + lr;
                    a[fi] = *(const bf16x8*)((const char*)Ws + row*256 + (kb ^ ((row&7)<<4)));
                }
                #pragma unroll
                for (int fj=0;fj<2;fj++){
                    int nr = nl0 + fj*16 + lr;
                    x[fj] = *(const bf16x8*)((const char*)Xs + nr*256 + (kb ^ ((nr&7)<<4)));
                }
                #pragma unroll
                for (int fi=0;fi<4;fi++)
                    #pragma unroll
                    for (int fj=0;fj<2;fj++)
                        hacc[fi][fj] = __builtin_amdgcn_mfma_f32_16x16x32_bf16(a[fi], x[fj], hacc[fi][fj], 0,0,0);
            }
            #pragma unroll
            for (int fi=0;fi<4;fi++){
                #pragma unroll
                for (int fj=0;fj<2;fj++){
                    int o = o0 + fi*16 + lg*4;
                    int jo = jh*128 + o;
                    int nl = nl0 + fj*16 + lr;
                    float v0 = gelu(hacc[fi][fj].x*s_msc[jo+0] + s_msh[jo+0]);
                    float v1 = gelu(hacc[fi][fj].y*s_msc[jo+1] + s_msh[jo+1]);
                    float v2 = gelu(hacc[fi][fj].z*s_msc[jo+2] + s_msh[jo+2]);
                    float v3 = gelu(hacc[fi][fj].w*s_msc[jo+3] + s_msh[jo+3]);
                    u32x2 v; v.x = pk2(v0,v1); v.y = pk2(v2,v3);
                    *(u32x2*)((char*)Hs + nl*256 + ((o*2) ^ ((nl&7)<<4))) = v;
                }
            }
        }
        __syncthreads();   // Hs ready; Ws reads done
        {
            const char* img = (const char*)wb + (size_t)(5+jh)*32768;
            #pragma unroll
            for (int p=0;p<8;p++){
                int off = tid*16 + p*4096;
                *(u32x4*)((char*)Ws + off) = *(const u32x4*)(img + off);
            }
        }
        __syncthreads();
        // out += m_w2_half @ h2_half
        #pragma unroll
        for (int kk=0; kk<4; ++kk){
            const int kb = kk*64 + lg*16;
            bf16x8 a[4], x[2];
            #pragma unroll
            for (int fi=0;fi<4;fi++){
                int row = o0 + fi*16 + lr;
                a[fi] = *(const bf16x8*)((const char*)Ws + row*256 + (kb ^ ((row&7)<<4)));
            }
            #pragma unroll
            for (int fj=0;fj<2;fj++){
                int nr = nl0 + fj*16 + lr;
                x[fj] = *(const bf16x8*)((const char*)Hs + nr*256 + (kb ^ ((nr&7)<<4)));
            }
            #pragma unroll
            for (int fi=0;fi<4;fi++)
                #pragma unroll
                for (int fj=0;fj<2;fj++)
                    oacc[fi][fj] = __builtin_amdgcn_mfma_f32_16x16x32_bf16(a[fi], x[fj], oacc[fi][fj], 0,0,0);
        }
    }
    // epilogue: out = fmid(Xs) + oacc  (NT: final output, never re-read)
    #pragma unroll
    for (int fi=0;fi<4;fi++){
        #pragma unroll
        for (int fj=0;fj<2;fj++){
            int o = o0 + fi*16 + lg*4;
            int nl = nl0 + fj*16 + lr;
            int n = n0 + nl;
            u32x2 fm = *(const u32x2*)((const char*)Xs + nl*256 + ((o*2) ^ ((nl&7)<<4)));
            float* op = out + ((size_t)b*CC + o)*NN + n;
            __builtin_nontemporal_store(lo16(fm.x) + oacc[fi][fj].x, op + 0*(size_t)NN);
            __builtin_nontemporal_store(hi16(fm.x) + oacc[fi][fj].y, op + 1*(size_t)NN);
            __builtin_nontemporal_store(lo16(fm.y) + oacc[fi][fj].z, op + 2*(size_t)NN);
            __builtin_nontemporal_store(hi16(fm.y) + oacc[fi][fj].w, op + 3*(size_t)NN);
        }
    }
}

extern "C" void kernel_launch(void* const* d_in, const int* in_sizes, int n_in,
                              void* d_out, int out_size, void* d_ws, size_t ws_size,
                              hipStream_t stream)
{
    const float* f      = (const float*)d_in[0];
    const float* dp     = (const float*)d_in[1];
    const int*   qidx   = (const int*)  d_in[2];
    const float* dirs   = (const float*)d_in[3];
    const float* de_w1  = (const float*)d_in[4];
    const float* de_bng = (const float*)d_in[5];
    const float* de_bnb = (const float*)d_in[6];
    const float* de_bnm = (const float*)d_in[7];
    const float* de_bnv = (const float*)d_in[8];
    const float* de_w2  = (const float*)d_in[9];
    const float* de_b2  = (const float*)d_in[10];
    const float* l_w1   = (const float*)d_in[11];
    const float* l_b1   = (const float*)d_in[12];
    const float* l_w2   = (const float*)d_in[13];
    const float* l_b2   = (const float*)d_in[14];
    const float* l_w3   = (const float*)d_in[15];
    const float* l_b3   = (const float*)d_in[16];
    const float* l_bng  = (const float*)d_in[17];
    const float* l_bnb  = (const float*)d_in[18];
    const float* l_bnm  = (const float*)d_in[19];
    const float* l_bnv  = (const float*)d_in[20];
    const float* m_w1   = (const float*)d_in[21];
    const float* m_bng  = (const float*)d_in[22];
    const float* m_bnb  = (const float*)d_in[23];
    const float* m_bnm  = (const float*)d_in[24];
    const float* m_bnv  = (const float*)d_in[25];
    const float* m_w2   = (const float*)d_in[26];

    char* ws = (char*)d_ws;
    // layout (bytes), bf16/keys (B,N,128) = 8 MB each:
    //   t1    [0,        8388608)
    //   t2    [8388608,  16777216)
    //   baseb [16777216, 25165824)
    //   agg1  [25165824, 33554432)
    //   agg2  [33554432, 41943040)
    //   wb    [41943040, 42172416)   7 x 32KB weight images
    unsigned short* t1    = (unsigned short*)(ws + 0);
    unsigned short* t2    = (unsigned short*)(ws + 8388608);
    unsigned short* baseb = (unsigned short*)(ws + 16777216);
    unsigned short* agg1  = (unsigned short*)(ws + 25165824);
    unsigned short* agg2  = (unsigned short*)(ws + 33554432);
    unsigned short* wb    = (unsigned short*)(ws + 41943040);

    k_wcv<<<dim3(112), dim3(256), 0, stream>>>(l_w1, l_w2, l_w3, m_w1, m_w2, wb);
    k_linpe<<<dim3(512), dim3(256), 0, stream>>>(f, dp, dirs,
                                                 de_w1, de_bng, de_bnb, de_bnm, de_bnv,
                                                 de_w2, de_b2, wb,
                                                 l_b1, l_b2, l_b3,
                                                 l_bng, l_bnb, l_bnm, l_bnv,
                                                 t1, t2, baseb);
    k_gather<<<dim3(8192), dim3(256), 0, stream>>>(qidx, t1, t2, agg1, agg2);
    k_h2o<<<dim3(512), dim3(256), 0, stream>>>(agg1, agg2, baseb,
                                               l_bng, l_bnv, wb,
                                               m_bng, m_bnb, m_bnm, m_bnv,
                                               (float*)d_out);
}